// Round 8
// baseline (515.687 us; speedup 1.0000x reference)
//
#include <hip/hip_runtime.h>
#include <math.h>

#define NF 128
#define EPS 1e-5f
#define BNB 1e-4f
#define CHUNK 8192

static inline int cdiv(int a, int b){ return (a + b - 1) / b; }

typedef __attribute__((ext_vector_type(8))) short bf16x8;
typedef __attribute__((ext_vector_type(4))) float f32x4;

__device__ __forceinline__ float lrelu(float x){ return x > 0.f ? x : 0.2f * x; }
__device__ __forceinline__ float sel4(float4 v, int h){
  float r = v.x;
  r = (h == 1) ? v.y : r;
  r = (h == 2) ? v.z : r;
  r = (h == 3) ? v.w : r;
  return r;
}

// f32 -> bf16 round-to-nearest-even (finite inputs)
__device__ __forceinline__ unsigned short f2b(float f){
  unsigned u = __float_as_uint(f);
  u += 0x7fffu + ((u >> 16) & 1u);
  return (unsigned short)(u >> 16);
}
__device__ __forceinline__ float b2f_lo(unsigned v){ return __uint_as_float(v << 16); }
__device__ __forceinline__ float b2f_hi(unsigned v){ return __uint_as_float(v & 0xffff0000u); }

// ---------------- CSR build: chunked-reservation bucket sort ----------------
__global__ void k_zero(float* stats, int* bcnt, int nbkt){
  int i = blockIdx.x * blockDim.x + threadIdx.x;
  if (i < 1024) stats[i] = 0.f;
  if (i < nbkt) bcnt[i] = 0;
}

// coarse histogram over buckets (dst>>8), LDS-aggregated
__global__ __launch_bounds__(256) void k_bhist(const int* __restrict__ ei, int E, int n,
                                               int* __restrict__ bcnt, int nbkt){
  __shared__ int h[256];
  h[threadIdx.x] = 0;
  __syncthreads();
  int total = E + n;
  for (int i = blockIdx.x * 256 + threadIdx.x; i < total; i += gridDim.x * 256){
    int d = (i < E) ? ei[E + i] : (i - E);
    atomicAdd(&h[d >> 8], 1);
  }
  __syncthreads();
  if (threadIdx.x < nbkt && h[threadIdx.x]) atomicAdd(&bcnt[threadIdx.x], h[threadIdx.x]);
}

// 1-block exclusive scan over nbkt (<=256) bucket counts -> boff, bcursor
__global__ __launch_bounds__(256) void k_bscan(const int* __restrict__ bcnt, int* __restrict__ boff,
                                               int* __restrict__ bcursor, int nb){
  int t = threadIdx.x;
  int v = (t < nb) ? bcnt[t] : 0;
  int lane = t & 63, w = t >> 6;
  int x = v;
  #pragma unroll
  for (int d = 1; d < 64; d <<= 1){
    int y = __shfl_up(x, d, 64);
    if (lane >= d) x += y;
  }
  __shared__ int wt[4], wex[4];
  if (lane == 63) wt[w] = x;
  __syncthreads();
  if (t == 0){ int r = 0; for (int i = 0; i < 4; ++i){ wex[i] = r; r += wt[i]; } }
  __syncthreads();
  int ex = wex[w] + x - v;
  if (t < nb){ boff[t] = ex; bcursor[t] = ex; }
  if (t == nb - 1) boff[nb] = ex + v;
}

// chunked scatter: per block, LDS hist -> one reservation atomic per bucket -> ranked write.
__global__ __launch_bounds__(256) void k_bscatter2(const int* __restrict__ ei, int E, int n,
                                                   int* __restrict__ bcursor,
                                                   unsigned* __restrict__ ebuf, int nbkt){
  __shared__ int h[256], base[256];
  int t = threadIdx.x;
  int total = E + n;
  int lo = blockIdx.x * CHUNK;
  int hi = min(lo + CHUNK, total);
  h[t] = 0;
  __syncthreads();
  for (int i = lo + t; i < hi; i += 256){
    int d = (i < E) ? ei[E + i] : (i - E);
    atomicAdd(&h[d >> 8], 1);
  }
  __syncthreads();
  int cnt = h[t];
  if (t < nbkt && cnt > 0) base[t] = atomicAdd(&bcursor[t], cnt);
  __syncthreads();
  h[t] = 0;
  __syncthreads();
  for (int i = lo + t; i < hi; i += 256){
    int s, d;
    if (i < E){ s = ei[i]; d = ei[E + i]; }
    else { s = i - E; d = s; }
    int b = d >> 8;
    int r = atomicAdd(&h[b], 1);
    ebuf[base[b] + r] = ((unsigned)s << 8) | (unsigned)(d & 255);
  }
}

// per-bucket degree via LDS histogram (no global atomics; includes self-loops)
__global__ __launch_bounds__(256) void k_deg(const unsigned* __restrict__ ebuf,
                                             const int* __restrict__ boff,
                                             int* __restrict__ deg, int n){
  __shared__ int h[256];
  int t = threadIdx.x, b = blockIdx.x;
  h[t] = 0;
  __syncthreads();
  int lo = boff[b], hi = boff[b + 1];
  for (int i = lo + t; i < hi; i += 256) atomicAdd(&h[ebuf[i] & 255u], 1);
  __syncthreads();
  int node = b * 256 + t;
  if (node < n) deg[node] = h[t];
}

// ---- 3-phase multi-block exclusive scan over deg -> off ----
__global__ __launch_bounds__(256) void k_scan1(const int* __restrict__ deg, int* __restrict__ bsum, int n){
  int i = blockIdx.x * 256 + threadIdx.x;
  int v = (i < n) ? deg[i] : 0;
  int lane = threadIdx.x & 63, w = threadIdx.x >> 6;
  int s = v;
  #pragma unroll
  for (int d = 1; d < 64; d <<= 1) s += __shfl_xor(s, d, 64);
  __shared__ int ws_[4];
  if (lane == 0) ws_[w] = s;
  __syncthreads();
  if (threadIdx.x == 0) bsum[blockIdx.x] = ws_[0] + ws_[1] + ws_[2] + ws_[3];
}

__global__ __launch_bounds__(256) void k_scan2(int* __restrict__ bsum, int nb){
  int t = threadIdx.x;
  int v = (t < nb) ? bsum[t] : 0;
  int lane = t & 63, w = t >> 6;
  int x = v;
  #pragma unroll
  for (int d = 1; d < 64; d <<= 1){
    int y = __shfl_up(x, d, 64);
    if (lane >= d) x += y;
  }
  __shared__ int wt[4], wex[4];
  if (lane == 63) wt[w] = x;
  __syncthreads();
  if (t == 0){ int r = 0; for (int i = 0; i < 4; ++i){ wex[i] = r; r += wt[i]; } }
  __syncthreads();
  if (t < nb) bsum[t] = wex[w] + x - v;   // exclusive
}

__global__ __launch_bounds__(256) void k_scan3(const int* __restrict__ deg, const int* __restrict__ bsum,
                                               int* __restrict__ off, int n){
  int i = blockIdx.x * 256 + threadIdx.x;
  int v = (i < n) ? deg[i] : 0;
  int lane = threadIdx.x & 63, w = threadIdx.x >> 6;
  int x = v;
  #pragma unroll
  for (int d = 1; d < 64; d <<= 1){
    int y = __shfl_up(x, d, 64);
    if (lane >= d) x += y;
  }
  __shared__ int wt[4], wex[4];
  if (lane == 63) wt[w] = x;
  __syncthreads();
  if (threadIdx.x == 0){ int r = 0; for (int j = 0; j < 4; ++j){ wex[j] = r; r += wt[j]; } }
  __syncthreads();
  int excl = bsum[blockIdx.x] + wex[w] + (x - v);
  if (i < n) off[i] = excl;
  if (i == n - 1) off[n] = excl + v;
}

// per-bucket fine scatter: rank via LDS atomics, write into L2-resident CSR window
__global__ __launch_bounds__(256) void k_fine(const unsigned* __restrict__ ebuf,
                                              const int* __restrict__ boff,
                                              const int* __restrict__ off,
                                              int* __restrict__ esrc, int n){
  __shared__ int h[256];
  int t = threadIdx.x, b = blockIdx.x;
  h[t] = 0;
  __syncthreads();
  int lo = boff[b], hi = boff[b + 1];
  int base = b * 256;
  for (int i = lo + t; i < hi; i += 256){
    unsigned pk = ebuf[i];
    int ld = (int)(pk & 255u);
    int s  = (int)(pk >> 8);
    int r = atomicAdd(&h[ld], 1);
    esrc[off[base + ld] + r] = s;
  }
}

// ---------------- BN column stats (sum, sumsq into stats[0..127], stats[128..255]) ----------------
__global__ __launch_bounds__(256) void k_colstats(const float* __restrict__ X, int n, float* __restrict__ out){
  __shared__ float ss[4][128], sq[4][128];
  int t = threadIdx.x, lane = t & 63, w = t >> 6;
  float sx = 0.f, sy = 0.f, qx = 0.f, qy = 0.f;
  for (int r = blockIdx.x * 4 + w; r < n; r += gridDim.x * 4){
    float2 v = *(const float2*)(X + (size_t)r * NF + lane * 2);
    sx += v.x; sy += v.y; qx += v.x * v.x; qy += v.y * v.y;
  }
  ss[w][lane * 2] = sx; ss[w][lane * 2 + 1] = sy;
  sq[w][lane * 2] = qx; sq[w][lane * 2 + 1] = qy;
  __syncthreads();
  if (t < 128){
    float tot = ss[0][t] + ss[1][t] + ss[2][t] + ss[3][t];
    atomicAdd(&out[t], tot);
  } else {
    int c = t - 128;
    float tot = sq[0][c] + sq[1][c] + sq[2][c] + sq[3][c];
    atomicAdd(&out[128 + c], tot);
  }
}

// H = (X - m) * rsqrt(var+eps) + BNB   (writes f32 + bf16 copy)
__global__ void k_bnx(const float* __restrict__ X, const float* __restrict__ stats,
                      float* __restrict__ H, ushort4* __restrict__ H16, int n){
  size_t tot4 = (size_t)n * (NF / 4);
  float inv_n = 1.f / (float)n;
  for (size_t i = blockIdx.x * (size_t)blockDim.x + threadIdx.x; i < tot4;
       i += (size_t)gridDim.x * blockDim.x){
    float4 v = ((const float4*)X)[i];
    int c0 = (int)((i * 4) % NF);
    float* vv = (float*)&v;
    #pragma unroll
    for (int j = 0; j < 4; ++j){
      float m = stats[c0 + j] * inv_n;
      float var = stats[128 + c0 + j] * inv_n - m * m;
      vv[j] = (vv[j] - m) * rsqrtf(var + EPS) + BNB;
    }
    ((float4*)H)[i] = v;
    ushort4 b;
    b.x = f2b(v.x); b.y = f2b(v.y); b.z = f2b(v.z); b.w = f2b(v.w);
    H16[i] = b;
  }
}

// H = relu( (Xg - m)*inv + BNB + H )   (writes f32 + bf16 copy)
__global__ void k_bnres(const float* __restrict__ Xg, const float* __restrict__ stats,
                        float* __restrict__ H, ushort4* __restrict__ H16, int n){
  size_t tot4 = (size_t)n * (NF / 4);
  float inv_n = 1.f / (float)n;
  for (size_t i = blockIdx.x * (size_t)blockDim.x + threadIdx.x; i < tot4;
       i += (size_t)gridDim.x * blockDim.x){
    float4 v = ((const float4*)Xg)[i];
    float4 hc = ((const float4*)H)[i];
    int c0 = (int)((i * 4) % NF);
    float* vv = (float*)&v;
    float* hh = (float*)&hc;
    #pragma unroll
    for (int j = 0; j < 4; ++j){
      float m = stats[c0 + j] * inv_n;
      float var = stats[128 + c0 + j] * inv_n - m * m;
      float z = (vv[j] - m) * rsqrtf(var + EPS) + BNB + hh[j];
      hh[j] = fmaxf(z, 0.f);
    }
    ((float4*)H)[i] = hc;
    ushort4 b;
    b.x = f2b(hc.x); b.y = f2b(hc.y); b.z = f2b(hc.z); b.w = f2b(hc.w);
    H16[i] = b;
  }
}

__global__ void k_relu(const float* __restrict__ X, float* __restrict__ H,
                       ushort4* __restrict__ H16, size_t tot4){
  for (size_t i = blockIdx.x * (size_t)blockDim.x + threadIdx.x; i < tot4;
       i += (size_t)gridDim.x * blockDim.x){
    float4 v = ((const float4*)X)[i];
    v.x = fmaxf(v.x, 0.f); v.y = fmaxf(v.y, 0.f);
    v.z = fmaxf(v.z, 0.f); v.w = fmaxf(v.w, 0.f);
    ((float4*)H)[i] = v;
    ushort4 b;
    b.x = f2b(v.x); b.y = f2b(v.y); b.z = f2b(v.z); b.w = f2b(v.w);
    H16[i] = b;
  }
}

// ---------------- weight convert + transpose: Wt[l][n][k] bf16 ----------------
__global__ void k_cvtw(const float* __restrict__ W, unsigned short* __restrict__ Wt){
  int i = blockIdx.x * blockDim.x + threadIdx.x;   // 4*128*128
  int l = i >> 14, rem = i & 16383;
  int k = rem >> 7, nn = rem & 127;
  Wt[(l << 14) + nn * 128 + k] = f2b(W[i]);
}

// ---------------- MFMA GEMM + fused att-vec epilogue ----------------
__global__ __launch_bounds__(256) void k_gemm(const unsigned short* __restrict__ X,
                                              const unsigned short* __restrict__ Wt,
                                              unsigned short* __restrict__ Y,
                                              const float* __restrict__ asrc,
                                              const float* __restrict__ adst,
                                              float* __restrict__ a_s,
                                              float* __restrict__ a_d, int n){
  __shared__ unsigned short sX[64 * 128];    // 16 KB, XOR-swizzled 16B units
  __shared__ unsigned short sW[128 * 128];   // 32 KB, [n][k], XOR-swizzled
  int t = threadIdx.x;
  int rbase = blockIdx.x * 64;
  #pragma unroll
  for (int i = 0; i < 8; ++i){               // stage Wt: 2048 uint4
    int idx = t + 256 * i;
    int rn = idx >> 4, c16 = idx & 15;
    uint4 v = ((const uint4*)Wt)[idx];
    *(uint4*)&sW[rn * 128 + ((c16 ^ (rn & 7)) << 3)] = v;
  }
  #pragma unroll
  for (int i = 0; i < 4; ++i){               // stage X: 1024 uint4
    int idx = t + 256 * i;
    int r = idx >> 4, c16 = idx & 15;
    int gr = rbase + r;
    uint4 v = (gr < n) ? ((const uint4*)(X + (size_t)gr * NF))[c16] : make_uint4(0, 0, 0, 0);
    *(uint4*)&sX[r * 128 + ((c16 ^ (r & 7)) << 3)] = v;
  }
  __syncthreads();
  int lane = t & 63, w = t >> 6;
  int lrow = w * 16 + (lane & 15);
  int khi = lane >> 4;                       // 0..3
  bf16x8 a[4];
  #pragma unroll
  for (int ks = 0; ks < 4; ++ks){
    int c16 = ks * 4 + khi;
    a[ks] = *(const bf16x8*)&sX[lrow * 128 + ((c16 ^ (lrow & 7)) << 3)];
  }
  f32x4 acc[8];
  #pragma unroll
  for (int nt = 0; nt < 8; ++nt){
    f32x4 z = {0.f, 0.f, 0.f, 0.f};
    acc[nt] = z;
    int nrow = nt * 16 + (lane & 15);
    #pragma unroll
    for (int ks = 0; ks < 4; ++ks){
      int c16 = ks * 4 + khi;
      bf16x8 b = *(const bf16x8*)&sW[nrow * 128 + ((c16 ^ (nrow & 7)) << 3)];
      acc[nt] = __builtin_amdgcn_mfma_f32_16x16x32_bf16(a[ks], b, acc[nt], 0, 0, 0);
    }
  }
  // stage D (bf16, swizzled) back into sX
  #pragma unroll
  for (int nt = 0; nt < 8; ++nt){
    #pragma unroll
    for (int i = 0; i < 4; ++i){
      int r = w * 16 + (khi << 2) + i;
      int c = nt * 16 + (lane & 15);
      int csw = c ^ ((r & 7) << 3);
      sX[r * 128 + csw] = f2b(acc[nt][i]);
    }
  }
  __syncthreads();
  // coalesced Y store
  #pragma unroll
  for (int i = 0; i < 4; ++i){
    int idx = t + 256 * i;
    int r = idx >> 4, c16 = idx & 15;
    int gr = rbase + r;
    if (gr < n)
      ((uint4*)(Y + (size_t)gr * NF))[c16] = *(const uint4*)&sX[r * 128 + ((c16 ^ (r & 7)) << 3)];
  }
  // fused att-vec: thread -> (row = t>>2, head = t&3); dot 32 elems from LDS
  int r = t >> 2, hh = t & 3;
  int gr = rbase + r;
  if (gr < n){
    float ps = 0.f, pd = 0.f;
    #pragma unroll
    for (int j = 0; j < 16; ++j){
      int c = hh * 32 + j * 2;
      int u = (c >> 3) ^ (r & 7);
      unsigned v = *(const unsigned*)&sX[r * 128 + (u << 3) + (c & 7)];
      float vx = b2f_lo(v), vy = b2f_hi(v);
      ps += vx * asrc[c] + vy * asrc[c + 1];
      pd += vx * adst[c] + vy * adst[c + 1];
    }
    a_s[(size_t)gr * 4 + hh] = ps;
    a_d[(size_t)gr * 4 + hh] = pd;
  }
}

// ---------------- attention: shfl-broadcast softmax (no-max exp) + aggregate ----------------
// Lane l: head = l>>4, owns features [2l, 2l+1]. Per 16-edge slab, lane computes exp-weight
// for edge e0+(l&15); weights/srcs broadcast within the 16-lane head group via shfl.
__global__ __launch_bounds__(256) void k_attn(const unsigned short* __restrict__ Hm16,
                                              const float* __restrict__ a_s,
                                              const float* __restrict__ a_d,
                                              const int* __restrict__ off,
                                              const int* __restrict__ esrc,
                                              const float* __restrict__ bias,
                                              float* __restrict__ Y, int n){
  int t = threadIdx.x, lane = t & 63, w = t >> 6;
  int node = blockIdx.x * 4 + w;
  if (node >= n) return;
  node = __builtin_amdgcn_readfirstlane(node);
  int head = lane >> 4;
  int hbase = head << 4;
  float4 ad4 = ((const float4*)a_d)[node];
  float adh = sel4(ad4, head);
  int lo = off[node], hi = off[node + 1];
  lo = __builtin_amdgcn_readfirstlane(lo);
  hi = __builtin_amdgcn_readfirstlane(hi);
  int fo = lane * 2;
  float sum = 0.f, ax = 0.f, ay = 0.f;
  for (int e0 = lo; e0 < hi; e0 += 16){
    int ee = e0 + (lane & 15);
    int s = 0; float wgt = 0.f;
    if (ee < hi){
      s = esrc[ee];
      wgt = __expf(lrelu(a_s[(s << 2) + head] + adh));
    }
    sum += wgt;
    int cnt = hi - e0;                 // wave-uniform
    if (cnt >= 16){
      #pragma unroll
      for (int j = 0; j < 16; ++j){
        float wj = __shfl(wgt, hbase + j, 64);
        int   sj = __shfl(s,   hbase + j, 64);
        unsigned v = *(const unsigned*)(Hm16 + (size_t)sj * NF + fo);
        ax += wj * b2f_lo(v);
        ay += wj * b2f_hi(v);
      }
    } else {
      for (int j = 0; j < cnt; ++j){   // uniform bound -> no divergence
        float wj = __shfl(wgt, hbase + j, 64);
        int   sj = __shfl(s,   hbase + j, 64);
        unsigned v = *(const unsigned*)(Hm16 + (size_t)sj * NF + fo);
        ax += wj * b2f_lo(v);
        ay += wj * b2f_hi(v);
      }
    }
  }
  // reduce sum within the 16-lane head group
  #pragma unroll
  for (int d = 1; d < 16; d <<= 1) sum += __shfl_xor(sum, d, 64);
  float inv = 1.f / (sum + 1e-16f);
  float2 b = *(const float2*)(bias + fo);
  float2 r;
  r.x = ax * inv + b.x;
  r.y = ay * inv + b.y;
  *(float2*)(Y + (size_t)node * NF + fo) = r;
}

// ---------------- pooling: batch is sorted; one block per graph ----------------
__global__ __launch_bounds__(256) void k_pool(const float* __restrict__ H, const int* __restrict__ batch,
                                              float* __restrict__ g, int n){
  int gid = blockIdx.x;
  int t = threadIdx.x, lane = t & 63, w = t >> 6;
  int lo = 0, hi = n;
  while (lo < hi){ int mid = (lo + hi) >> 1; if (batch[mid] < gid) lo = mid + 1; else hi = mid; }
  int a = lo, b = n;
  while (a < b){ int mid = (a + b) >> 1; if (batch[mid] < gid + 1) a = mid + 1; else b = mid; }
  float sx = 0.f, sy = 0.f;
  for (int r = lo + w; r < a; r += 4){
    float2 v = *(const float2*)(H + (size_t)r * NF + lane * 2);
    sx += v.x; sy += v.y;
  }
  __shared__ float ss[4][128];
  ss[w][lane * 2] = sx; ss[w][lane * 2 + 1] = sy;
  __syncthreads();
  if (t < 128) g[(size_t)gid * NF + t] = ss[0][t] + ss[1][t] + ss[2][t] + ss[3][t];
}

// ---------------- head: BN -> fc+relu -> BN -> cls -> log_softmax (single block) ----------------
__global__ __launch_bounds__(1024) void k_head(const float* __restrict__ g, const float* __restrict__ fc_w,
                                               const float* __restrict__ fc_b, const float* __restrict__ cls_w,
                                               const float* __restrict__ cls_b, float* __restrict__ out){
  __shared__ float A[128 * 128];
  __shared__ float mbuf[128], ibuf[128];
  __shared__ float logits[256];
  int t = threadIdx.x;
  #pragma unroll
  for (int i = 0; i < 4; ++i)
    ((float4*)A)[t + 1024 * i] = ((const float4*)g)[t + 1024 * i];
  __syncthreads();
  if (t < 128){
    float s = 0.f, q = 0.f;
    for (int r = 0; r < 128; ++r){ float v = A[r * 128 + t]; s += v; q += v * v; }
    float m = s * (1.f / 128.f);
    float var = q * (1.f / 128.f) - m * m;
    mbuf[t] = m; ibuf[t] = rsqrtf(var + EPS);
  }
  __syncthreads();
  #pragma unroll
  for (int i = 0; i < 16; ++i){
    int idx = t + 1024 * i;
    int c = idx & 127;
    A[idx] = (A[idx] - mbuf[c]) * ibuf[c] + BNB;
  }
  __syncthreads();
  int c0 = (t & 31) * 4, r0 = (t >> 5) * 4;
  float o[4][4];
  float4 bb = *(const float4*)(fc_b + c0);
  #pragma unroll
  for (int i = 0; i < 4; ++i){ o[i][0] = bb.x; o[i][1] = bb.y; o[i][2] = bb.z; o[i][3] = bb.w; }
  for (int k = 0; k < 128; ++k){
    float4 wv = *(const float4*)(fc_w + (size_t)k * 128 + c0);
    #pragma unroll
    for (int i = 0; i < 4; ++i){
      float xs = A[(r0 + i) * 128 + k];
      o[i][0] += xs * wv.x; o[i][1] += xs * wv.y;
      o[i][2] += xs * wv.z; o[i][3] += xs * wv.w;
    }
  }
  __syncthreads();
  #pragma unroll
  for (int i = 0; i < 4; ++i)
    #pragma unroll
    for (int j = 0; j < 4; ++j)
      A[(r0 + i) * 128 + c0 + j] = fmaxf(o[i][j], 0.f);
  __syncthreads();
  if (t < 128){
    float s = 0.f, q = 0.f;
    for (int r = 0; r < 128; ++r){ float v = A[r * 128 + t]; s += v; q += v * v; }
    float m = s * (1.f / 128.f);
    float var = q * (1.f / 128.f) - m * m;
    mbuf[t] = m; ibuf[t] = rsqrtf(var + EPS);
  }
  __syncthreads();
  #pragma unroll
  for (int i = 0; i < 16; ++i){
    int idx = t + 1024 * i;
    int c = idx & 127;
    A[idx] = (A[idx] - mbuf[c]) * ibuf[c] + BNB;
  }
  __syncthreads();
  if (t < 256){
    int r = t >> 1, j = t & 1;
    float accv = cls_b[j];
    for (int k = 0; k < 128; ++k) accv += A[r * 128 + k] * cls_w[k * 2 + j];
    logits[t] = accv;
  }
  __syncthreads();
  if (t < 256){
    int r = t >> 1;
    float l0 = logits[r * 2], l1 = logits[r * 2 + 1];
    float mx = fmaxf(l0, l1);
    float lse = mx + logf(__expf(l0 - mx) + __expf(l1 - mx));
    out[t] = logits[t] - lse;
  }
}

extern "C" void kernel_launch(void* const* d_in, const int* in_sizes, int n_in,
                              void* d_out, int out_size, void* d_ws, size_t ws_size,
                              hipStream_t stream){
  const float* x        = (const float*)d_in[0];
  const int*   ei       = (const int*)d_in[1];
  const int*   batch    = (const int*)d_in[2];
  const float* gat_lin  = (const float*)d_in[3];
  const float* att_src  = (const float*)d_in[4];
  const float* att_dst  = (const float*)d_in[5];
  const float* gat_bias = (const float*)d_in[6];
  const float* fc_w     = (const float*)d_in[7];
  const float* fc_b     = (const float*)d_in[8];
  const float* cls_w    = (const float*)d_in[9];
  const float* cls_b    = (const float*)d_in[10];
  float* out = (float*)d_out;
  (void)n_in; (void)out_size; (void)ws_size;

  int N = in_sizes[0] / NF;
  int E = in_sizes[1] / 2;
  int total = E + N;
  int nb = cdiv(N, 256);     // scan blocks == coarse buckets (196 for N=50000)
  int nbkt = nb;

  char* p = (char*)d_ws;
  auto alloc = [&](size_t bytes) -> char* {
    char* r = p;
    p += (bytes + 255) & ~(size_t)255;
    return r;
  };
  int*   deg     = (int*)alloc((size_t)N * 4);
  int*   off     = (int*)alloc((size_t)(N + 1) * 4);
  int*   bsum    = (int*)alloc((size_t)nb * 4);
  int*   bcnt    = (int*)alloc((size_t)nbkt * 4);
  int*   boff    = (int*)alloc((size_t)(nbkt + 1) * 4);
  int*   bcursor = (int*)alloc((size_t)nbkt * 4);
  unsigned* ebuf = (unsigned*)alloc((size_t)total * 4);
  int*   esrc    = (int*)alloc((size_t)total * 4);
  float* stats   = (float*)alloc(4 * 256 * 4);
  float* hbuf    = (float*)alloc((size_t)N * NF * 4);
  unsigned short* hbuf16 = (unsigned short*)alloc((size_t)N * NF * 2);
  unsigned short* tmp16  = (unsigned short*)alloc((size_t)N * NF * 2);
  unsigned short* wbuf16 = (unsigned short*)alloc((size_t)4 * NF * NF * 2);
  float* gout    = (float*)alloc((size_t)N * NF * 4);
  float* a_s     = (float*)alloc((size_t)N * 4 * 4);
  float* a_d     = (float*)alloc((size_t)N * 4 * 4);
  float* gpool   = (float*)alloc(128 * NF * 4);

  // CSR build: chunked-reservation bucket sort
  k_zero<<<8, 256, 0, stream>>>(stats, bcnt, nbkt);
  k_bhist<<<256, 256, 0, stream>>>(ei, E, N, bcnt, nbkt);
  k_bscan<<<1, 256, 0, stream>>>(bcnt, boff, bcursor, nbkt);
  k_bscatter2<<<cdiv(total, CHUNK), 256, 0, stream>>>(ei, E, N, bcursor, ebuf, nbkt);
  k_deg<<<nbkt, 256, 0, stream>>>(ebuf, boff, deg, N);
  k_scan1<<<nb, 256, 0, stream>>>(deg, bsum, N);
  k_scan2<<<1, 256, 0, stream>>>(bsum, nb);
  k_scan3<<<nb, 256, 0, stream>>>(deg, bsum, off, N);
  k_fine<<<nbkt, 256, 0, stream>>>(ebuf, boff, off, esrc, N);
  k_cvtw<<<256, 256, 0, stream>>>(gat_lin, wbuf16);

  k_colstats<<<256, 256, 0, stream>>>(x, N, stats);
  k_bnx<<<1024, 256, 0, stream>>>(x, stats, hbuf, (ushort4*)hbuf16, N);

  for (int L = 0; L < 4; ++L){
    k_gemm<<<cdiv(N, 64), 256, 0, stream>>>(hbuf16, wbuf16 + (size_t)L * NF * NF, tmp16,
                                            att_src + (size_t)L * NF, att_dst + (size_t)L * NF,
                                            a_s, a_d, N);
    k_attn<<<cdiv(N, 4), 256, 0, stream>>>(tmp16, a_s, a_d, off, esrc,
                                           gat_bias + (size_t)L * NF, gout, N);
    if (L == 0){
      k_relu<<<1024, 256, 0, stream>>>(gout, hbuf, (ushort4*)hbuf16, (size_t)N * (NF / 4));
    } else {
      k_colstats<<<256, 256, 0, stream>>>(gout, N, stats + L * 256);
      k_bnres<<<1024, 256, 0, stream>>>(gout, stats + L * 256, hbuf, (ushort4*)hbuf16, N);
    }
  }

  k_pool<<<128, 256, 0, stream>>>(hbuf, batch, gpool, N);
  k_head<<<1, 1024, 0, stream>>>(gpool, fc_w, fc_b, cls_w, cls_b, out);
}

// Round 9
// 501.557 us; speedup vs baseline: 1.0282x; 1.0282x over previous
//
#include <hip/hip_runtime.h>
#include <math.h>

#define NF 128
#define EPS 1e-5f
#define BNB 1e-4f
#define CHUNK 8192

static inline int cdiv(int a, int b){ return (a + b - 1) / b; }

typedef __attribute__((ext_vector_type(8))) short bf16x8;
typedef __attribute__((ext_vector_type(4))) float f32x4;

__device__ __forceinline__ float lrelu(float x){ return x > 0.f ? x : 0.2f * x; }

// f32 -> bf16 round-to-nearest-even (finite inputs)
__device__ __forceinline__ unsigned short f2b(float f){
  unsigned u = __float_as_uint(f);
  u += 0x7fffu + ((u >> 16) & 1u);
  return (unsigned short)(u >> 16);
}
__device__ __forceinline__ float b2f_lo(unsigned v){ return __uint_as_float(v << 16); }
__device__ __forceinline__ float b2f_hi(unsigned v){ return __uint_as_float(v & 0xffff0000u); }

// ---------------- CSR build: chunked-reservation bucket sort ----------------
__global__ void k_zero(float* stats, int* bcnt, int nbkt){
  int i = blockIdx.x * blockDim.x + threadIdx.x;
  if (i < 1024) stats[i] = 0.f;
  if (i < nbkt) bcnt[i] = 0;
}

// coarse histogram over buckets (dst>>8), LDS-aggregated
__global__ __launch_bounds__(256) void k_bhist(const int* __restrict__ ei, int E, int n,
                                               int* __restrict__ bcnt, int nbkt){
  __shared__ int h[256];
  h[threadIdx.x] = 0;
  __syncthreads();
  int total = E + n;
  for (int i = blockIdx.x * 256 + threadIdx.x; i < total; i += gridDim.x * 256){
    int d = (i < E) ? ei[E + i] : (i - E);
    atomicAdd(&h[d >> 8], 1);
  }
  __syncthreads();
  if (threadIdx.x < nbkt && h[threadIdx.x]) atomicAdd(&bcnt[threadIdx.x], h[threadIdx.x]);
}

// 1-block exclusive scan over nbkt (<=256) bucket counts -> boff, bcursor
__global__ __launch_bounds__(256) void k_bscan(const int* __restrict__ bcnt, int* __restrict__ boff,
                                               int* __restrict__ bcursor, int nb){
  int t = threadIdx.x;
  int v = (t < nb) ? bcnt[t] : 0;
  int lane = t & 63, w = t >> 6;
  int x = v;
  #pragma unroll
  for (int d = 1; d < 64; d <<= 1){
    int y = __shfl_up(x, d, 64);
    if (lane >= d) x += y;
  }
  __shared__ int wt[4], wex[4];
  if (lane == 63) wt[w] = x;
  __syncthreads();
  if (t == 0){ int r = 0; for (int i = 0; i < 4; ++i){ wex[i] = r; r += wt[i]; } }
  __syncthreads();
  int ex = wex[w] + x - v;
  if (t < nb){ boff[t] = ex; bcursor[t] = ex; }
  if (t == nb - 1) boff[nb] = ex + v;
}

// chunked scatter: per block, LDS hist -> one reservation atomic per bucket -> ranked write.
__global__ __launch_bounds__(256) void k_bscatter2(const int* __restrict__ ei, int E, int n,
                                                   int* __restrict__ bcursor,
                                                   unsigned* __restrict__ ebuf, int nbkt){
  __shared__ int h[256], base[256];
  int t = threadIdx.x;
  int total = E + n;
  int lo = blockIdx.x * CHUNK;
  int hi = min(lo + CHUNK, total);
  h[t] = 0;
  __syncthreads();
  for (int i = lo + t; i < hi; i += 256){
    int d = (i < E) ? ei[E + i] : (i - E);
    atomicAdd(&h[d >> 8], 1);
  }
  __syncthreads();
  int cnt = h[t];
  if (t < nbkt && cnt > 0) base[t] = atomicAdd(&bcursor[t], cnt);
  __syncthreads();
  h[t] = 0;
  __syncthreads();
  for (int i = lo + t; i < hi; i += 256){
    int s, d;
    if (i < E){ s = ei[i]; d = ei[E + i]; }
    else { s = i - E; d = s; }
    int b = d >> 8;
    int r = atomicAdd(&h[b], 1);
    ebuf[base[b] + r] = ((unsigned)s << 8) | (unsigned)(d & 255);
  }
}

// per-bucket degree via LDS histogram (no global atomics; includes self-loops)
__global__ __launch_bounds__(256) void k_deg(const unsigned* __restrict__ ebuf,
                                             const int* __restrict__ boff,
                                             int* __restrict__ deg, int n){
  __shared__ int h[256];
  int t = threadIdx.x, b = blockIdx.x;
  h[t] = 0;
  __syncthreads();
  int lo = boff[b], hi = boff[b + 1];
  for (int i = lo + t; i < hi; i += 256) atomicAdd(&h[ebuf[i] & 255u], 1);
  __syncthreads();
  int node = b * 256 + t;
  if (node < n) deg[node] = h[t];
}

// ---- 3-phase multi-block exclusive scan over deg -> off ----
__global__ __launch_bounds__(256) void k_scan1(const int* __restrict__ deg, int* __restrict__ bsum, int n){
  int i = blockIdx.x * 256 + threadIdx.x;
  int v = (i < n) ? deg[i] : 0;
  int lane = threadIdx.x & 63, w = threadIdx.x >> 6;
  int s = v;
  #pragma unroll
  for (int d = 1; d < 64; d <<= 1) s += __shfl_xor(s, d, 64);
  __shared__ int ws_[4];
  if (lane == 0) ws_[w] = s;
  __syncthreads();
  if (threadIdx.x == 0) bsum[blockIdx.x] = ws_[0] + ws_[1] + ws_[2] + ws_[3];
}

__global__ __launch_bounds__(256) void k_scan2(int* __restrict__ bsum, int nb){
  int t = threadIdx.x;
  int v = (t < nb) ? bsum[t] : 0;
  int lane = t & 63, w = t >> 6;
  int x = v;
  #pragma unroll
  for (int d = 1; d < 64; d <<= 1){
    int y = __shfl_up(x, d, 64);
    if (lane >= d) x += y;
  }
  __shared__ int wt[4], wex[4];
  if (lane == 63) wt[w] = x;
  __syncthreads();
  if (t == 0){ int r = 0; for (int i = 0; i < 4; ++i){ wex[i] = r; r += wt[i]; } }
  __syncthreads();
  if (t < nb) bsum[t] = wex[w] + x - v;   // exclusive
}

__global__ __launch_bounds__(256) void k_scan3(const int* __restrict__ deg, const int* __restrict__ bsum,
                                               int* __restrict__ off, int n){
  int i = blockIdx.x * 256 + threadIdx.x;
  int v = (i < n) ? deg[i] : 0;
  int lane = threadIdx.x & 63, w = threadIdx.x >> 6;
  int x = v;
  #pragma unroll
  for (int d = 1; d < 64; d <<= 1){
    int y = __shfl_up(x, d, 64);
    if (lane >= d) x += y;
  }
  __shared__ int wt[4], wex[4];
  if (lane == 63) wt[w] = x;
  __syncthreads();
  if (threadIdx.x == 0){ int r = 0; for (int j = 0; j < 4; ++j){ wex[j] = r; r += wt[j]; } }
  __syncthreads();
  int excl = bsum[blockIdx.x] + wex[w] + (x - v);
  if (i < n) off[i] = excl;
  if (i == n - 1) off[n] = excl + v;
}

// per-bucket fine scatter: rank via LDS atomics; writes esrc + edst (CSR order)
__global__ __launch_bounds__(256) void k_fine(const unsigned* __restrict__ ebuf,
                                              const int* __restrict__ boff,
                                              const int* __restrict__ off,
                                              int* __restrict__ esrc,
                                              int* __restrict__ edst, int n){
  __shared__ int h[256];
  int t = threadIdx.x, b = blockIdx.x;
  h[t] = 0;
  __syncthreads();
  int lo = boff[b], hi = boff[b + 1];
  int base = b * 256;
  for (int i = lo + t; i < hi; i += 256){
    unsigned pk = ebuf[i];
    int ld = (int)(pk & 255u);
    int s  = (int)(pk >> 8);
    int r = atomicAdd(&h[ld], 1);
    int pos = off[base + ld] + r;
    esrc[pos] = s;
    edst[pos] = base + ld;
  }
}

// ---------------- BN column stats (sum, sumsq into stats[0..127], stats[128..255]) ----------------
__global__ __launch_bounds__(256) void k_colstats(const float* __restrict__ X, int n, float* __restrict__ out){
  __shared__ float ss[4][128], sq[4][128];
  int t = threadIdx.x, lane = t & 63, w = t >> 6;
  float sx = 0.f, sy = 0.f, qx = 0.f, qy = 0.f;
  for (int r = blockIdx.x * 4 + w; r < n; r += gridDim.x * 4){
    float2 v = *(const float2*)(X + (size_t)r * NF + lane * 2);
    sx += v.x; sy += v.y; qx += v.x * v.x; qy += v.y * v.y;
  }
  ss[w][lane * 2] = sx; ss[w][lane * 2 + 1] = sy;
  sq[w][lane * 2] = qx; sq[w][lane * 2 + 1] = qy;
  __syncthreads();
  if (t < 128){
    float tot = ss[0][t] + ss[1][t] + ss[2][t] + ss[3][t];
    atomicAdd(&out[t], tot);
  } else {
    int c = t - 128;
    float tot = sq[0][c] + sq[1][c] + sq[2][c] + sq[3][c];
    atomicAdd(&out[128 + c], tot);
  }
}

// H = (X - m) * rsqrt(var+eps) + BNB   (writes f32 + bf16 copy)
__global__ void k_bnx(const float* __restrict__ X, const float* __restrict__ stats,
                      float* __restrict__ H, ushort4* __restrict__ H16, int n){
  size_t tot4 = (size_t)n * (NF / 4);
  float inv_n = 1.f / (float)n;
  for (size_t i = blockIdx.x * (size_t)blockDim.x + threadIdx.x; i < tot4;
       i += (size_t)gridDim.x * blockDim.x){
    float4 v = ((const float4*)X)[i];
    int c0 = (int)((i * 4) % NF);
    float* vv = (float*)&v;
    #pragma unroll
    for (int j = 0; j < 4; ++j){
      float m = stats[c0 + j] * inv_n;
      float var = stats[128 + c0 + j] * inv_n - m * m;
      vv[j] = (vv[j] - m) * rsqrtf(var + EPS) + BNB;
    }
    ((float4*)H)[i] = v;
    ushort4 b;
    b.x = f2b(v.x); b.y = f2b(v.y); b.z = f2b(v.z); b.w = f2b(v.w);
    H16[i] = b;
  }
}

// H = relu( (Xg - m)*inv + BNB + H )   (writes f32 + bf16 copy)
__global__ void k_bnres(const float* __restrict__ Xg, const float* __restrict__ stats,
                        float* __restrict__ H, ushort4* __restrict__ H16, int n){
  size_t tot4 = (size_t)n * (NF / 4);
  float inv_n = 1.f / (float)n;
  for (size_t i = blockIdx.x * (size_t)blockDim.x + threadIdx.x; i < tot4;
       i += (size_t)gridDim.x * blockDim.x){
    float4 v = ((const float4*)Xg)[i];
    float4 hc = ((const float4*)H)[i];
    int c0 = (int)((i * 4) % NF);
    float* vv = (float*)&v;
    float* hh = (float*)&hc;
    #pragma unroll
    for (int j = 0; j < 4; ++j){
      float m = stats[c0 + j] * inv_n;
      float var = stats[128 + c0 + j] * inv_n - m * m;
      float z = (vv[j] - m) * rsqrtf(var + EPS) + BNB + hh[j];
      hh[j] = fmaxf(z, 0.f);
    }
    ((float4*)H)[i] = hc;
    ushort4 b;
    b.x = f2b(hc.x); b.y = f2b(hc.y); b.z = f2b(hc.z); b.w = f2b(hc.w);
    H16[i] = b;
  }
}

__global__ void k_relu(const float* __restrict__ X, float* __restrict__ H,
                       ushort4* __restrict__ H16, size_t tot4){
  for (size_t i = blockIdx.x * (size_t)blockDim.x + threadIdx.x; i < tot4;
       i += (size_t)gridDim.x * blockDim.x){
    float4 v = ((const float4*)X)[i];
    v.x = fmaxf(v.x, 0.f); v.y = fmaxf(v.y, 0.f);
    v.z = fmaxf(v.z, 0.f); v.w = fmaxf(v.w, 0.f);
    ((float4*)H)[i] = v;
    ushort4 b;
    b.x = f2b(v.x); b.y = f2b(v.y); b.z = f2b(v.z); b.w = f2b(v.w);
    H16[i] = b;
  }
}

// ---------------- weight convert + transpose: Wt[l][n][k] bf16 ----------------
__global__ void k_cvtw(const float* __restrict__ W, unsigned short* __restrict__ Wt){
  int i = blockIdx.x * blockDim.x + threadIdx.x;   // 4*128*128
  int l = i >> 14, rem = i & 16383;
  int k = rem >> 7, nn = rem & 127;
  Wt[(l << 14) + nn * 128 + k] = f2b(W[i]);
}

// ---------------- MFMA GEMM + fused att-vec epilogue ----------------
__global__ __launch_bounds__(256) void k_gemm(const unsigned short* __restrict__ X,
                                              const unsigned short* __restrict__ Wt,
                                              unsigned short* __restrict__ Y,
                                              const float* __restrict__ asrc,
                                              const float* __restrict__ adst,
                                              float* __restrict__ a_s,
                                              float* __restrict__ a_d, int n){
  __shared__ unsigned short sX[64 * 128];    // 16 KB, XOR-swizzled 16B units
  __shared__ unsigned short sW[128 * 128];   // 32 KB, [n][k], XOR-swizzled
  int t = threadIdx.x;
  int rbase = blockIdx.x * 64;
  #pragma unroll
  for (int i = 0; i < 8; ++i){               // stage Wt: 2048 uint4
    int idx = t + 256 * i;
    int rn = idx >> 4, c16 = idx & 15;
    uint4 v = ((const uint4*)Wt)[idx];
    *(uint4*)&sW[rn * 128 + ((c16 ^ (rn & 7)) << 3)] = v;
  }
  #pragma unroll
  for (int i = 0; i < 4; ++i){               // stage X: 1024 uint4
    int idx = t + 256 * i;
    int r = idx >> 4, c16 = idx & 15;
    int gr = rbase + r;
    uint4 v = (gr < n) ? ((const uint4*)(X + (size_t)gr * NF))[c16] : make_uint4(0, 0, 0, 0);
    *(uint4*)&sX[r * 128 + ((c16 ^ (r & 7)) << 3)] = v;
  }
  __syncthreads();
  int lane = t & 63, w = t >> 6;
  int lrow = w * 16 + (lane & 15);
  int khi = lane >> 4;                       // 0..3
  bf16x8 a[4];
  #pragma unroll
  for (int ks = 0; ks < 4; ++ks){
    int c16 = ks * 4 + khi;
    a[ks] = *(const bf16x8*)&sX[lrow * 128 + ((c16 ^ (lrow & 7)) << 3)];
  }
  f32x4 acc[8];
  #pragma unroll
  for (int nt = 0; nt < 8; ++nt){
    f32x4 z = {0.f, 0.f, 0.f, 0.f};
    acc[nt] = z;
    int nrow = nt * 16 + (lane & 15);
    #pragma unroll
    for (int ks = 0; ks < 4; ++ks){
      int c16 = ks * 4 + khi;
      bf16x8 b = *(const bf16x8*)&sW[nrow * 128 + ((c16 ^ (nrow & 7)) << 3)];
      acc[nt] = __builtin_amdgcn_mfma_f32_16x16x32_bf16(a[ks], b, acc[nt], 0, 0, 0);
    }
  }
  // stage D (bf16, swizzled) back into sX
  #pragma unroll
  for (int nt = 0; nt < 8; ++nt){
    #pragma unroll
    for (int i = 0; i < 4; ++i){
      int r = w * 16 + (khi << 2) + i;
      int c = nt * 16 + (lane & 15);
      int csw = c ^ ((r & 7) << 3);
      sX[r * 128 + csw] = f2b(acc[nt][i]);
    }
  }
  __syncthreads();
  // coalesced Y store
  #pragma unroll
  for (int i = 0; i < 4; ++i){
    int idx = t + 256 * i;
    int r = idx >> 4, c16 = idx & 15;
    int gr = rbase + r;
    if (gr < n)
      ((uint4*)(Y + (size_t)gr * NF))[c16] = *(const uint4*)&sX[r * 128 + ((c16 ^ (r & 7)) << 3)];
  }
  // fused att-vec: thread -> (row = t>>2, head = t&3); dot 32 elems from LDS
  int r = t >> 2, hh = t & 3;
  int gr = rbase + r;
  if (gr < n){
    float ps = 0.f, pd = 0.f;
    #pragma unroll
    for (int j = 0; j < 16; ++j){
      int c = hh * 32 + j * 2;
      int u = (c >> 3) ^ (r & 7);
      unsigned v = *(const unsigned*)&sX[r * 128 + (u << 3) + (c & 7)];
      float vx = b2f_lo(v), vy = b2f_hi(v);
      ps += vx * asrc[c] + vy * asrc[c + 1];
      pd += vx * adst[c] + vy * adst[c + 1];
    }
    a_s[(size_t)gr * 4 + hh] = ps;
    a_d[(size_t)gr * 4 + hh] = pd;
  }
}

// ---------------- per-edge exp-weights, SoA by head: ew[h*total + e] ----------------
__global__ void k_edgew(const int* __restrict__ esrc, const int* __restrict__ edst,
                        const float4* __restrict__ a_s, const float4* __restrict__ a_d,
                        float* __restrict__ ew, int total){
  int e = blockIdx.x * blockDim.x + threadIdx.x;
  if (e >= total) return;
  float4 as = a_s[esrc[e]];
  float4 ad = a_d[edst[e]];
  ew[e]             = __expf(lrelu(as.x + ad.x));
  ew[total + e]     = __expf(lrelu(as.y + ad.y));
  ew[2 * total + e] = __expf(lrelu(as.z + ad.z));
  ew[3 * total + e] = __expf(lrelu(as.w + ad.w));
}

// ---------------- attention: precomputed exp-weights, unroll-8 gather + accumulate ----------------
__global__ __launch_bounds__(256) void k_attn(const unsigned short* __restrict__ Hm16,
                                              const float* __restrict__ ew,
                                              const int* __restrict__ off,
                                              const int* __restrict__ esrc,
                                              const float* __restrict__ bias,
                                              float* __restrict__ Y, int n, int estride){
  int t = threadIdx.x, lane = t & 63, w = t >> 6;
  int node = blockIdx.x * 4 + w;
  if (node >= n) return;
  node = __builtin_amdgcn_readfirstlane(node);
  int head = lane >> 4;
  const float* ep = ew + (size_t)head * estride;
  int lo = off[node], hi = off[node + 1];
  lo = __builtin_amdgcn_readfirstlane(lo);
  hi = __builtin_amdgcn_readfirstlane(hi);
  int fo = lane * 2;
  float sum = 0.f, ax = 0.f, ay = 0.f;
  for (int e = lo; e < hi; e += 8){
    int ei[8]; int si[8]; float wi[8]; unsigned vi[8];
    #pragma unroll
    for (int k = 0; k < 8; ++k) ei[k] = min(e + k, hi - 1);
    #pragma unroll
    for (int k = 0; k < 8; ++k) si[k] = esrc[ei[k]];
    #pragma unroll
    for (int k = 0; k < 8; ++k) wi[k] = ep[ei[k]];
    #pragma unroll
    for (int k = 0; k < 8; ++k) vi[k] = *(const unsigned*)(Hm16 + (size_t)si[k] * NF + fo);
    #pragma unroll
    for (int k = 0; k < 8; ++k){
      if (e + k >= hi) wi[k] = 0.f;    // clamped duplicates get weight 0
      sum += wi[k];
      ax += wi[k] * b2f_lo(vi[k]);
      ay += wi[k] * b2f_hi(vi[k]);
    }
  }
  float inv = 1.f / (sum + 1e-16f);
  float2 b = *(const float2*)(bias + fo);
  float2 r;
  r.x = ax * inv + b.x;
  r.y = ay * inv + b.y;
  *(float2*)(Y + (size_t)node * NF + fo) = r;
}

// ---------------- pooling: batch is sorted; one block per graph ----------------
__global__ __launch_bounds__(256) void k_pool(const float* __restrict__ H, const int* __restrict__ batch,
                                              float* __restrict__ g, int n){
  int gid = blockIdx.x;
  int t = threadIdx.x, lane = t & 63, w = t >> 6;
  int lo = 0, hi = n;
  while (lo < hi){ int mid = (lo + hi) >> 1; if (batch[mid] < gid) lo = mid + 1; else hi = mid; }
  int a = lo, b = n;
  while (a < b){ int mid = (a + b) >> 1; if (batch[mid] < gid + 1) a = mid + 1; else b = mid; }
  float sx = 0.f, sy = 0.f;
  for (int r = lo + w; r < a; r += 4){
    float2 v = *(const float2*)(H + (size_t)r * NF + lane * 2);
    sx += v.x; sy += v.y;
  }
  __shared__ float ss[4][128];
  ss[w][lane * 2] = sx; ss[w][lane * 2 + 1] = sy;
  __syncthreads();
  if (t < 128) g[(size_t)gid * NF + t] = ss[0][t] + ss[1][t] + ss[2][t] + ss[3][t];
}

// ---------------- head: BN -> fc+relu -> BN -> cls -> log_softmax (single block) ----------------
__global__ __launch_bounds__(1024) void k_head(const float* __restrict__ g, const float* __restrict__ fc_w,
                                               const float* __restrict__ fc_b, const float* __restrict__ cls_w,
                                               const float* __restrict__ cls_b, float* __restrict__ out){
  __shared__ float A[128 * 128];
  __shared__ float mbuf[128], ibuf[128];
  __shared__ float logits[256];
  int t = threadIdx.x;
  #pragma unroll
  for (int i = 0; i < 4; ++i)
    ((float4*)A)[t + 1024 * i] = ((const float4*)g)[t + 1024 * i];
  __syncthreads();
  if (t < 128){
    float s = 0.f, q = 0.f;
    for (int r = 0; r < 128; ++r){ float v = A[r * 128 + t]; s += v; q += v * v; }
    float m = s * (1.f / 128.f);
    float var = q * (1.f / 128.f) - m * m;
    mbuf[t] = m; ibuf[t] = rsqrtf(var + EPS);
  }
  __syncthreads();
  #pragma unroll
  for (int i = 0; i < 16; ++i){
    int idx = t + 1024 * i;
    int c = idx & 127;
    A[idx] = (A[idx] - mbuf[c]) * ibuf[c] + BNB;
  }
  __syncthreads();
  int c0 = (t & 31) * 4, r0 = (t >> 5) * 4;
  float o[4][4];
  float4 bb = *(const float4*)(fc_b + c0);
  #pragma unroll
  for (int i = 0; i < 4; ++i){ o[i][0] = bb.x; o[i][1] = bb.y; o[i][2] = bb.z; o[i][3] = bb.w; }
  for (int k = 0; k < 128; ++k){
    float4 wv = *(const float4*)(fc_w + (size_t)k * 128 + c0);
    #pragma unroll
    for (int i = 0; i < 4; ++i){
      float xs = A[(r0 + i) * 128 + k];
      o[i][0] += xs * wv.x; o[i][1] += xs * wv.y;
      o[i][2] += xs * wv.z; o[i][3] += xs * wv.w;
    }
  }
  __syncthreads();
  #pragma unroll
  for (int i = 0; i < 4; ++i)
    #pragma unroll
    for (int j = 0; j < 4; ++j)
      A[(r0 + i) * 128 + c0 + j] = fmaxf(o[i][j], 0.f);
  __syncthreads();
  if (t < 128){
    float s = 0.f, q = 0.f;
    for (int r = 0; r < 128; ++r){ float v = A[r * 128 + t]; s += v; q += v * v; }
    float m = s * (1.f / 128.f);
    float var = q * (1.f / 128.f) - m * m;
    mbuf[t] = m; ibuf[t] = rsqrtf(var + EPS);
  }
  __syncthreads();
  #pragma unroll
  for (int i = 0; i < 16; ++i){
    int idx = t + 1024 * i;
    int c = idx & 127;
    A[idx] = (A[idx] - mbuf[c]) * ibuf[c] + BNB;
  }
  __syncthreads();
  if (t < 256){
    int r = t >> 1, j = t & 1;
    float accv = cls_b[j];
    for (int k = 0; k < 128; ++k) accv += A[r * 128 + k] * cls_w[k * 2 + j];
    logits[t] = accv;
  }
  __syncthreads();
  if (t < 256){
    int r = t >> 1;
    float l0 = logits[r * 2], l1 = logits[r * 2 + 1];
    float mx = fmaxf(l0, l1);
    float lse = mx + logf(__expf(l0 - mx) + __expf(l1 - mx));
    out[t] = logits[t] - lse;
  }
}

extern "C" void kernel_launch(void* const* d_in, const int* in_sizes, int n_in,
                              void* d_out, int out_size, void* d_ws, size_t ws_size,
                              hipStream_t stream){
  const float* x        = (const float*)d_in[0];
  const int*   ei       = (const int*)d_in[1];
  const int*   batch    = (const int*)d_in[2];
  const float* gat_lin  = (const float*)d_in[3];
  const float* att_src  = (const float*)d_in[4];
  const float* att_dst  = (const float*)d_in[5];
  const float* gat_bias = (const float*)d_in[6];
  const float* fc_w     = (const float*)d_in[7];
  const float* fc_b     = (const float*)d_in[8];
  const float* cls_w    = (const float*)d_in[9];
  const float* cls_b    = (const float*)d_in[10];
  float* out = (float*)d_out;
  (void)n_in; (void)out_size; (void)ws_size;

  int N = in_sizes[0] / NF;
  int E = in_sizes[1] / 2;
  int total = E + N;
  int nb = cdiv(N, 256);     // scan blocks == coarse buckets (196 for N=50000)
  int nbkt = nb;

  char* p = (char*)d_ws;
  auto alloc = [&](size_t bytes) -> char* {
    char* r = p;
    p += (bytes + 255) & ~(size_t)255;
    return r;
  };
  int*   deg     = (int*)alloc((size_t)N * 4);
  int*   off     = (int*)alloc((size_t)(N + 1) * 4);
  int*   bsum    = (int*)alloc((size_t)nb * 4);
  int*   bcnt    = (int*)alloc((size_t)nbkt * 4);
  int*   boff    = (int*)alloc((size_t)(nbkt + 1) * 4);
  int*   bcursor = (int*)alloc((size_t)nbkt * 4);
  unsigned* ebuf = (unsigned*)alloc((size_t)total * 4);
  int*   esrc    = (int*)alloc((size_t)total * 4);
  int*   edst    = (int*)alloc((size_t)total * 4);
  float* ew      = (float*)alloc((size_t)total * 4 * 4);
  float* stats   = (float*)alloc(4 * 256 * 4);
  float* hbuf    = (float*)alloc((size_t)N * NF * 4);
  unsigned short* hbuf16 = (unsigned short*)alloc((size_t)N * NF * 2);
  unsigned short* tmp16  = (unsigned short*)alloc((size_t)N * NF * 2);
  unsigned short* wbuf16 = (unsigned short*)alloc((size_t)4 * NF * NF * 2);
  float* gout    = (float*)alloc((size_t)N * NF * 4);
  float* a_s     = (float*)alloc((size_t)N * 4 * 4);
  float* a_d     = (float*)alloc((size_t)N * 4 * 4);
  float* gpool   = (float*)alloc(128 * NF * 4);

  // CSR build: chunked-reservation bucket sort
  k_zero<<<8, 256, 0, stream>>>(stats, bcnt, nbkt);
  k_bhist<<<256, 256, 0, stream>>>(ei, E, N, bcnt, nbkt);
  k_bscan<<<1, 256, 0, stream>>>(bcnt, boff, bcursor, nbkt);
  k_bscatter2<<<cdiv(total, CHUNK), 256, 0, stream>>>(ei, E, N, bcursor, ebuf, nbkt);
  k_deg<<<nbkt, 256, 0, stream>>>(ebuf, boff, deg, N);
  k_scan1<<<nb, 256, 0, stream>>>(deg, bsum, N);
  k_scan2<<<1, 256, 0, stream>>>(bsum, nb);
  k_scan3<<<nb, 256, 0, stream>>>(deg, bsum, off, N);
  k_fine<<<nbkt, 256, 0, stream>>>(ebuf, boff, off, esrc, edst, N);
  k_cvtw<<<256, 256, 0, stream>>>(gat_lin, wbuf16);

  k_colstats<<<256, 256, 0, stream>>>(x, N, stats);
  k_bnx<<<1024, 256, 0, stream>>>(x, stats, hbuf, (ushort4*)hbuf16, N);

  for (int L = 0; L < 4; ++L){
    k_gemm<<<cdiv(N, 64), 256, 0, stream>>>(hbuf16, wbuf16 + (size_t)L * NF * NF, tmp16,
                                            att_src + (size_t)L * NF, att_dst + (size_t)L * NF,
                                            a_s, a_d, N);
    k_edgew<<<cdiv(total, 256), 256, 0, stream>>>(esrc, edst, (const float4*)a_s,
                                                  (const float4*)a_d, ew, total);
    k_attn<<<cdiv(N, 4), 256, 0, stream>>>(tmp16, ew, off, esrc,
                                           gat_bias + (size_t)L * NF, gout, N, total);
    if (L == 0){
      k_relu<<<1024, 256, 0, stream>>>(gout, hbuf, (ushort4*)hbuf16, (size_t)N * (NF / 4));
    } else {
      k_colstats<<<256, 256, 0, stream>>>(gout, N, stats + L * 256);
      k_bnres<<<1024, 256, 0, stream>>>(gout, stats + L * 256, hbuf, (ushort4*)hbuf16, N);
    }
  }

  k_pool<<<128, 256, 0, stream>>>(hbuf, batch, gpool, N);
  k_head<<<1, 1024, 0, stream>>>(gpool, fc_w, fc_b, cls_w, cls_b, out);
}

// Round 10
// 489.685 us; speedup vs baseline: 1.0531x; 1.0242x over previous
//
#include <hip/hip_runtime.h>
#include <math.h>

#define NF 128
#define EPS 1e-5f
#define BNB 1e-4f
#define CHUNK 8192

static inline int cdiv(int a, int b){ return (a + b - 1) / b; }

typedef __attribute__((ext_vector_type(8))) short bf16x8;
typedef __attribute__((ext_vector_type(4))) float f32x4;

__device__ __forceinline__ float lrelu(float x){ return x > 0.f ? x : 0.2f * x; }

// f32 -> bf16 round-to-nearest-even (finite inputs)
__device__ __forceinline__ unsigned short f2b(float f){
  unsigned u = __float_as_uint(f);
  u += 0x7fffu + ((u >> 16) & 1u);
  return (unsigned short)(u >> 16);
}
__device__ __forceinline__ float b2f_lo(unsigned v){ return __uint_as_float(v << 16); }
__device__ __forceinline__ float b2f_hi(unsigned v){ return __uint_as_float(v & 0xffff0000u); }

// ---------------- CSR build: chunked-reservation bucket sort ----------------
__global__ void k_zero(float* stats, int* bcnt, int nbkt, int statcount){
  int i = blockIdx.x * blockDim.x + threadIdx.x;
  if (i < statcount) stats[i] = 0.f;
  if (i < nbkt) bcnt[i] = 0;
}

// coarse histogram over buckets (dst>>8), LDS-aggregated
__global__ __launch_bounds__(256) void k_bhist(const int* __restrict__ ei, int E, int n,
                                               int* __restrict__ bcnt, int nbkt){
  __shared__ int h[256];
  h[threadIdx.x] = 0;
  __syncthreads();
  int total = E + n;
  for (int i = blockIdx.x * 256 + threadIdx.x; i < total; i += gridDim.x * 256){
    int d = (i < E) ? ei[E + i] : (i - E);
    atomicAdd(&h[d >> 8], 1);
  }
  __syncthreads();
  if (threadIdx.x < nbkt && h[threadIdx.x]) atomicAdd(&bcnt[threadIdx.x], h[threadIdx.x]);
}

// 1-block exclusive scan over nbkt (<=256) bucket counts -> boff, bcursor
__global__ __launch_bounds__(256) void k_bscan(const int* __restrict__ bcnt, int* __restrict__ boff,
                                               int* __restrict__ bcursor, int nb){
  int t = threadIdx.x;
  int v = (t < nb) ? bcnt[t] : 0;
  int lane = t & 63, w = t >> 6;
  int x = v;
  #pragma unroll
  for (int d = 1; d < 64; d <<= 1){
    int y = __shfl_up(x, d, 64);
    if (lane >= d) x += y;
  }
  __shared__ int wt[4], wex[4];
  if (lane == 63) wt[w] = x;
  __syncthreads();
  if (t == 0){ int r = 0; for (int i = 0; i < 4; ++i){ wex[i] = r; r += wt[i]; } }
  __syncthreads();
  int ex = wex[w] + x - v;
  if (t < nb){ boff[t] = ex; bcursor[t] = ex; }
  if (t == nb - 1) boff[nb] = ex + v;
}

// chunked scatter: per block, LDS hist -> one reservation atomic per bucket -> ranked write.
__global__ __launch_bounds__(256) void k_bscatter2(const int* __restrict__ ei, int E, int n,
                                                   int* __restrict__ bcursor,
                                                   unsigned* __restrict__ ebuf, int nbkt){
  __shared__ int h[256], base[256];
  int t = threadIdx.x;
  int total = E + n;
  int lo = blockIdx.x * CHUNK;
  int hi = min(lo + CHUNK, total);
  h[t] = 0;
  __syncthreads();
  for (int i = lo + t; i < hi; i += 256){
    int d = (i < E) ? ei[E + i] : (i - E);
    atomicAdd(&h[d >> 8], 1);
  }
  __syncthreads();
  int cnt = h[t];
  if (t < nbkt && cnt > 0) base[t] = atomicAdd(&bcursor[t], cnt);
  __syncthreads();
  h[t] = 0;
  __syncthreads();
  for (int i = lo + t; i < hi; i += 256){
    int s, d;
    if (i < E){ s = ei[i]; d = ei[E + i]; }
    else { s = i - E; d = s; }
    int b = d >> 8;
    int r = atomicAdd(&h[b], 1);
    ebuf[base[b] + r] = ((unsigned)s << 8) | (unsigned)(d & 255);
  }
}

// per-bucket degree via LDS histogram (no global atomics; includes self-loops)
__global__ __launch_bounds__(256) void k_deg(const unsigned* __restrict__ ebuf,
                                             const int* __restrict__ boff,
                                             int* __restrict__ deg, int n){
  __shared__ int h[256];
  int t = threadIdx.x, b = blockIdx.x;
  h[t] = 0;
  __syncthreads();
  int lo = boff[b], hi = boff[b + 1];
  for (int i = lo + t; i < hi; i += 256) atomicAdd(&h[ebuf[i] & 255u], 1);
  __syncthreads();
  int node = b * 256 + t;
  if (node < n) deg[node] = h[t];
}

// ---- 3-phase multi-block exclusive scan over deg -> off ----
__global__ __launch_bounds__(256) void k_scan1(const int* __restrict__ deg, int* __restrict__ bsum, int n){
  int i = blockIdx.x * 256 + threadIdx.x;
  int v = (i < n) ? deg[i] : 0;
  int lane = threadIdx.x & 63, w = threadIdx.x >> 6;
  int s = v;
  #pragma unroll
  for (int d = 1; d < 64; d <<= 1) s += __shfl_xor(s, d, 64);
  __shared__ int ws_[4];
  if (lane == 0) ws_[w] = s;
  __syncthreads();
  if (threadIdx.x == 0) bsum[blockIdx.x] = ws_[0] + ws_[1] + ws_[2] + ws_[3];
}

__global__ __launch_bounds__(256) void k_scan2(int* __restrict__ bsum, int nb){
  int t = threadIdx.x;
  int v = (t < nb) ? bsum[t] : 0;
  int lane = t & 63, w = t >> 6;
  int x = v;
  #pragma unroll
  for (int d = 1; d < 64; d <<= 1){
    int y = __shfl_up(x, d, 64);
    if (lane >= d) x += y;
  }
  __shared__ int wt[4], wex[4];
  if (lane == 63) wt[w] = x;
  __syncthreads();
  if (t == 0){ int r = 0; for (int i = 0; i < 4; ++i){ wex[i] = r; r += wt[i]; } }
  __syncthreads();
  if (t < nb) bsum[t] = wex[w] + x - v;   // exclusive
}

__global__ __launch_bounds__(256) void k_scan3(const int* __restrict__ deg, const int* __restrict__ bsum,
                                               int* __restrict__ off, int n){
  int i = blockIdx.x * 256 + threadIdx.x;
  int v = (i < n) ? deg[i] : 0;
  int lane = threadIdx.x & 63, w = threadIdx.x >> 6;
  int x = v;
  #pragma unroll
  for (int d = 1; d < 64; d <<= 1){
    int y = __shfl_up(x, d, 64);
    if (lane >= d) x += y;
  }
  __shared__ int wt[4], wex[4];
  if (lane == 63) wt[w] = x;
  __syncthreads();
  if (threadIdx.x == 0){ int r = 0; for (int j = 0; j < 4; ++j){ wex[j] = r; r += wt[j]; } }
  __syncthreads();
  int excl = bsum[blockIdx.x] + wex[w] + (x - v);
  if (i < n) off[i] = excl;
  if (i == n - 1) off[n] = excl + v;
}

// per-bucket fine scatter: rank via LDS atomics; writes esrc + edst (CSR order)
__global__ __launch_bounds__(256) void k_fine(const unsigned* __restrict__ ebuf,
                                              const int* __restrict__ boff,
                                              const int* __restrict__ off,
                                              int* __restrict__ esrc,
                                              int* __restrict__ edst, int n){
  __shared__ int h[256];
  int t = threadIdx.x, b = blockIdx.x;
  h[t] = 0;
  __syncthreads();
  int lo = boff[b], hi = boff[b + 1];
  int base = b * 256;
  for (int i = lo + t; i < hi; i += 256){
    unsigned pk = ebuf[i];
    int ld = (int)(pk & 255u);
    int s  = (int)(pk >> 8);
    int r = atomicAdd(&h[ld], 1);
    int pos = off[base + ld] + r;
    esrc[pos] = s;
    edst[pos] = base + ld;
  }
}

// ---------------- BN column stats (sum, sumsq into out[0..127], out[128..255]) ----------------
__global__ __launch_bounds__(256) void k_colstats(const float* __restrict__ X, int n, float* __restrict__ out){
  __shared__ float ss[4][128], sq[4][128];
  int t = threadIdx.x, lane = t & 63, w = t >> 6;
  float sx = 0.f, sy = 0.f, qx = 0.f, qy = 0.f;
  for (int r = blockIdx.x * 4 + w; r < n; r += gridDim.x * 4){
    float2 v = *(const float2*)(X + (size_t)r * NF + lane * 2);
    sx += v.x; sy += v.y; qx += v.x * v.x; qy += v.y * v.y;
  }
  ss[w][lane * 2] = sx; ss[w][lane * 2 + 1] = sy;
  sq[w][lane * 2] = qx; sq[w][lane * 2 + 1] = qy;
  __syncthreads();
  if (t < 128){
    float tot = ss[0][t] + ss[1][t] + ss[2][t] + ss[3][t];
    atomicAdd(&out[t], tot);
  } else {
    int c = t - 128;
    float tot = sq[0][c] + sq[1][c] + sq[2][c] + sq[3][c];
    atomicAdd(&out[128 + c], tot);
  }
}

// H = (X - m) * rsqrt(var+eps) + BNB   (writes f32 + bf16 copy)
__global__ void k_bnx(const float* __restrict__ X, const float* __restrict__ stats,
                      float* __restrict__ H, ushort4* __restrict__ H16, int n){
  size_t tot4 = (size_t)n * (NF / 4);
  float inv_n = 1.f / (float)n;
  for (size_t i = blockIdx.x * (size_t)blockDim.x + threadIdx.x; i < tot4;
       i += (size_t)gridDim.x * blockDim.x){
    float4 v = ((const float4*)X)[i];
    int c0 = (int)((i * 4) % NF);
    float* vv = (float*)&v;
    #pragma unroll
    for (int j = 0; j < 4; ++j){
      float m = stats[c0 + j] * inv_n;
      float var = stats[128 + c0 + j] * inv_n - m * m;
      vv[j] = (vv[j] - m) * rsqrtf(var + EPS) + BNB;
    }
    ((float4*)H)[i] = v;
    ushort4 b;
    b.x = f2b(v.x); b.y = f2b(v.y); b.z = f2b(v.z); b.w = f2b(v.w);
    H16[i] = b;
  }
}

// H = relu( (Xg - m)*inv + BNB + H )   (writes f32 + bf16 copy)
__global__ void k_bnres(const float* __restrict__ Xg, const float* __restrict__ stats,
                        float* __restrict__ H, ushort4* __restrict__ H16, int n){
  size_t tot4 = (size_t)n * (NF / 4);
  float inv_n = 1.f / (float)n;
  for (size_t i = blockIdx.x * (size_t)blockDim.x + threadIdx.x; i < tot4;
       i += (size_t)gridDim.x * blockDim.x){
    float4 v = ((const float4*)Xg)[i];
    float4 hc = ((const float4*)H)[i];
    int c0 = (int)((i * 4) % NF);
    float* vv = (float*)&v;
    float* hh = (float*)&hc;
    #pragma unroll
    for (int j = 0; j < 4; ++j){
      float m = stats[c0 + j] * inv_n;
      float var = stats[128 + c0 + j] * inv_n - m * m;
      float z = (vv[j] - m) * rsqrtf(var + EPS) + BNB + hh[j];
      hh[j] = fmaxf(z, 0.f);
    }
    ((float4*)H)[i] = hc;
    ushort4 b;
    b.x = f2b(hc.x); b.y = f2b(hc.y); b.z = f2b(hc.z); b.w = f2b(hc.w);
    H16[i] = b;
  }
}

// ---------------- weight convert + transpose: Wt[l][n][k] bf16 ----------------
__global__ void k_cvtw(const float* __restrict__ W, unsigned short* __restrict__ Wt){
  int i = blockIdx.x * blockDim.x + threadIdx.x;   // 4*128*128
  int l = i >> 14, rem = i & 16383;
  int k = rem >> 7, nn = rem & 127;
  Wt[(l << 14) + nn * 128 + k] = f2b(W[i]);
}

// ---------------- MFMA GEMM + fused att-vec epilogue ----------------
__global__ __launch_bounds__(256) void k_gemm(const unsigned short* __restrict__ X,
                                              const unsigned short* __restrict__ Wt,
                                              unsigned short* __restrict__ Y,
                                              const float* __restrict__ asrc,
                                              const float* __restrict__ adst,
                                              float* __restrict__ a_s,
                                              float* __restrict__ a_d, int n){
  __shared__ unsigned short sX[64 * 128];    // 16 KB, XOR-swizzled 16B units
  __shared__ unsigned short sW[128 * 128];   // 32 KB, [n][k], XOR-swizzled
  int t = threadIdx.x;
  int rbase = blockIdx.x * 64;
  #pragma unroll
  for (int i = 0; i < 8; ++i){               // stage Wt: 2048 uint4
    int idx = t + 256 * i;
    int rn = idx >> 4, c16 = idx & 15;
    uint4 v = ((const uint4*)Wt)[idx];
    *(uint4*)&sW[rn * 128 + ((c16 ^ (rn & 7)) << 3)] = v;
  }
  #pragma unroll
  for (int i = 0; i < 4; ++i){               // stage X: 1024 uint4
    int idx = t + 256 * i;
    int r = idx >> 4, c16 = idx & 15;
    int gr = rbase + r;
    uint4 v = (gr < n) ? ((const uint4*)(X + (size_t)gr * NF))[c16] : make_uint4(0, 0, 0, 0);
    *(uint4*)&sX[r * 128 + ((c16 ^ (r & 7)) << 3)] = v;
  }
  __syncthreads();
  int lane = t & 63, w = t >> 6;
  int lrow = w * 16 + (lane & 15);
  int khi = lane >> 4;                       // 0..3
  bf16x8 a[4];
  #pragma unroll
  for (int ks = 0; ks < 4; ++ks){
    int c16 = ks * 4 + khi;
    a[ks] = *(const bf16x8*)&sX[lrow * 128 + ((c16 ^ (lrow & 7)) << 3)];
  }
  f32x4 acc[8];
  #pragma unroll
  for (int nt = 0; nt < 8; ++nt){
    f32x4 z = {0.f, 0.f, 0.f, 0.f};
    acc[nt] = z;
    int nrow = nt * 16 + (lane & 15);
    #pragma unroll
    for (int ks = 0; ks < 4; ++ks){
      int c16 = ks * 4 + khi;
      bf16x8 b = *(const bf16x8*)&sW[nrow * 128 + ((c16 ^ (nrow & 7)) << 3)];
      acc[nt] = __builtin_amdgcn_mfma_f32_16x16x32_bf16(a[ks], b, acc[nt], 0, 0, 0);
    }
  }
  // stage D (bf16, swizzled) back into sX
  #pragma unroll
  for (int nt = 0; nt < 8; ++nt){
    #pragma unroll
    for (int i = 0; i < 4; ++i){
      int r = w * 16 + (khi << 2) + i;
      int c = nt * 16 + (lane & 15);
      int csw = c ^ ((r & 7) << 3);
      sX[r * 128 + csw] = f2b(acc[nt][i]);
    }
  }
  __syncthreads();
  // coalesced Y store
  #pragma unroll
  for (int i = 0; i < 4; ++i){
    int idx = t + 256 * i;
    int r = idx >> 4, c16 = idx & 15;
    int gr = rbase + r;
    if (gr < n)
      ((uint4*)(Y + (size_t)gr * NF))[c16] = *(const uint4*)&sX[r * 128 + ((c16 ^ (r & 7)) << 3)];
  }
  // fused att-vec: thread -> (row = t>>2, head = t&3); dot 32 elems from LDS
  int r = t >> 2, hh = t & 3;
  int gr = rbase + r;
  if (gr < n){
    float ps = 0.f, pd = 0.f;
    #pragma unroll
    for (int j = 0; j < 16; ++j){
      int c = hh * 32 + j * 2;
      int u = (c >> 3) ^ (r & 7);
      unsigned v = *(const unsigned*)&sX[r * 128 + (u << 3) + (c & 7)];
      float vx = b2f_lo(v), vy = b2f_hi(v);
      ps += vx * asrc[c] + vy * asrc[c + 1];
      pd += vx * adst[c] + vy * adst[c + 1];
    }
    a_s[(size_t)gr * 4 + hh] = ps;
    a_d[(size_t)gr * 4 + hh] = pd;
  }
}

// ---------------- per-edge exp-weights, SoA by head: ew[h*total + e] ----------------
__global__ void k_edgew(const int* __restrict__ esrc, const int* __restrict__ edst,
                        const float4* __restrict__ a_s, const float4* __restrict__ a_d,
                        float* __restrict__ ew, int total){
  int e = blockIdx.x * blockDim.x + threadIdx.x;
  if (e >= total) return;
  float4 as = a_s[esrc[e]];
  float4 ad = a_d[edst[e]];
  ew[e]             = __expf(lrelu(as.x + ad.x));
  ew[total + e]     = __expf(lrelu(as.y + ad.y));
  ew[2 * total + e] = __expf(lrelu(as.z + ad.z));
  ew[3 * total + e] = __expf(lrelu(as.w + ad.w));
}

// ---------------- attention: precomputed exp-weights, unroll-8; optional fused relu+bf16 out ----------------
__global__ __launch_bounds__(256) void k_attn(const unsigned short* __restrict__ Hm16,
                                              const float* __restrict__ ew,
                                              const int* __restrict__ off,
                                              const int* __restrict__ esrc,
                                              const float* __restrict__ bias,
                                              float* __restrict__ Yf,
                                              unsigned short* __restrict__ Y16,
                                              int dorelu, int n, int estride){
  int t = threadIdx.x, lane = t & 63, w = t >> 6;
  int node = blockIdx.x * 4 + w;
  if (node >= n) return;
  node = __builtin_amdgcn_readfirstlane(node);
  int head = lane >> 4;
  const float* ep = ew + (size_t)head * estride;
  int lo = off[node], hi = off[node + 1];
  lo = __builtin_amdgcn_readfirstlane(lo);
  hi = __builtin_amdgcn_readfirstlane(hi);
  int fo = lane * 2;
  float sum = 0.f, ax = 0.f, ay = 0.f;
  for (int e = lo; e < hi; e += 8){
    int ei[8]; int si[8]; float wi[8]; unsigned vi[8];
    #pragma unroll
    for (int k = 0; k < 8; ++k) ei[k] = min(e + k, hi - 1);
    #pragma unroll
    for (int k = 0; k < 8; ++k) si[k] = esrc[ei[k]];
    #pragma unroll
    for (int k = 0; k < 8; ++k) wi[k] = ep[ei[k]];
    #pragma unroll
    for (int k = 0; k < 8; ++k) vi[k] = *(const unsigned*)(Hm16 + (size_t)si[k] * NF + fo);
    #pragma unroll
    for (int k = 0; k < 8; ++k){
      if (e + k >= hi) wi[k] = 0.f;    // clamped duplicates get weight 0
      sum += wi[k];
      ax += wi[k] * b2f_lo(vi[k]);
      ay += wi[k] * b2f_hi(vi[k]);
    }
  }
  float inv = 1.f / (sum + 1e-16f);
  float2 b = *(const float2*)(bias + fo);
  float rx = ax * inv + b.x;
  float ry = ay * inv + b.y;
  if (dorelu){
    rx = fmaxf(rx, 0.f); ry = fmaxf(ry, 0.f);
    ushort2 pk; pk.x = f2b(rx); pk.y = f2b(ry);
    *(ushort2*)(Y16 + (size_t)node * NF + fo) = pk;
  }
  float2 r; r.x = rx; r.y = ry;
  *(float2*)(Yf + (size_t)node * NF + fo) = r;
}

// ---------------- pooling: batch is sorted; one block per graph ----------------
__global__ __launch_bounds__(256) void k_pool(const float* __restrict__ H, const int* __restrict__ batch,
                                              float* __restrict__ g, int n){
  int gid = blockIdx.x;
  int t = threadIdx.x, lane = t & 63, w = t >> 6;
  int lo = 0, hi = n;
  while (lo < hi){ int mid = (lo + hi) >> 1; if (batch[mid] < gid) lo = mid + 1; else hi = mid; }
  int a = lo, b = n;
  while (a < b){ int mid = (a + b) >> 1; if (batch[mid] < gid + 1) a = mid + 1; else b = mid; }
  float sx = 0.f, sy = 0.f;
  for (int r = lo + w; r < a; r += 4){
    float2 v = *(const float2*)(H + (size_t)r * NF + lane * 2);
    sx += v.x; sy += v.y;
  }
  __shared__ float ss[4][128];
  ss[w][lane * 2] = sx; ss[w][lane * 2 + 1] = sy;
  __syncthreads();
  if (t < 128) g[(size_t)gid * NF + t] = ss[0][t] + ss[1][t] + ss[2][t] + ss[3][t];
}

// ---------------- head stage 2: BN1-apply -> fc (LDS weights) -> relu -> BN2 partial stats ----------------
// grid 4 x 256; block handles 32 rows of the 128x128 pooled matrix
__global__ __launch_bounds__(256) void k_h2(const float* __restrict__ g,
                                            const float* __restrict__ st1,
                                            const float* __restrict__ fc_w,
                                            const float* __restrict__ fc_b,
                                            float* __restrict__ hfc,
                                            float* __restrict__ st2){
  __shared__ float sA[32 * 128];     // 16 KB
  __shared__ float sW[128 * 128];    // 64 KB
  __shared__ float redS[8][128], redQ[8][128];  // 8 KB
  int t = threadIdx.x;
  int rbase = blockIdx.x * 32;
  #pragma unroll
  for (int i = 0; i < 16; ++i)
    ((float4*)sW)[t + 256 * i] = ((const float4*)fc_w)[t + 256 * i];
  const float inv128 = 1.f / 128.f;
  #pragma unroll
  for (int i = 0; i < 4; ++i){
    int idx = t + 256 * i;           // 0..1023
    int r = idx >> 5, c4 = idx & 31;
    float4 v = ((const float4*)(g + (size_t)(rbase + r) * 128))[c4];
    int c0 = c4 * 4;
    float* vv = (float*)&v;
    #pragma unroll
    for (int j = 0; j < 4; ++j){
      float m = st1[c0 + j] * inv128;
      float var = st1[128 + c0 + j] * inv128 - m * m;
      vv[j] = (vv[j] - m) * rsqrtf(var + EPS) + BNB;
    }
    ((float4*)sA)[idx] = v;
  }
  __syncthreads();
  int c0 = (t & 31) * 4, r0 = (t >> 5) * 4;
  float o[4][4];
  float4 bb = *(const float4*)(fc_b + c0);
  #pragma unroll
  for (int i = 0; i < 4; ++i){ o[i][0] = bb.x; o[i][1] = bb.y; o[i][2] = bb.z; o[i][3] = bb.w; }
  for (int k = 0; k < 128; ++k){
    float4 wv = *(const float4*)&sW[k * 128 + c0];
    #pragma unroll
    for (int i = 0; i < 4; ++i){
      float xs = sA[(r0 + i) * 128 + k];
      o[i][0] += xs * wv.x; o[i][1] += xs * wv.y;
      o[i][2] += xs * wv.z; o[i][3] += xs * wv.w;
    }
  }
  float ps[4] = {0, 0, 0, 0}, pq[4] = {0, 0, 0, 0};
  #pragma unroll
  for (int i = 0; i < 4; ++i){
    #pragma unroll
    for (int j = 0; j < 4; ++j){
      float v = fmaxf(o[i][j], 0.f);
      o[i][j] = v;
      ps[j] += v; pq[j] += v * v;
    }
    float4 wv; wv.x = o[i][0]; wv.y = o[i][1]; wv.z = o[i][2]; wv.w = o[i][3];
    *(float4*)(hfc + (size_t)(rbase + r0 + i) * 128 + c0) = wv;
  }
  int g8 = t >> 5;
  #pragma unroll
  for (int j = 0; j < 4; ++j){ redS[g8][c0 + j] = ps[j]; redQ[g8][c0 + j] = pq[j]; }
  __syncthreads();
  if (t < 128){
    float s = 0.f, q = 0.f;
    #pragma unroll
    for (int gg = 0; gg < 8; ++gg){ s += redS[gg][t]; q += redQ[gg][t]; }
    atomicAdd(&st2[t], s);
    atomicAdd(&st2[128 + t], q);
  }
}

// ---------------- head stage 3: BN2-apply -> classifier -> log_softmax ----------------
__global__ __launch_bounds__(1024) void k_h3(const float* __restrict__ hfc,
                                             const float* __restrict__ st2,
                                             const float* __restrict__ cls_w,
                                             const float* __restrict__ cls_b,
                                             float* __restrict__ out){
  __shared__ float A[128 * 128];
  __shared__ float logits[256];
  int t = threadIdx.x;
  #pragma unroll
  for (int i = 0; i < 4; ++i)
    ((float4*)A)[t + 1024 * i] = ((const float4*)hfc)[t + 1024 * i];
  __syncthreads();
  const float inv128 = 1.f / 128.f;
  #pragma unroll
  for (int i = 0; i < 16; ++i){
    int idx = t + 1024 * i;
    int c = idx & 127;
    float m = st2[c] * inv128;
    float var = st2[128 + c] * inv128 - m * m;
    A[idx] = (A[idx] - m) * rsqrtf(var + EPS) + BNB;
  }
  __syncthreads();
  int o = t >> 2, sub = t & 3;       // 256 outputs x 4 lanes
  int r = o >> 1, j = o & 1;
  float acc = 0.f;
  int k0 = sub * 32;
  for (int k = k0; k < k0 + 32; ++k)
    acc += A[r * 128 + k] * cls_w[k * 2 + j];
  acc += __shfl_xor(acc, 1, 64);
  acc += __shfl_xor(acc, 2, 64);
  if (sub == 0) logits[o] = acc + cls_b[j];
  __syncthreads();
  if (t < 256){
    int rr = t >> 1;
    float l0 = logits[rr * 2], l1 = logits[rr * 2 + 1];
    float mx = fmaxf(l0, l1);
    float lse = mx + logf(__expf(l0 - mx) + __expf(l1 - mx));
    out[t] = logits[t] - lse;
  }
}

extern "C" void kernel_launch(void* const* d_in, const int* in_sizes, int n_in,
                              void* d_out, int out_size, void* d_ws, size_t ws_size,
                              hipStream_t stream){
  const float* x        = (const float*)d_in[0];
  const int*   ei       = (const int*)d_in[1];
  const int*   batch    = (const int*)d_in[2];
  const float* gat_lin  = (const float*)d_in[3];
  const float* att_src  = (const float*)d_in[4];
  const float* att_dst  = (const float*)d_in[5];
  const float* gat_bias = (const float*)d_in[6];
  const float* fc_w     = (const float*)d_in[7];
  const float* fc_b     = (const float*)d_in[8];
  const float* cls_w    = (const float*)d_in[9];
  const float* cls_b    = (const float*)d_in[10];
  float* out = (float*)d_out;
  (void)n_in; (void)out_size; (void)ws_size;

  int N = in_sizes[0] / NF;
  int E = in_sizes[1] / 2;
  int total = E + N;
  int nb = cdiv(N, 256);     // scan blocks == coarse buckets (196 for N=50000)
  int nbkt = nb;

  char* p = (char*)d_ws;
  auto alloc = [&](size_t bytes) -> char* {
    char* r = p;
    p += (bytes + 255) & ~(size_t)255;
    return r;
  };
  int*   deg     = (int*)alloc((size_t)N * 4);
  int*   off     = (int*)alloc((size_t)(N + 1) * 4);
  int*   bsum    = (int*)alloc((size_t)nb * 4);
  int*   bcnt    = (int*)alloc((size_t)nbkt * 4);
  int*   boff    = (int*)alloc((size_t)(nbkt + 1) * 4);
  int*   bcursor = (int*)alloc((size_t)nbkt * 4);
  unsigned* ebuf = (unsigned*)alloc((size_t)total * 4);
  int*   esrc    = (int*)alloc((size_t)total * 4);
  int*   edst    = (int*)alloc((size_t)total * 4);
  float* ew      = (float*)alloc((size_t)total * 4 * 4);
  float* stats   = (float*)alloc(8 * 256 * 4);
  float* hbuf    = (float*)alloc((size_t)N * NF * 4);
  unsigned short* hbuf16 = (unsigned short*)alloc((size_t)N * NF * 2);
  unsigned short* tmp16  = (unsigned short*)alloc((size_t)N * NF * 2);
  unsigned short* wbuf16 = (unsigned short*)alloc((size_t)4 * NF * NF * 2);
  float* gout    = (float*)alloc((size_t)N * NF * 4);
  float* a_s     = (float*)alloc((size_t)N * 4 * 4);
  float* a_d     = (float*)alloc((size_t)N * 4 * 4);
  float* gpool   = (float*)alloc(128 * NF * 4);
  float* hfc     = (float*)alloc(128 * NF * 4);

  // CSR build: chunked-reservation bucket sort
  k_zero<<<8, 256, 0, stream>>>(stats, bcnt, nbkt, 1536);
  k_bhist<<<256, 256, 0, stream>>>(ei, E, N, bcnt, nbkt);
  k_bscan<<<1, 256, 0, stream>>>(bcnt, boff, bcursor, nbkt);
  k_bscatter2<<<cdiv(total, CHUNK), 256, 0, stream>>>(ei, E, N, bcursor, ebuf, nbkt);
  k_deg<<<nbkt, 256, 0, stream>>>(ebuf, boff, deg, N);
  k_scan1<<<nb, 256, 0, stream>>>(deg, bsum, N);
  k_scan2<<<1, 256, 0, stream>>>(bsum, nb);
  k_scan3<<<nb, 256, 0, stream>>>(deg, bsum, off, N);
  k_fine<<<nbkt, 256, 0, stream>>>(ebuf, boff, off, esrc, edst, N);
  k_cvtw<<<256, 256, 0, stream>>>(gat_lin, wbuf16);

  k_colstats<<<256, 256, 0, stream>>>(x, N, stats);
  k_bnx<<<1024, 256, 0, stream>>>(x, stats, hbuf, (ushort4*)hbuf16, N);

  for (int L = 0; L < 4; ++L){
    k_gemm<<<cdiv(N, 64), 256, 0, stream>>>(hbuf16, wbuf16 + (size_t)L * NF * NF, tmp16,
                                            att_src + (size_t)L * NF, att_dst + (size_t)L * NF,
                                            a_s, a_d, N);
    k_edgew<<<cdiv(total, 256), 256, 0, stream>>>(esrc, edst, (const float4*)a_s,
                                                  (const float4*)a_d, ew, total);
    if (L == 0){
      // fused relu: write hbuf (f32) + hbuf16 (bf16) directly
      k_attn<<<cdiv(N, 4), 256, 0, stream>>>(tmp16, ew, off, esrc,
                                             gat_bias + (size_t)L * NF,
                                             hbuf, hbuf16, 1, N, total);
    } else {
      k_attn<<<cdiv(N, 4), 256, 0, stream>>>(tmp16, ew, off, esrc,
                                             gat_bias + (size_t)L * NF,
                                             gout, hbuf16, 0, N, total);
      k_colstats<<<256, 256, 0, stream>>>(gout, N, stats + L * 256);
      k_bnres<<<1024, 256, 0, stream>>>(gout, stats + L * 256, hbuf, (ushort4*)hbuf16, N);
    }
  }

  k_pool<<<128, 256, 0, stream>>>(hbuf, batch, gpool, N);
  // parallel head: BN1 stats -> fc+relu+BN2-partials -> BN2+cls+log_softmax
  k_colstats<<<32, 256, 0, stream>>>(gpool, 128, stats + 1024);
  k_h2<<<4, 256, 0, stream>>>(gpool, stats + 1024, fc_w, fc_b, hfc, stats + 1280);
  k_h3<<<1, 1024, 0, stream>>>(hfc, stats + 1280, cls_w, cls_b, out);
}

// Round 11
// 474.189 us; speedup vs baseline: 1.0875x; 1.0327x over previous
//
#include <hip/hip_runtime.h>
#include <math.h>

#define NF 128
#define EPS 1e-5f
#define BNB 1e-4f
#define CHUNK 8192

static inline int cdiv(int a, int b){ return (a + b - 1) / b; }

typedef __attribute__((ext_vector_type(8))) short bf16x8;
typedef __attribute__((ext_vector_type(4))) float f32x4;

__device__ __forceinline__ float lrelu(float x){ return x > 0.f ? x : 0.2f * x; }

// f32 -> bf16 round-to-nearest-even (finite inputs)
__device__ __forceinline__ unsigned short f2b(float f){
  unsigned u = __float_as_uint(f);
  u += 0x7fffu + ((u >> 16) & 1u);
  return (unsigned short)(u >> 16);
}
__device__ __forceinline__ float b2f_lo(unsigned v){ return __uint_as_float(v << 16); }
__device__ __forceinline__ float b2f_hi(unsigned v){ return __uint_as_float(v & 0xffff0000u); }

// ---------------- CSR build: chunked-reservation bucket sort ----------------
__global__ void k_zero(float* stats, int* bcnt, int nbkt, int statcount){
  int i = blockIdx.x * blockDim.x + threadIdx.x;
  if (i < statcount) stats[i] = 0.f;
  if (i < nbkt) bcnt[i] = 0;
}

// coarse histogram over buckets (dst>>8), LDS-aggregated
__global__ __launch_bounds__(256) void k_bhist(const int* __restrict__ ei, int E, int n,
                                               int* __restrict__ bcnt, int nbkt){
  __shared__ int h[256];
  h[threadIdx.x] = 0;
  __syncthreads();
  int total = E + n;
  for (int i = blockIdx.x * 256 + threadIdx.x; i < total; i += gridDim.x * 256){
    int d = (i < E) ? ei[E + i] : (i - E);
    atomicAdd(&h[d >> 8], 1);
  }
  __syncthreads();
  if (threadIdx.x < nbkt && h[threadIdx.x]) atomicAdd(&bcnt[threadIdx.x], h[threadIdx.x]);
}

// 1-block exclusive scan over nbkt (<=256) bucket counts -> boff, bcursor
__global__ __launch_bounds__(256) void k_bscan(const int* __restrict__ bcnt, int* __restrict__ boff,
                                               int* __restrict__ bcursor, int nb){
  int t = threadIdx.x;
  int v = (t < nb) ? bcnt[t] : 0;
  int lane = t & 63, w = t >> 6;
  int x = v;
  #pragma unroll
  for (int d = 1; d < 64; d <<= 1){
    int y = __shfl_up(x, d, 64);
    if (lane >= d) x += y;
  }
  __shared__ int wt[4], wex[4];
  if (lane == 63) wt[w] = x;
  __syncthreads();
  if (t == 0){ int r = 0; for (int i = 0; i < 4; ++i){ wex[i] = r; r += wt[i]; } }
  __syncthreads();
  int ex = wex[w] + x - v;
  if (t < nb){ boff[t] = ex; bcursor[t] = ex; }
  if (t == nb - 1) boff[nb] = ex + v;
}

// chunked scatter: per block, LDS hist -> one reservation atomic per bucket -> ranked write.
__global__ __launch_bounds__(256) void k_bscatter2(const int* __restrict__ ei, int E, int n,
                                                   int* __restrict__ bcursor,
                                                   unsigned* __restrict__ ebuf, int nbkt){
  __shared__ int h[256], base[256];
  int t = threadIdx.x;
  int total = E + n;
  int lo = blockIdx.x * CHUNK;
  int hi = min(lo + CHUNK, total);
  h[t] = 0;
  __syncthreads();
  for (int i = lo + t; i < hi; i += 256){
    int d = (i < E) ? ei[E + i] : (i - E);
    atomicAdd(&h[d >> 8], 1);
  }
  __syncthreads();
  int cnt = h[t];
  if (t < nbkt && cnt > 0) base[t] = atomicAdd(&bcursor[t], cnt);
  __syncthreads();
  h[t] = 0;
  __syncthreads();
  for (int i = lo + t; i < hi; i += 256){
    int s, d;
    if (i < E){ s = ei[i]; d = ei[E + i]; }
    else { s = i - E; d = s; }
    int b = d >> 8;
    int r = atomicAdd(&h[b], 1);
    ebuf[base[b] + r] = ((unsigned)s << 8) | (unsigned)(d & 255);
  }
}

// fused per-bucket CSR finisher: deg hist -> in-block scan -> off write -> ranked scatter.
// Key identity: boff[b] == off[b*256] (buckets are node-aligned).
__global__ __launch_bounds__(256) void k_bucket(const unsigned* __restrict__ ebuf,
                                                const int* __restrict__ boff,
                                                int* __restrict__ off,
                                                int* __restrict__ esrc,
                                                int* __restrict__ edst, int n){
  __shared__ int h[256], sbase[256];
  __shared__ int wt[4], wex[4];
  int t = threadIdx.x, b = blockIdx.x;
  int lo = boff[b], hi = boff[b + 1];
  h[t] = 0;
  __syncthreads();
  for (int i = lo + t; i < hi; i += 256) atomicAdd(&h[ebuf[i] & 255u], 1);
  __syncthreads();
  int v = h[t];
  int lane = t & 63, w = t >> 6;
  int x = v;
  #pragma unroll
  for (int d = 1; d < 64; d <<= 1){
    int y = __shfl_up(x, d, 64);
    if (lane >= d) x += y;
  }
  if (lane == 63) wt[w] = x;
  __syncthreads();
  if (t == 0){ int r = 0; for (int i = 0; i < 4; ++i){ wex[i] = r; r += wt[i]; } }
  __syncthreads();
  int base = lo + wex[w] + (x - v);    // global CSR offset of this node
  int node = b * 256 + t;
  if (node < n) off[node] = base;
  if (node == n - 1) off[n] = base + v;
  sbase[t] = base;
  __syncthreads();
  h[t] = 0;
  __syncthreads();
  for (int i = lo + t; i < hi; i += 256){
    unsigned pk = ebuf[i];
    int ld = (int)(pk & 255u);
    int s  = (int)(pk >> 8);
    int r = atomicAdd(&h[ld], 1);
    int pos = sbase[ld] + r;
    esrc[pos] = s;
    edst[pos] = b * 256 + ld;
  }
}

// ---------------- BN column stats (sum, sumsq into out[0..127], out[128..255]) ----------------
__global__ __launch_bounds__(256) void k_colstats(const float* __restrict__ X, int n, float* __restrict__ out){
  __shared__ float ss[4][128], sq[4][128];
  int t = threadIdx.x, lane = t & 63, w = t >> 6;
  float sx = 0.f, sy = 0.f, qx = 0.f, qy = 0.f;
  for (int r = blockIdx.x * 4 + w; r < n; r += gridDim.x * 4){
    float2 v = *(const float2*)(X + (size_t)r * NF + lane * 2);
    sx += v.x; sy += v.y; qx += v.x * v.x; qy += v.y * v.y;
  }
  ss[w][lane * 2] = sx; ss[w][lane * 2 + 1] = sy;
  sq[w][lane * 2] = qx; sq[w][lane * 2 + 1] = qy;
  __syncthreads();
  if (t < 128){
    float tot = ss[0][t] + ss[1][t] + ss[2][t] + ss[3][t];
    atomicAdd(&out[t], tot);
  } else {
    int c = t - 128;
    float tot = sq[0][c] + sq[1][c] + sq[2][c] + sq[3][c];
    atomicAdd(&out[128 + c], tot);
  }
}

// H = (X - m) * rsqrt(var+eps) + BNB   (writes f32 + bf16 copy)
__global__ void k_bnx(const float* __restrict__ X, const float* __restrict__ stats,
                      float* __restrict__ H, ushort4* __restrict__ H16, int n){
  size_t tot4 = (size_t)n * (NF / 4);
  float inv_n = 1.f / (float)n;
  for (size_t i = blockIdx.x * (size_t)blockDim.x + threadIdx.x; i < tot4;
       i += (size_t)gridDim.x * blockDim.x){
    float4 v = ((const float4*)X)[i];
    int c0 = (int)((i * 4) % NF);
    float* vv = (float*)&v;
    #pragma unroll
    for (int j = 0; j < 4; ++j){
      float m = stats[c0 + j] * inv_n;
      float var = stats[128 + c0 + j] * inv_n - m * m;
      vv[j] = (vv[j] - m) * rsqrtf(var + EPS) + BNB;
    }
    ((float4*)H)[i] = v;
    ushort4 b;
    b.x = f2b(v.x); b.y = f2b(v.y); b.z = f2b(v.z); b.w = f2b(v.w);
    H16[i] = b;
  }
}

// H = relu( (Xg - m)*inv + BNB + H )   (writes f32 + bf16 copy)
__global__ void k_bnres(const float* __restrict__ Xg, const float* __restrict__ stats,
                        float* __restrict__ H, ushort4* __restrict__ H16, int n){
  size_t tot4 = (size_t)n * (NF / 4);
  float inv_n = 1.f / (float)n;
  for (size_t i = blockIdx.x * (size_t)blockDim.x + threadIdx.x; i < tot4;
       i += (size_t)gridDim.x * blockDim.x){
    float4 v = ((const float4*)Xg)[i];
    float4 hc = ((const float4*)H)[i];
    int c0 = (int)((i * 4) % NF);
    float* vv = (float*)&v;
    float* hh = (float*)&hc;
    #pragma unroll
    for (int j = 0; j < 4; ++j){
      float m = stats[c0 + j] * inv_n;
      float var = stats[128 + c0 + j] * inv_n - m * m;
      float z = (vv[j] - m) * rsqrtf(var + EPS) + BNB + hh[j];
      hh[j] = fmaxf(z, 0.f);
    }
    ((float4*)H)[i] = hc;
    ushort4 b;
    b.x = f2b(hc.x); b.y = f2b(hc.y); b.z = f2b(hc.z); b.w = f2b(hc.w);
    H16[i] = b;
  }
}

// ---------------- weight convert + transpose: Wt[l][n][k] bf16 ----------------
__global__ void k_cvtw(const float* __restrict__ W, unsigned short* __restrict__ Wt){
  int i = blockIdx.x * blockDim.x + threadIdx.x;   // 4*128*128
  int l = i >> 14, rem = i & 16383;
  int k = rem >> 7, nn = rem & 127;
  Wt[(l << 14) + nn * 128 + k] = f2b(W[i]);
}

// ---------------- MFMA GEMM (128-row blocks, 8 waves) + fused att-vec epilogue ----------------
__global__ __launch_bounds__(512) void k_gemm(const unsigned short* __restrict__ X,
                                              const unsigned short* __restrict__ Wt,
                                              unsigned short* __restrict__ Y,
                                              const float* __restrict__ asrc,
                                              const float* __restrict__ adst,
                                              float* __restrict__ a_s,
                                              float* __restrict__ a_d, int n){
  __shared__ unsigned short sX[128 * 128];   // 32 KB, XOR-swizzled 16B units
  __shared__ unsigned short sW[128 * 128];   // 32 KB, [n][k], XOR-swizzled
  int t = threadIdx.x;
  int rbase = blockIdx.x * 128;
  #pragma unroll
  for (int i = 0; i < 4; ++i){               // stage Wt: 2048 uint4 / 512
    int idx = t + 512 * i;
    int rn = idx >> 4, c16 = idx & 15;
    uint4 v = ((const uint4*)Wt)[idx];
    *(uint4*)&sW[rn * 128 + ((c16 ^ (rn & 7)) << 3)] = v;
  }
  #pragma unroll
  for (int i = 0; i < 4; ++i){               // stage X: 2048 uint4 / 512
    int idx = t + 512 * i;
    int r = idx >> 4, c16 = idx & 15;
    int gr = rbase + r;
    uint4 v = (gr < n) ? ((const uint4*)(X + (size_t)gr * NF))[c16] : make_uint4(0, 0, 0, 0);
    *(uint4*)&sX[r * 128 + ((c16 ^ (r & 7)) << 3)] = v;
  }
  __syncthreads();
  int lane = t & 63, w = t >> 6;             // 8 waves, wave w owns rows w*16..w*16+15
  int lrow = w * 16 + (lane & 15);
  int khi = lane >> 4;                       // 0..3
  bf16x8 a[4];
  #pragma unroll
  for (int ks = 0; ks < 4; ++ks){
    int c16 = ks * 4 + khi;
    a[ks] = *(const bf16x8*)&sX[lrow * 128 + ((c16 ^ (lrow & 7)) << 3)];
  }
  f32x4 acc[8];
  #pragma unroll
  for (int nt = 0; nt < 8; ++nt){
    f32x4 z = {0.f, 0.f, 0.f, 0.f};
    acc[nt] = z;
    int nrow = nt * 16 + (lane & 15);
    #pragma unroll
    for (int ks = 0; ks < 4; ++ks){
      int c16 = ks * 4 + khi;
      bf16x8 b = *(const bf16x8*)&sW[nrow * 128 + ((c16 ^ (nrow & 7)) << 3)];
      acc[nt] = __builtin_amdgcn_mfma_f32_16x16x32_bf16(a[ks], b, acc[nt], 0, 0, 0);
    }
  }
  // stage D (bf16, swizzled) back into own wave's 16 rows of sX
  #pragma unroll
  for (int nt = 0; nt < 8; ++nt){
    #pragma unroll
    for (int i = 0; i < 4; ++i){
      int r = w * 16 + (khi << 2) + i;
      int c = nt * 16 + (lane & 15);
      int csw = c ^ ((r & 7) << 3);
      sX[r * 128 + csw] = f2b(acc[nt][i]);
    }
  }
  __syncthreads();
  // coalesced Y store
  #pragma unroll
  for (int i = 0; i < 4; ++i){
    int idx = t + 512 * i;
    int r = idx >> 4, c16 = idx & 15;
    int gr = rbase + r;
    if (gr < n)
      ((uint4*)(Y + (size_t)gr * NF))[c16] = *(const uint4*)&sX[r * 128 + ((c16 ^ (r & 7)) << 3)];
  }
  // fused att-vec: thread -> (row = t>>2, head = t&3); dot 32 elems from LDS
  int r = t >> 2, hh = t & 3;
  int gr = rbase + r;
  if (gr < n){
    float ps = 0.f, pd = 0.f;
    #pragma unroll
    for (int j = 0; j < 16; ++j){
      int c = hh * 32 + j * 2;
      int u = (c >> 3) ^ (r & 7);
      unsigned v = *(const unsigned*)&sX[r * 128 + (u << 3) + (c & 7)];
      float vx = b2f_lo(v), vy = b2f_hi(v);
      ps += vx * asrc[c] + vy * asrc[c + 1];
      pd += vx * adst[c] + vy * adst[c + 1];
    }
    a_s[(size_t)gr * 4 + hh] = ps;
    a_d[(size_t)gr * 4 + hh] = pd;
  }
}

// ---------------- per-edge exp-weights, SoA by head: ew[h*total + e] ----------------
__global__ void k_edgew(const int* __restrict__ esrc, const int* __restrict__ edst,
                        const float4* __restrict__ a_s, const float4* __restrict__ a_d,
                        float* __restrict__ ew, int total){
  int e = blockIdx.x * blockDim.x + threadIdx.x;
  if (e >= total) return;
  float4 as = a_s[esrc[e]];
  float4 ad = a_d[edst[e]];
  ew[e]             = __expf(lrelu(as.x + ad.x));
  ew[total + e]     = __expf(lrelu(as.y + ad.y));
  ew[2 * total + e] = __expf(lrelu(as.z + ad.z));
  ew[3 * total + e] = __expf(lrelu(as.w + ad.w));
}

// ---------------- attention: precomputed exp-weights, unroll-8; optional fused relu+bf16 out ----------------
__global__ __launch_bounds__(256) void k_attn(const unsigned short* __restrict__ Hm16,
                                              const float* __restrict__ ew,
                                              const int* __restrict__ off,
                                              const int* __restrict__ esrc,
                                              const float* __restrict__ bias,
                                              float* __restrict__ Yf,
                                              unsigned short* __restrict__ Y16,
                                              int dorelu, int n, int estride){
  int t = threadIdx.x, lane = t & 63, w = t >> 6;
  int node = blockIdx.x * 4 + w;
  if (node >= n) return;
  node = __builtin_amdgcn_readfirstlane(node);
  int head = lane >> 4;
  const float* ep = ew + (size_t)head * estride;
  int lo = off[node], hi = off[node + 1];
  lo = __builtin_amdgcn_readfirstlane(lo);
  hi = __builtin_amdgcn_readfirstlane(hi);
  int fo = lane * 2;
  float sum = 0.f, ax = 0.f, ay = 0.f;
  for (int e = lo; e < hi; e += 8){
    int ei[8]; int si[8]; float wi[8]; unsigned vi[8];
    #pragma unroll
    for (int k = 0; k < 8; ++k) ei[k] = min(e + k, hi - 1);
    #pragma unroll
    for (int k = 0; k < 8; ++k) si[k] = esrc[ei[k]];
    #pragma unroll
    for (int k = 0; k < 8; ++k) wi[k] = ep[ei[k]];
    #pragma unroll
    for (int k = 0; k < 8; ++k) vi[k] = *(const unsigned*)(Hm16 + (size_t)si[k] * NF + fo);
    #pragma unroll
    for (int k = 0; k < 8; ++k){
      if (e + k >= hi) wi[k] = 0.f;    // clamped duplicates get weight 0
      sum += wi[k];
      ax += wi[k] * b2f_lo(vi[k]);
      ay += wi[k] * b2f_hi(vi[k]);
    }
  }
  float inv = 1.f / (sum + 1e-16f);
  float2 b = *(const float2*)(bias + fo);
  float rx = ax * inv + b.x;
  float ry = ay * inv + b.y;
  if (dorelu){
    rx = fmaxf(rx, 0.f); ry = fmaxf(ry, 0.f);
    ushort2 pk; pk.x = f2b(rx); pk.y = f2b(ry);
    *(ushort2*)(Y16 + (size_t)node * NF + fo) = pk;
  }
  float2 r; r.x = rx; r.y = ry;
  *(float2*)(Yf + (size_t)node * NF + fo) = r;
}

// ---------------- pooling: batch is sorted; one block per graph ----------------
__global__ __launch_bounds__(256) void k_pool(const float* __restrict__ H, const int* __restrict__ batch,
                                              float* __restrict__ g, int n){
  int gid = blockIdx.x;
  int t = threadIdx.x, lane = t & 63, w = t >> 6;
  int lo = 0, hi = n;
  while (lo < hi){ int mid = (lo + hi) >> 1; if (batch[mid] < gid) lo = mid + 1; else hi = mid; }
  int a = lo, b = n;
  while (a < b){ int mid = (a + b) >> 1; if (batch[mid] < gid + 1) a = mid + 1; else b = mid; }
  float sx = 0.f, sy = 0.f;
  for (int r = lo + w; r < a; r += 4){
    float2 v = *(const float2*)(H + (size_t)r * NF + lane * 2);
    sx += v.x; sy += v.y;
  }
  __shared__ float ss[4][128];
  ss[w][lane * 2] = sx; ss[w][lane * 2 + 1] = sy;
  __syncthreads();
  if (t < 128) g[(size_t)gid * NF + t] = ss[0][t] + ss[1][t] + ss[2][t] + ss[3][t];
}

// ---------------- head stage 2: BN1-apply -> fc (LDS weights) -> relu -> BN2 partial stats ----------------
__global__ __launch_bounds__(256) void k_h2(const float* __restrict__ g,
                                            const float* __restrict__ st1,
                                            const float* __restrict__ fc_w,
                                            const float* __restrict__ fc_b,
                                            float* __restrict__ hfc,
                                            float* __restrict__ st2){
  __shared__ float sA[32 * 128];
  __shared__ float sW[128 * 128];
  __shared__ float redS[8][128], redQ[8][128];
  int t = threadIdx.x;
  int rbase = blockIdx.x * 32;
  #pragma unroll
  for (int i = 0; i < 16; ++i)
    ((float4*)sW)[t + 256 * i] = ((const float4*)fc_w)[t + 256 * i];
  const float inv128 = 1.f / 128.f;
  #pragma unroll
  for (int i = 0; i < 4; ++i){
    int idx = t + 256 * i;
    int r = idx >> 5, c4 = idx & 31;
    float4 v = ((const float4*)(g + (size_t)(rbase + r) * 128))[c4];
    int c0 = c4 * 4;
    float* vv = (float*)&v;
    #pragma unroll
    for (int j = 0; j < 4; ++j){
      float m = st1[c0 + j] * inv128;
      float var = st1[128 + c0 + j] * inv128 - m * m;
      vv[j] = (vv[j] - m) * rsqrtf(var + EPS) + BNB;
    }
    ((float4*)sA)[idx] = v;
  }
  __syncthreads();
  int c0 = (t & 31) * 4, r0 = (t >> 5) * 4;
  float o[4][4];
  float4 bb = *(const float4*)(fc_b + c0);
  #pragma unroll
  for (int i = 0; i < 4; ++i){ o[i][0] = bb.x; o[i][1] = bb.y; o[i][2] = bb.z; o[i][3] = bb.w; }
  for (int k = 0; k < 128; ++k){
    float4 wv = *(const float4*)&sW[k * 128 + c0];
    #pragma unroll
    for (int i = 0; i < 4; ++i){
      float xs = sA[(r0 + i) * 128 + k];
      o[i][0] += xs * wv.x; o[i][1] += xs * wv.y;
      o[i][2] += xs * wv.z; o[i][3] += xs * wv.w;
    }
  }
  float ps[4] = {0, 0, 0, 0}, pq[4] = {0, 0, 0, 0};
  #pragma unroll
  for (int i = 0; i < 4; ++i){
    #pragma unroll
    for (int j = 0; j < 4; ++j){
      float v = fmaxf(o[i][j], 0.f);
      o[i][j] = v;
      ps[j] += v; pq[j] += v * v;
    }
    float4 wv; wv.x = o[i][0]; wv.y = o[i][1]; wv.z = o[i][2]; wv.w = o[i][3];
    *(float4*)(hfc + (size_t)(rbase + r0 + i) * 128 + c0) = wv;
  }
  int g8 = t >> 5;
  #pragma unroll
  for (int j = 0; j < 4; ++j){ redS[g8][c0 + j] = ps[j]; redQ[g8][c0 + j] = pq[j]; }
  __syncthreads();
  if (t < 128){
    float s = 0.f, q = 0.f;
    #pragma unroll
    for (int gg = 0; gg < 8; ++gg){ s += redS[gg][t]; q += redQ[gg][t]; }
    atomicAdd(&st2[t], s);
    atomicAdd(&st2[128 + t], q);
  }
}

// ---------------- head stage 3: BN2-apply -> classifier -> log_softmax ----------------
__global__ __launch_bounds__(1024) void k_h3(const float* __restrict__ hfc,
                                             const float* __restrict__ st2,
                                             const float* __restrict__ cls_w,
                                             const float* __restrict__ cls_b,
                                             float* __restrict__ out){
  __shared__ float A[128 * 128];
  __shared__ float logits[256];
  int t = threadIdx.x;
  #pragma unroll
  for (int i = 0; i < 4; ++i)
    ((float4*)A)[t + 1024 * i] = ((const float4*)hfc)[t + 1024 * i];
  __syncthreads();
  const float inv128 = 1.f / 128.f;
  #pragma unroll
  for (int i = 0; i < 16; ++i){
    int idx = t + 1024 * i;
    int c = idx & 127;
    float m = st2[c] * inv128;
    float var = st2[128 + c] * inv128 - m * m;
    A[idx] = (A[idx] - m) * rsqrtf(var + EPS) + BNB;
  }
  __syncthreads();
  int o = t >> 2, sub = t & 3;
  int r = o >> 1, j = o & 1;
  float acc = 0.f;
  int k0 = sub * 32;
  for (int k = k0; k < k0 + 32; ++k)
    acc += A[r * 128 + k] * cls_w[k * 2 + j];
  acc += __shfl_xor(acc, 1, 64);
  acc += __shfl_xor(acc, 2, 64);
  if (sub == 0) logits[o] = acc + cls_b[j];
  __syncthreads();
  if (t < 256){
    int rr = t >> 1;
    float l0 = logits[rr * 2], l1 = logits[rr * 2 + 1];
    float mx = fmaxf(l0, l1);
    float lse = mx + logf(__expf(l0 - mx) + __expf(l1 - mx));
    out[t] = logits[t] - lse;
  }
}

extern "C" void kernel_launch(void* const* d_in, const int* in_sizes, int n_in,
                              void* d_out, int out_size, void* d_ws, size_t ws_size,
                              hipStream_t stream){
  const float* x        = (const float*)d_in[0];
  const int*   ei       = (const int*)d_in[1];
  const int*   batch    = (const int*)d_in[2];
  const float* gat_lin  = (const float*)d_in[3];
  const float* att_src  = (const float*)d_in[4];
  const float* att_dst  = (const float*)d_in[5];
  const float* gat_bias = (const float*)d_in[6];
  const float* fc_w     = (const float*)d_in[7];
  const float* fc_b     = (const float*)d_in[8];
  const float* cls_w    = (const float*)d_in[9];
  const float* cls_b    = (const float*)d_in[10];
  float* out = (float*)d_out;
  (void)n_in; (void)out_size; (void)ws_size;

  int N = in_sizes[0] / NF;
  int E = in_sizes[1] / 2;
  int total = E + N;
  int nbkt = cdiv(N, 256);   // coarse buckets (196 for N=50000)

  char* p = (char*)d_ws;
  auto alloc = [&](size_t bytes) -> char* {
    char* r = p;
    p += (bytes + 255) & ~(size_t)255;
    return r;
  };
  int*   off     = (int*)alloc((size_t)(N + 1) * 4);
  int*   bcnt    = (int*)alloc((size_t)nbkt * 4);
  int*   boff    = (int*)alloc((size_t)(nbkt + 1) * 4);
  int*   bcursor = (int*)alloc((size_t)nbkt * 4);
  unsigned* ebuf = (unsigned*)alloc((size_t)total * 4);
  int*   esrc    = (int*)alloc((size_t)total * 4);
  int*   edst    = (int*)alloc((size_t)total * 4);
  float* ew      = (float*)alloc((size_t)total * 4 * 4);
  float* stats   = (float*)alloc(8 * 256 * 4);
  float* hbuf    = (float*)alloc((size_t)N * NF * 4);
  unsigned short* hbuf16 = (unsigned short*)alloc((size_t)N * NF * 2);
  unsigned short* tmp16  = (unsigned short*)alloc((size_t)N * NF * 2);
  unsigned short* wbuf16 = (unsigned short*)alloc((size_t)4 * NF * NF * 2);
  float* gout    = (float*)alloc((size_t)N * NF * 4);
  float* a_s     = (float*)alloc((size_t)N * 4 * 4);
  float* a_d     = (float*)alloc((size_t)N * 4 * 4);
  float* gpool   = (float*)alloc(128 * NF * 4);
  float* hfc     = (float*)alloc(128 * NF * 4);

  // CSR build: chunked-reservation bucket sort + fused per-bucket finisher
  k_zero<<<8, 256, 0, stream>>>(stats, bcnt, nbkt, 1536);
  k_bhist<<<256, 256, 0, stream>>>(ei, E, N, bcnt, nbkt);
  k_bscan<<<1, 256, 0, stream>>>(bcnt, boff, bcursor, nbkt);
  k_bscatter2<<<cdiv(total, CHUNK), 256, 0, stream>>>(ei, E, N, bcursor, ebuf, nbkt);
  k_bucket<<<nbkt, 256, 0, stream>>>(ebuf, boff, off, esrc, edst, N);
  k_cvtw<<<256, 256, 0, stream>>>(gat_lin, wbuf16);

  k_colstats<<<256, 256, 0, stream>>>(x, N, stats);
  k_bnx<<<1024, 256, 0, stream>>>(x, stats, hbuf, (ushort4*)hbuf16, N);

  for (int L = 0; L < 4; ++L){
    k_gemm<<<cdiv(N, 128), 512, 0, stream>>>(hbuf16, wbuf16 + (size_t)L * NF * NF, tmp16,
                                             att_src + (size_t)L * NF, att_dst + (size_t)L * NF,
                                             a_s, a_d, N);
    k_edgew<<<cdiv(total, 256), 256, 0, stream>>>(esrc, edst, (const float4*)a_s,
                                                  (const float4*)a_d, ew, total);
    if (L == 0){
      k_attn<<<cdiv(N, 4), 256, 0, stream>>>(tmp16, ew, off, esrc,
                                             gat_bias + (size_t)L * NF,
                                             hbuf, hbuf16, 1, N, total);
    } else {
      k_attn<<<cdiv(N, 4), 256, 0, stream>>>(tmp16, ew, off, esrc,
                                             gat_bias + (size_t)L * NF,
                                             gout, hbuf16, 0, N, total);
      k_colstats<<<256, 256, 0, stream>>>(gout, N, stats + L * 256);
      k_bnres<<<1024, 256, 0, stream>>>(gout, stats + L * 256, hbuf, (ushort4*)hbuf16, N);
    }
  }

  k_pool<<<128, 256, 0, stream>>>(hbuf, batch, gpool, N);
  k_colstats<<<32, 256, 0, stream>>>(gpool, 128, stats + 1024);
  k_h2<<<4, 256, 0, stream>>>(gpool, stats + 1024, fc_w, fc_b, hfc, stats + 1280);
  k_h3<<<1, 1024, 0, stream>>>(hfc, stats + 1280, cls_w, cls_b, out);
}

// Round 12
// 453.881 us; speedup vs baseline: 1.1362x; 1.0447x over previous
//
#include <hip/hip_runtime.h>
#include <math.h>

#define NF 128
#define EPS 1e-5f
#define BNB 1e-4f
#define CHUNK 8192

static inline int cdiv(int a, int b){ return (a + b - 1) / b; }

typedef __attribute__((ext_vector_type(8))) short bf16x8;
typedef __attribute__((ext_vector_type(4))) float f32x4;

__device__ __forceinline__ float lrelu(float x){ return x > 0.f ? x : 0.2f * x; }
__device__ __forceinline__ float sel4(float4 v, int h){
  float r = v.x;
  r = (h == 1) ? v.y : r;
  r = (h == 2) ? v.z : r;
  r = (h == 3) ? v.w : r;
  return r;
}

// f32 -> bf16 round-to-nearest-even (finite inputs)
__device__ __forceinline__ unsigned short f2b(float f){
  unsigned u = __float_as_uint(f);
  u += 0x7fffu + ((u >> 16) & 1u);
  return (unsigned short)(u >> 16);
}
__device__ __forceinline__ float b2f_lo(unsigned v){ return __uint_as_float(v << 16); }
__device__ __forceinline__ float b2f_hi(unsigned v){ return __uint_as_float(v & 0xffff0000u); }

// ---------------- init: zero stats/bcnt + weight convert/transpose (fused) ----------------
// grid 256 x 256 = 65536 threads exactly covers Wt
__global__ __launch_bounds__(256) void k_init(float* stats, int* bcnt, int nbkt, int statcount,
                                              const float* __restrict__ W,
                                              unsigned short* __restrict__ Wt){
  int i = blockIdx.x * blockDim.x + threadIdx.x;
  if (i < statcount) stats[i] = 0.f;
  if (i < nbkt) bcnt[i] = 0;
  int l = i >> 14, rem = i & 16383;
  int k = rem >> 7, nn = rem & 127;
  Wt[(l << 14) + nn * 128 + k] = f2b(W[i]);
}

// coarse histogram over buckets (dst>>8), LDS-aggregated
__global__ __launch_bounds__(256) void k_bhist(const int* __restrict__ ei, int E, int n,
                                               int* __restrict__ bcnt, int nbkt){
  __shared__ int h[256];
  h[threadIdx.x] = 0;
  __syncthreads();
  int total = E + n;
  for (int i = blockIdx.x * 256 + threadIdx.x; i < total; i += gridDim.x * 256){
    int d = (i < E) ? ei[E + i] : (i - E);
    atomicAdd(&h[d >> 8], 1);
  }
  __syncthreads();
  if (threadIdx.x < nbkt && h[threadIdx.x]) atomicAdd(&bcnt[threadIdx.x], h[threadIdx.x]);
}

// 1-block exclusive scan over nbkt (<=256) bucket counts -> boff, bcursor
__global__ __launch_bounds__(256) void k_bscan(const int* __restrict__ bcnt, int* __restrict__ boff,
                                               int* __restrict__ bcursor, int nb){
  int t = threadIdx.x;
  int v = (t < nb) ? bcnt[t] : 0;
  int lane = t & 63, w = t >> 6;
  int x = v;
  #pragma unroll
  for (int d = 1; d < 64; d <<= 1){
    int y = __shfl_up(x, d, 64);
    if (lane >= d) x += y;
  }
  __shared__ int wt[4], wex[4];
  if (lane == 63) wt[w] = x;
  __syncthreads();
  if (t == 0){ int r = 0; for (int i = 0; i < 4; ++i){ wex[i] = r; r += wt[i]; } }
  __syncthreads();
  int ex = wex[w] + x - v;
  if (t < nb){ boff[t] = ex; bcursor[t] = ex; }
  if (t == nb - 1) boff[nb] = ex + v;
}

// chunked scatter: per block, LDS hist -> one reservation atomic per bucket -> ranked write.
__global__ __launch_bounds__(256) void k_bscatter2(const int* __restrict__ ei, int E, int n,
                                                   int* __restrict__ bcursor,
                                                   unsigned* __restrict__ ebuf, int nbkt){
  __shared__ int h[256], base[256];
  int t = threadIdx.x;
  int total = E + n;
  int lo = blockIdx.x * CHUNK;
  int hi = min(lo + CHUNK, total);
  h[t] = 0;
  __syncthreads();
  for (int i = lo + t; i < hi; i += 256){
    int d = (i < E) ? ei[E + i] : (i - E);
    atomicAdd(&h[d >> 8], 1);
  }
  __syncthreads();
  int cnt = h[t];
  if (t < nbkt && cnt > 0) base[t] = atomicAdd(&bcursor[t], cnt);
  __syncthreads();
  h[t] = 0;
  __syncthreads();
  for (int i = lo + t; i < hi; i += 256){
    int s, d;
    if (i < E){ s = ei[i]; d = ei[E + i]; }
    else { s = i - E; d = s; }
    int b = d >> 8;
    int r = atomicAdd(&h[b], 1);
    ebuf[base[b] + r] = ((unsigned)s << 8) | (unsigned)(d & 255);
  }
}

// fused per-bucket CSR finisher: deg hist -> in-block scan -> off write -> ranked scatter.
// Key identity: boff[b] == off[b*256] (buckets are node-aligned).
__global__ __launch_bounds__(256) void k_bucket(const unsigned* __restrict__ ebuf,
                                                const int* __restrict__ boff,
                                                int* __restrict__ off,
                                                int* __restrict__ esrc, int n){
  __shared__ int h[256], sbase[256];
  __shared__ int wt[4], wex[4];
  int t = threadIdx.x, b = blockIdx.x;
  int lo = boff[b], hi = boff[b + 1];
  h[t] = 0;
  __syncthreads();
  for (int i = lo + t; i < hi; i += 256) atomicAdd(&h[ebuf[i] & 255u], 1);
  __syncthreads();
  int v = h[t];
  int lane = t & 63, w = t >> 6;
  int x = v;
  #pragma unroll
  for (int d = 1; d < 64; d <<= 1){
    int y = __shfl_up(x, d, 64);
    if (lane >= d) x += y;
  }
  if (lane == 63) wt[w] = x;
  __syncthreads();
  if (t == 0){ int r = 0; for (int i = 0; i < 4; ++i){ wex[i] = r; r += wt[i]; } }
  __syncthreads();
  int base = lo + wex[w] + (x - v);    // global CSR offset of this node
  int node = b * 256 + t;
  if (node < n) off[node] = base;
  if (node == n - 1) off[n] = base + v;
  sbase[t] = base;
  __syncthreads();
  h[t] = 0;
  __syncthreads();
  for (int i = lo + t; i < hi; i += 256){
    unsigned pk = ebuf[i];
    int ld = (int)(pk & 255u);
    int s  = (int)(pk >> 8);
    int r = atomicAdd(&h[ld], 1);
    esrc[sbase[ld] + r] = s;
  }
}

// ---------------- BN column stats (sum, sumsq into out[0..127], out[128..255]) ----------------
__global__ __launch_bounds__(256) void k_colstats(const float* __restrict__ X, int n, float* __restrict__ out){
  __shared__ float ss[4][128], sq[4][128];
  int t = threadIdx.x, lane = t & 63, w = t >> 6;
  float sx = 0.f, sy = 0.f, qx = 0.f, qy = 0.f;
  for (int r = blockIdx.x * 4 + w; r < n; r += gridDim.x * 4){
    float2 v = *(const float2*)(X + (size_t)r * NF + lane * 2);
    sx += v.x; sy += v.y; qx += v.x * v.x; qy += v.y * v.y;
  }
  ss[w][lane * 2] = sx; ss[w][lane * 2 + 1] = sy;
  sq[w][lane * 2] = qx; sq[w][lane * 2 + 1] = qy;
  __syncthreads();
  if (t < 128){
    float tot = ss[0][t] + ss[1][t] + ss[2][t] + ss[3][t];
    atomicAdd(&out[t], tot);
  } else {
    int c = t - 128;
    float tot = sq[0][c] + sq[1][c] + sq[2][c] + sq[3][c];
    atomicAdd(&out[128 + c], tot);
  }
}

// H = (X - m) * rsqrt(var+eps) + BNB   (writes f32 + bf16 copy)
__global__ void k_bnx(const float* __restrict__ X, const float* __restrict__ stats,
                      float* __restrict__ H, ushort4* __restrict__ H16, int n){
  size_t tot4 = (size_t)n * (NF / 4);
  float inv_n = 1.f / (float)n;
  for (size_t i = blockIdx.x * (size_t)blockDim.x + threadIdx.x; i < tot4;
       i += (size_t)gridDim.x * blockDim.x){
    float4 v = ((const float4*)X)[i];
    int c0 = (int)((i * 4) % NF);
    float* vv = (float*)&v;
    #pragma unroll
    for (int j = 0; j < 4; ++j){
      float m = stats[c0 + j] * inv_n;
      float var = stats[128 + c0 + j] * inv_n - m * m;
      vv[j] = (vv[j] - m) * rsqrtf(var + EPS) + BNB;
    }
    ((float4*)H)[i] = v;
    ushort4 b;
    b.x = f2b(v.x); b.y = f2b(v.y); b.z = f2b(v.z); b.w = f2b(v.w);
    H16[i] = b;
  }
}

// H = relu( (Xg - m)*inv + BNB + H )   (writes f32 + bf16 copy)
__global__ void k_bnres(const float* __restrict__ Xg, const float* __restrict__ stats,
                        float* __restrict__ H, ushort4* __restrict__ H16, int n){
  size_t tot4 = (size_t)n * (NF / 4);
  float inv_n = 1.f / (float)n;
  for (size_t i = blockIdx.x * (size_t)blockDim.x + threadIdx.x; i < tot4;
       i += (size_t)gridDim.x * blockDim.x){
    float4 v = ((const float4*)Xg)[i];
    float4 hc = ((const float4*)H)[i];
    int c0 = (int)((i * 4) % NF);
    float* vv = (float*)&v;
    float* hh = (float*)&hc;
    #pragma unroll
    for (int j = 0; j < 4; ++j){
      float m = stats[c0 + j] * inv_n;
      float var = stats[128 + c0 + j] * inv_n - m * m;
      float z = (vv[j] - m) * rsqrtf(var + EPS) + BNB + hh[j];
      hh[j] = fmaxf(z, 0.f);
    }
    ((float4*)H)[i] = hc;
    ushort4 b;
    b.x = f2b(hc.x); b.y = f2b(hc.y); b.z = f2b(hc.z); b.w = f2b(hc.w);
    H16[i] = b;
  }
}

// ---------------- MFMA GEMM (128-row blocks, 8 waves) + fused att-vec epilogue ----------------
__global__ __launch_bounds__(512) void k_gemm(const unsigned short* __restrict__ X,
                                              const unsigned short* __restrict__ Wt,
                                              unsigned short* __restrict__ Y,
                                              const float* __restrict__ asrc,
                                              const float* __restrict__ adst,
                                              float* __restrict__ a_s,
                                              float* __restrict__ a_d, int n){
  __shared__ unsigned short sX[128 * 128];   // 32 KB, XOR-swizzled 16B units
  __shared__ unsigned short sW[128 * 128];   // 32 KB, [n][k], XOR-swizzled
  int t = threadIdx.x;
  int rbase = blockIdx.x * 128;
  #pragma unroll
  for (int i = 0; i < 4; ++i){               // stage Wt: 2048 uint4 / 512
    int idx = t + 512 * i;
    int rn = idx >> 4, c16 = idx & 15;
    uint4 v = ((const uint4*)Wt)[idx];
    *(uint4*)&sW[rn * 128 + ((c16 ^ (rn & 7)) << 3)] = v;
  }
  #pragma unroll
  for (int i = 0; i < 4; ++i){               // stage X: 2048 uint4 / 512
    int idx = t + 512 * i;
    int r = idx >> 4, c16 = idx & 15;
    int gr = rbase + r;
    uint4 v = (gr < n) ? ((const uint4*)(X + (size_t)gr * NF))[c16] : make_uint4(0, 0, 0, 0);
    *(uint4*)&sX[r * 128 + ((c16 ^ (r & 7)) << 3)] = v;
  }
  __syncthreads();
  int lane = t & 63, w = t >> 6;             // 8 waves, wave w owns rows w*16..w*16+15
  int lrow = w * 16 + (lane & 15);
  int khi = lane >> 4;                       // 0..3
  bf16x8 a[4];
  #pragma unroll
  for (int ks = 0; ks < 4; ++ks){
    int c16 = ks * 4 + khi;
    a[ks] = *(const bf16x8*)&sX[lrow * 128 + ((c16 ^ (lrow & 7)) << 3)];
  }
  f32x4 acc[8];
  #pragma unroll
  for (int nt = 0; nt < 8; ++nt){
    f32x4 z = {0.f, 0.f, 0.f, 0.f};
    acc[nt] = z;
    int nrow = nt * 16 + (lane & 15);
    #pragma unroll
    for (int ks = 0; ks < 4; ++ks){
      int c16 = ks * 4 + khi;
      bf16x8 b = *(const bf16x8*)&sW[nrow * 128 + ((c16 ^ (nrow & 7)) << 3)];
      acc[nt] = __builtin_amdgcn_mfma_f32_16x16x32_bf16(a[ks], b, acc[nt], 0, 0, 0);
    }
  }
  // stage D (bf16, swizzled) back into own wave's 16 rows of sX
  #pragma unroll
  for (int nt = 0; nt < 8; ++nt){
    #pragma unroll
    for (int i = 0; i < 4; ++i){
      int r = w * 16 + (khi << 2) + i;
      int c = nt * 16 + (lane & 15);
      int csw = c ^ ((r & 7) << 3);
      sX[r * 128 + csw] = f2b(acc[nt][i]);
    }
  }
  __syncthreads();
  // coalesced Y store
  #pragma unroll
  for (int i = 0; i < 4; ++i){
    int idx = t + 512 * i;
    int r = idx >> 4, c16 = idx & 15;
    int gr = rbase + r;
    if (gr < n)
      ((uint4*)(Y + (size_t)gr * NF))[c16] = *(const uint4*)&sX[r * 128 + ((c16 ^ (r & 7)) << 3)];
  }
  // fused att-vec: thread -> (row = t>>2, head = t&3); dot 32 elems from LDS
  int r = t >> 2, hh = t & 3;
  int gr = rbase + r;
  if (gr < n){
    float ps = 0.f, pd = 0.f;
    #pragma unroll
    for (int j = 0; j < 16; ++j){
      int c = hh * 32 + j * 2;
      int u = (c >> 3) ^ (r & 7);
      unsigned v = *(const unsigned*)&sX[r * 128 + (u << 3) + (c & 7)];
      float vx = b2f_lo(v), vy = b2f_hi(v);
      ps += vx * asrc[c] + vy * asrc[c + 1];
      pd += vx * adst[c] + vy * adst[c + 1];
    }
    a_s[(size_t)gr * 4 + hh] = ps;
    a_d[(size_t)gr * 4 + hh] = pd;
  }
}

// ---------------- attention: inline alpha (no-max exp), unroll-8 gather + accumulate ----------------
// Per edge: a_s[(s<<2)+head] is the same address across a head's 16 lanes -> broadcast, L2-hot.
__global__ __launch_bounds__(256) void k_attn(const unsigned short* __restrict__ Hm16,
                                              const float* __restrict__ a_s,
                                              const float* __restrict__ a_d,
                                              const int* __restrict__ off,
                                              const int* __restrict__ esrc,
                                              const float* __restrict__ bias,
                                              float* __restrict__ Yf,
                                              unsigned short* __restrict__ Y16,
                                              int dorelu, int n){
  int t = threadIdx.x, lane = t & 63, w = t >> 6;
  int node = blockIdx.x * 4 + w;
  if (node >= n) return;
  node = __builtin_amdgcn_readfirstlane(node);
  int head = lane >> 4;
  float4 ad4 = ((const float4*)a_d)[node];
  float adh = sel4(ad4, head);
  int lo = off[node], hi = off[node + 1];
  lo = __builtin_amdgcn_readfirstlane(lo);
  hi = __builtin_amdgcn_readfirstlane(hi);
  int fo = lane * 2;
  float sum = 0.f, ax = 0.f, ay = 0.f;
  for (int e = lo; e < hi; e += 8){
    int si[8]; float ai[8]; unsigned vi[8];
    #pragma unroll
    for (int k = 0; k < 8; ++k) si[k] = esrc[min(e + k, hi - 1)];
    #pragma unroll
    for (int k = 0; k < 8; ++k) ai[k] = a_s[(si[k] << 2) + head];
    #pragma unroll
    for (int k = 0; k < 8; ++k) vi[k] = *(const unsigned*)(Hm16 + (size_t)si[k] * NF + fo);
    #pragma unroll
    for (int k = 0; k < 8; ++k){
      float wgt = (e + k < hi) ? __expf(lrelu(ai[k] + adh)) : 0.f;
      sum += wgt;
      ax += wgt * b2f_lo(vi[k]);
      ay += wgt * b2f_hi(vi[k]);
    }
  }
  float inv = 1.f / (sum + 1e-16f);
  float2 b = *(const float2*)(bias + fo);
  float rx = ax * inv + b.x;
  float ry = ay * inv + b.y;
  if (dorelu){
    rx = fmaxf(rx, 0.f); ry = fmaxf(ry, 0.f);
    ushort2 pk; pk.x = f2b(rx); pk.y = f2b(ry);
    *(ushort2*)(Y16 + (size_t)node * NF + fo) = pk;
  }
  float2 r; r.x = rx; r.y = ry;
  *(float2*)(Yf + (size_t)node * NF + fo) = r;
}

// ---------------- pooling: batch is sorted; one block per graph ----------------
__global__ __launch_bounds__(256) void k_pool(const float* __restrict__ H, const int* __restrict__ batch,
                                              float* __restrict__ g, int n){
  int gid = blockIdx.x;
  int t = threadIdx.x, lane = t & 63, w = t >> 6;
  int lo = 0, hi = n;
  while (lo < hi){ int mid = (lo + hi) >> 1; if (batch[mid] < gid) lo = mid + 1; else hi = mid; }
  int a = lo, b = n;
  while (a < b){ int mid = (a + b) >> 1; if (batch[mid] < gid + 1) a = mid + 1; else b = mid; }
  float sx = 0.f, sy = 0.f;
  for (int r = lo + w; r < a; r += 4){
    float2 v = *(const float2*)(H + (size_t)r * NF + lane * 2);
    sx += v.x; sy += v.y;
  }
  __shared__ float ss[4][128];
  ss[w][lane * 2] = sx; ss[w][lane * 2 + 1] = sy;
  __syncthreads();
  if (t < 128) g[(size_t)gid * NF + t] = ss[0][t] + ss[1][t] + ss[2][t] + ss[3][t];
}

// ---------------- head stage 2: BN1-apply -> fc (LDS weights) -> relu -> BN2 partial stats ----------------
__global__ __launch_bounds__(256) void k_h2(const float* __restrict__ g,
                                            const float* __restrict__ st1,
                                            const float* __restrict__ fc_w,
                                            const float* __restrict__ fc_b,
                                            float* __restrict__ hfc,
                                            float* __restrict__ st2){
  __shared__ float sA[32 * 128];
  __shared__ float sW[128 * 128];
  __shared__ float redS[8][128], redQ[8][128];
  int t = threadIdx.x;
  int rbase = blockIdx.x * 32;
  #pragma unroll
  for (int i = 0; i < 16; ++i)
    ((float4*)sW)[t + 256 * i] = ((const float4*)fc_w)[t + 256 * i];
  const float inv128 = 1.f / 128.f;
  #pragma unroll
  for (int i = 0; i < 4; ++i){
    int idx = t + 256 * i;
    int r = idx >> 5, c4 = idx & 31;
    float4 v = ((const float4*)(g + (size_t)(rbase + r) * 128))[c4];
    int c0 = c4 * 4;
    float* vv = (float*)&v;
    #pragma unroll
    for (int j = 0; j < 4; ++j){
      float m = st1[c0 + j] * inv128;
      float var = st1[128 + c0 + j] * inv128 - m * m;
      vv[j] = (vv[j] - m) * rsqrtf(var + EPS) + BNB;
    }
    ((float4*)sA)[idx] = v;
  }
  __syncthreads();
  int c0 = (t & 31) * 4, r0 = (t >> 5) * 4;
  float o[4][4];
  float4 bb = *(const float4*)(fc_b + c0);
  #pragma unroll
  for (int i = 0; i < 4; ++i){ o[i][0] = bb.x; o[i][1] = bb.y; o[i][2] = bb.z; o[i][3] = bb.w; }
  for (int k = 0; k < 128; ++k){
    float4 wv = *(const float4*)&sW[k * 128 + c0];
    #pragma unroll
    for (int i = 0; i < 4; ++i){
      float xs = sA[(r0 + i) * 128 + k];
      o[i][0] += xs * wv.x; o[i][1] += xs * wv.y;
      o[i][2] += xs * wv.z; o[i][3] += xs * wv.w;
    }
  }
  float ps[4] = {0, 0, 0, 0}, pq[4] = {0, 0, 0, 0};
  #pragma unroll
  for (int i = 0; i < 4; ++i){
    #pragma unroll
    for (int j = 0; j < 4; ++j){
      float v = fmaxf(o[i][j], 0.f);
      o[i][j] = v;
      ps[j] += v; pq[j] += v * v;
    }
    float4 wv; wv.x = o[i][0]; wv.y = o[i][1]; wv.z = o[i][2]; wv.w = o[i][3];
    *(float4*)(hfc + (size_t)(rbase + r0 + i) * 128 + c0) = wv;
  }
  int g8 = t >> 5;
  #pragma unroll
  for (int j = 0; j < 4; ++j){ redS[g8][c0 + j] = ps[j]; redQ[g8][c0 + j] = pq[j]; }
  __syncthreads();
  if (t < 128){
    float s = 0.f, q = 0.f;
    #pragma unroll
    for (int gg = 0; gg < 8; ++gg){ s += redS[gg][t]; q += redQ[gg][t]; }
    atomicAdd(&st2[t], s);
    atomicAdd(&st2[128 + t], q);
  }
}

// ---------------- head stage 3: BN2-apply -> classifier -> log_softmax ----------------
__global__ __launch_bounds__(1024) void k_h3(const float* __restrict__ hfc,
                                             const float* __restrict__ st2,
                                             const float* __restrict__ cls_w,
                                             const float* __restrict__ cls_b,
                                             float* __restrict__ out){
  __shared__ float A[128 * 128];
  __shared__ float logits[256];
  int t = threadIdx.x;
  #pragma unroll
  for (int i = 0; i < 4; ++i)
    ((float4*)A)[t + 1024 * i] = ((const float4*)hfc)[t + 1024 * i];
  __syncthreads();
  const float inv128 = 1.f / 128.f;
  #pragma unroll
  for (int i = 0; i < 16; ++i){
    int idx = t + 1024 * i;
    int c = idx & 127;
    float m = st2[c] * inv128;
    float var = st2[128 + c] * inv128 - m * m;
    A[idx] = (A[idx] - m) * rsqrtf(var + EPS) + BNB;
  }
  __syncthreads();
  int o = t >> 2, sub = t & 3;
  int r = o >> 1, j = o & 1;
  float acc = 0.f;
  int k0 = sub * 32;
  for (int k = k0; k < k0 + 32; ++k)
    acc += A[r * 128 + k] * cls_w[k * 2 + j];
  acc += __shfl_xor(acc, 1, 64);
  acc += __shfl_xor(acc, 2, 64);
  if (sub == 0) logits[o] = acc + cls_b[j];
  __syncthreads();
  if (t < 256){
    int rr = t >> 1;
    float l0 = logits[rr * 2], l1 = logits[rr * 2 + 1];
    float mx = fmaxf(l0, l1);
    float lse = mx + logf(__expf(l0 - mx) + __expf(l1 - mx));
    out[t] = logits[t] - lse;
  }
}

extern "C" void kernel_launch(void* const* d_in, const int* in_sizes, int n_in,
                              void* d_out, int out_size, void* d_ws, size_t ws_size,
                              hipStream_t stream){
  const float* x        = (const float*)d_in[0];
  const int*   ei       = (const int*)d_in[1];
  const int*   batch    = (const int*)d_in[2];
  const float* gat_lin  = (const float*)d_in[3];
  const float* att_src  = (const float*)d_in[4];
  const float* att_dst  = (const float*)d_in[5];
  const float* gat_bias = (const float*)d_in[6];
  const float* fc_w     = (const float*)d_in[7];
  const float* fc_b     = (const float*)d_in[8];
  const float* cls_w    = (const float*)d_in[9];
  const float* cls_b    = (const float*)d_in[10];
  float* out = (float*)d_out;
  (void)n_in; (void)out_size; (void)ws_size;

  int N = in_sizes[0] / NF;
  int E = in_sizes[1] / 2;
  int total = E + N;
  int nbkt = cdiv(N, 256);   // coarse buckets (196 for N=50000)

  char* p = (char*)d_ws;
  auto alloc = [&](size_t bytes) -> char* {
    char* r = p;
    p += (bytes + 255) & ~(size_t)255;
    return r;
  };
  int*   off     = (int*)alloc((size_t)(N + 1) * 4);
  int*   bcnt    = (int*)alloc((size_t)nbkt * 4);
  int*   boff    = (int*)alloc((size_t)(nbkt + 1) * 4);
  int*   bcursor = (int*)alloc((size_t)nbkt * 4);
  unsigned* ebuf = (unsigned*)alloc((size_t)total * 4);
  int*   esrc    = (int*)alloc((size_t)total * 4);
  float* stats   = (float*)alloc(8 * 256 * 4);
  float* hbuf    = (float*)alloc((size_t)N * NF * 4);
  unsigned short* hbuf16 = (unsigned short*)alloc((size_t)N * NF * 2);
  unsigned short* tmp16  = (unsigned short*)alloc((size_t)N * NF * 2);
  unsigned short* wbuf16 = (unsigned short*)alloc((size_t)4 * NF * NF * 2);
  float* gout    = (float*)alloc((size_t)N * NF * 4);
  float* a_s     = (float*)alloc((size_t)N * 4 * 4);
  float* a_d     = (float*)alloc((size_t)N * 4 * 4);
  float* gpool   = (float*)alloc(128 * NF * 4);
  float* hfc     = (float*)alloc(128 * NF * 4);

  // CSR build: chunked-reservation bucket sort + fused per-bucket finisher
  k_init<<<256, 256, 0, stream>>>(stats, bcnt, nbkt, 1536, gat_lin, wbuf16);
  k_bhist<<<256, 256, 0, stream>>>(ei, E, N, bcnt, nbkt);
  k_bscan<<<1, 256, 0, stream>>>(bcnt, boff, bcursor, nbkt);
  k_bscatter2<<<cdiv(total, CHUNK), 256, 0, stream>>>(ei, E, N, bcursor, ebuf, nbkt);
  k_bucket<<<nbkt, 256, 0, stream>>>(ebuf, boff, off, esrc, N);

  k_colstats<<<256, 256, 0, stream>>>(x, N, stats);
  k_bnx<<<1024, 256, 0, stream>>>(x, stats, hbuf, (ushort4*)hbuf16, N);

  for (int L = 0; L < 4; ++L){
    k_gemm<<<cdiv(N, 128), 512, 0, stream>>>(hbuf16, wbuf16 + (size_t)L * NF * NF, tmp16,
                                             att_src + (size_t)L * NF, att_dst + (size_t)L * NF,
                                             a_s, a_d, N);
    if (L == 0){
      k_attn<<<cdiv(N, 4), 256, 0, stream>>>(tmp16, a_s, a_d, off, esrc,
                                             gat_bias + (size_t)L * NF,
                                             hbuf, hbuf16, 1, N);
    } else {
      k_attn<<<cdiv(N, 4), 256, 0, stream>>>(tmp16, a_s, a_d, off, esrc,
                                             gat_bias + (size_t)L * NF,
                                             gout, hbuf16, 0, N);
      k_colstats<<<256, 256, 0, stream>>>(gout, N, stats + L * 256);
      k_bnres<<<1024, 256, 0, stream>>>(gout, stats + L * 256, hbuf, (ushort4*)hbuf16, N);
    }
  }

  k_pool<<<128, 256, 0, stream>>>(hbuf, batch, gpool, N);
  k_colstats<<<32, 256, 0, stream>>>(gpool, 128, stats + 1024);
  k_h2<<<4, 256, 0, stream>>>(gpool, stats + 1024, fc_w, fc_b, hfc, stats + 1280);
  k_h3<<<1, 1024, 0, stream>>>(hfc, stats + 1280, cls_w, cls_b, out);
}

// Round 13
// 433.645 us; speedup vs baseline: 1.1892x; 1.0467x over previous
//
#include <hip/hip_runtime.h>
#include <math.h>

#define NF 128
#define EPS 1e-5f
#define BNB 1e-4f
#define CHUNK 8192
#define LOG2E 1.44269504088896f

static inline int cdiv(int a, int b){ return (a + b - 1) / b; }

typedef __attribute__((ext_vector_type(8))) short bf16x8;
typedef __attribute__((ext_vector_type(4))) float f32x4;

__device__ __forceinline__ float lrelu(float x){ return x > 0.f ? x : 0.2f * x; }
__device__ __forceinline__ float sel4(float4 v, int h){
  float r = v.x;
  r = (h == 1) ? v.y : r;
  r = (h == 2) ? v.z : r;
  r = (h == 3) ? v.w : r;
  return r;
}

// f32 -> bf16 round-to-nearest-even (finite inputs)
__device__ __forceinline__ unsigned short f2b(float f){
  unsigned u = __float_as_uint(f);
  u += 0x7fffu + ((u >> 16) & 1u);
  return (unsigned short)(u >> 16);
}
__device__ __forceinline__ unsigned pack2(float a, float b){
  return (unsigned)f2b(a) | ((unsigned)f2b(b) << 16);
}
__device__ __forceinline__ float b2f_lo(unsigned v){ return __uint_as_float(v << 16); }
__device__ __forceinline__ float b2f_hi(unsigned v){ return __uint_as_float(v & 0xffff0000u); }

// ---------------- init: zero stats/bcnt + weight convert/transpose (fused) ----------------
__global__ __launch_bounds__(256) void k_init(float* stats, int* bcnt, int nbkt, int statcount,
                                              const float* __restrict__ W,
                                              unsigned short* __restrict__ Wt){
  int i = blockIdx.x * blockDim.x + threadIdx.x;
  if (i < statcount) stats[i] = 0.f;
  if (i < nbkt) bcnt[i] = 0;
  int l = i >> 14, rem = i & 16383;
  int k = rem >> 7, nn = rem & 127;
  Wt[(l << 14) + nn * 128 + k] = f2b(W[i]);
}

// coarse histogram over buckets (dst>>8), LDS-aggregated
__global__ __launch_bounds__(256) void k_bhist(const int* __restrict__ ei, int E, int n,
                                               int* __restrict__ bcnt, int nbkt){
  __shared__ int h[256];
  h[threadIdx.x] = 0;
  __syncthreads();
  int total = E + n;
  for (int i = blockIdx.x * 256 + threadIdx.x; i < total; i += gridDim.x * 256){
    int d = (i < E) ? ei[E + i] : (i - E);
    atomicAdd(&h[d >> 8], 1);
  }
  __syncthreads();
  if (threadIdx.x < nbkt && h[threadIdx.x]) atomicAdd(&bcnt[threadIdx.x], h[threadIdx.x]);
}

// 1-block exclusive scan over nbkt (<=256) bucket counts -> boff, bcursor
__global__ __launch_bounds__(256) void k_bscan(const int* __restrict__ bcnt, int* __restrict__ boff,
                                               int* __restrict__ bcursor, int nb){
  int t = threadIdx.x;
  int v = (t < nb) ? bcnt[t] : 0;
  int lane = t & 63, w = t >> 6;
  int x = v;
  #pragma unroll
  for (int d = 1; d < 64; d <<= 1){
    int y = __shfl_up(x, d, 64);
    if (lane >= d) x += y;
  }
  __shared__ int wt[4], wex[4];
  if (lane == 63) wt[w] = x;
  __syncthreads();
  if (t == 0){ int r = 0; for (int i = 0; i < 4; ++i){ wex[i] = r; r += wt[i]; } }
  __syncthreads();
  int ex = wex[w] + x - v;
  if (t < nb){ boff[t] = ex; bcursor[t] = ex; }
  if (t == nb - 1) boff[nb] = ex + v;
}

// chunked scatter: per block, LDS hist -> one reservation atomic per bucket -> ranked write.
__global__ __launch_bounds__(256) void k_bscatter2(const int* __restrict__ ei, int E, int n,
                                                   int* __restrict__ bcursor,
                                                   unsigned* __restrict__ ebuf, int nbkt){
  __shared__ int h[256], base[256];
  int t = threadIdx.x;
  int total = E + n;
  int lo = blockIdx.x * CHUNK;
  int hi = min(lo + CHUNK, total);
  h[t] = 0;
  __syncthreads();
  for (int i = lo + t; i < hi; i += 256){
    int d = (i < E) ? ei[E + i] : (i - E);
    atomicAdd(&h[d >> 8], 1);
  }
  __syncthreads();
  int cnt = h[t];
  if (t < nbkt && cnt > 0) base[t] = atomicAdd(&bcursor[t], cnt);
  __syncthreads();
  h[t] = 0;
  __syncthreads();
  for (int i = lo + t; i < hi; i += 256){
    int s, d;
    if (i < E){ s = ei[i]; d = ei[E + i]; }
    else { s = i - E; d = s; }
    int b = d >> 8;
    int r = atomicAdd(&h[b], 1);
    ebuf[base[b] + r] = ((unsigned)s << 8) | (unsigned)(d & 255);
  }
}

// fused per-bucket CSR finisher: deg hist -> in-block scan -> off write -> ranked scatter.
__global__ __launch_bounds__(256) void k_bucket(const unsigned* __restrict__ ebuf,
                                                const int* __restrict__ boff,
                                                int* __restrict__ off,
                                                int* __restrict__ esrc, int n){
  __shared__ int h[256], sbase[256];
  __shared__ int wt[4], wex[4];
  int t = threadIdx.x, b = blockIdx.x;
  int lo = boff[b], hi = boff[b + 1];
  h[t] = 0;
  __syncthreads();
  for (int i = lo + t; i < hi; i += 256) atomicAdd(&h[ebuf[i] & 255u], 1);
  __syncthreads();
  int v = h[t];
  int lane = t & 63, w = t >> 6;
  int x = v;
  #pragma unroll
  for (int d = 1; d < 64; d <<= 1){
    int y = __shfl_up(x, d, 64);
    if (lane >= d) x += y;
  }
  if (lane == 63) wt[w] = x;
  __syncthreads();
  if (t == 0){ int r = 0; for (int i = 0; i < 4; ++i){ wex[i] = r; r += wt[i]; } }
  __syncthreads();
  int base = lo + wex[w] + (x - v);
  int node = b * 256 + t;
  if (node < n) off[node] = base;
  if (node == n - 1) off[n] = base + v;
  sbase[t] = base;
  __syncthreads();
  h[t] = 0;
  __syncthreads();
  for (int i = lo + t; i < hi; i += 256){
    unsigned pk = ebuf[i];
    int ld = (int)(pk & 255u);
    int s  = (int)(pk >> 8);
    int r = atomicAdd(&h[ld], 1);
    esrc[sbase[ld] + r] = s;
  }
}

// ---------------- BN column stats (sum, sumsq into out[0..127], out[128..255]) ----------------
__global__ __launch_bounds__(256) void k_colstats(const float* __restrict__ X, int n, float* __restrict__ out){
  __shared__ float ss[4][128], sq[4][128];
  int t = threadIdx.x, lane = t & 63, w = t >> 6;
  float sx = 0.f, sy = 0.f, qx = 0.f, qy = 0.f;
  for (int r = blockIdx.x * 4 + w; r < n; r += gridDim.x * 4){
    float2 v = *(const float2*)(X + (size_t)r * NF + lane * 2);
    sx += v.x; sy += v.y; qx += v.x * v.x; qy += v.y * v.y;
  }
  ss[w][lane * 2] = sx; ss[w][lane * 2 + 1] = sy;
  sq[w][lane * 2] = qx; sq[w][lane * 2 + 1] = qy;
  __syncthreads();
  if (t < 128){
    float tot = ss[0][t] + ss[1][t] + ss[2][t] + ss[3][t];
    atomicAdd(&out[t], tot);
  } else {
    int c = t - 128;
    float tot = sq[0][c] + sq[1][c] + sq[2][c] + sq[3][c];
    atomicAdd(&out[128 + c], tot);
  }
}

// ---------------- MFMA GEMM (128-row blocks, 8 waves) with fused BN staging + att-vec epilogue ----
// mode 0: stage bf16 from X16.  mode 1: stage bn(Xa) (f32 source).  mode 2: stage
// z = relu(bn(Xa)+Xb), persist z -> Xb (residual state).  Epilogue writes a_s/a_d scaled by log2e.
__global__ __launch_bounds__(512) void k_gemm(const unsigned short* __restrict__ X16,
                                              const float* __restrict__ Xa,
                                              float* __restrict__ Xb,
                                              const float* __restrict__ stats, float inv_n,
                                              int mode,
                                              const unsigned short* __restrict__ Wt,
                                              unsigned short* __restrict__ Y,
                                              const float* __restrict__ asrc,
                                              const float* __restrict__ adst,
                                              float* __restrict__ a_s,
                                              float* __restrict__ a_d, int n){
  __shared__ unsigned short sX[128 * 128];   // 32 KB, XOR-swizzled 16B units
  __shared__ unsigned short sW[128 * 128];   // 32 KB, [n][k], XOR-swizzled
  int t = threadIdx.x;
  int rbase = blockIdx.x * 128;
  #pragma unroll
  for (int i = 0; i < 4; ++i){               // stage Wt: 2048 uint4 / 512
    int idx = t + 512 * i;
    int rn = idx >> 4, c16 = idx & 15;
    uint4 v = ((const uint4*)Wt)[idx];
    *(uint4*)&sW[rn * 128 + ((c16 ^ (rn & 7)) << 3)] = v;
  }
  if (mode == 0){
    #pragma unroll
    for (int i = 0; i < 4; ++i){
      int idx = t + 512 * i;
      int r = idx >> 4, c16 = idx & 15;
      int gr = rbase + r;
      uint4 v = (gr < n) ? ((const uint4*)(X16 + (size_t)gr * NF))[c16] : make_uint4(0, 0, 0, 0);
      *(uint4*)&sX[r * 128 + ((c16 ^ (r & 7)) << 3)] = v;
    }
  } else {
    #pragma unroll
    for (int i = 0; i < 4; ++i){
      int idx = t + 512 * i;
      int r = idx >> 4, c16 = idx & 15;
      int gr = rbase + r;
      int c = c16 * 8;
      float z[8];
      if (gr < n){
        float4 va = *(const float4*)(Xa + (size_t)gr * NF + c);
        float4 vb = *(const float4*)(Xa + (size_t)gr * NF + c + 4);
        float4 m1 = *(const float4*)(stats + c);
        float4 m2 = *(const float4*)(stats + c + 4);
        float4 q1 = *(const float4*)(stats + 128 + c);
        float4 q2 = *(const float4*)(stats + 128 + c + 4);
        const float* pa = (const float*)&va; const float* pb = (const float*)&vb;
        const float* pm1 = (const float*)&m1; const float* pm2 = (const float*)&m2;
        const float* pq1 = (const float*)&q1; const float* pq2 = (const float*)&q2;
        #pragma unroll
        for (int j = 0; j < 4; ++j){
          float m = pm1[j] * inv_n;
          float var = pq1[j] * inv_n - m * m;
          z[j] = (pa[j] - m) * rsqrtf(var + EPS) + BNB;
          float m_ = pm2[j] * inv_n;
          float var_ = pq2[j] * inv_n - m_ * m_;
          z[4 + j] = (pb[j] - m_) * rsqrtf(var_ + EPS) + BNB;
        }
        if (mode == 2){
          float4 ha = *(const float4*)(Xb + (size_t)gr * NF + c);
          float4 hb = *(const float4*)(Xb + (size_t)gr * NF + c + 4);
          const float* ph1 = (const float*)&ha; const float* ph2 = (const float*)&hb;
          #pragma unroll
          for (int j = 0; j < 4; ++j){
            z[j]     = fmaxf(z[j]     + ph1[j], 0.f);
            z[4 + j] = fmaxf(z[4 + j] + ph2[j], 0.f);
          }
          float4 o1, o2;
          o1.x = z[0]; o1.y = z[1]; o1.z = z[2]; o1.w = z[3];
          o2.x = z[4]; o2.y = z[5]; o2.z = z[6]; o2.w = z[7];
          *(float4*)(Xb + (size_t)gr * NF + c) = o1;
          *(float4*)(Xb + (size_t)gr * NF + c + 4) = o2;
        }
      } else {
        #pragma unroll
        for (int j = 0; j < 8; ++j) z[j] = 0.f;
      }
      uint4 u;
      u.x = pack2(z[0], z[1]); u.y = pack2(z[2], z[3]);
      u.z = pack2(z[4], z[5]); u.w = pack2(z[6], z[7]);
      *(uint4*)&sX[r * 128 + ((c16 ^ (r & 7)) << 3)] = u;
    }
  }
  __syncthreads();
  int lane = t & 63, w = t >> 6;
  int lrow = w * 16 + (lane & 15);
  int khi = lane >> 4;
  bf16x8 a[4];
  #pragma unroll
  for (int ks = 0; ks < 4; ++ks){
    int c16 = ks * 4 + khi;
    a[ks] = *(const bf16x8*)&sX[lrow * 128 + ((c16 ^ (lrow & 7)) << 3)];
  }
  f32x4 acc[8];
  #pragma unroll
  for (int nt = 0; nt < 8; ++nt){
    f32x4 z = {0.f, 0.f, 0.f, 0.f};
    acc[nt] = z;
    int nrow = nt * 16 + (lane & 15);
    #pragma unroll
    for (int ks = 0; ks < 4; ++ks){
      int c16 = ks * 4 + khi;
      bf16x8 b = *(const bf16x8*)&sW[nrow * 128 + ((c16 ^ (nrow & 7)) << 3)];
      acc[nt] = __builtin_amdgcn_mfma_f32_16x16x32_bf16(a[ks], b, acc[nt], 0, 0, 0);
    }
  }
  #pragma unroll
  for (int nt = 0; nt < 8; ++nt){
    #pragma unroll
    for (int i = 0; i < 4; ++i){
      int r = w * 16 + (khi << 2) + i;
      int c = nt * 16 + (lane & 15);
      int csw = c ^ ((r & 7) << 3);
      sX[r * 128 + csw] = f2b(acc[nt][i]);
    }
  }
  __syncthreads();
  #pragma unroll
  for (int i = 0; i < 4; ++i){
    int idx = t + 512 * i;
    int r = idx >> 4, c16 = idx & 15;
    int gr = rbase + r;
    if (gr < n)
      ((uint4*)(Y + (size_t)gr * NF))[c16] = *(const uint4*)&sX[r * 128 + ((c16 ^ (r & 7)) << 3)];
  }
  // fused att-vec (pre-scaled by log2e for exp2 in attn)
  int r = t >> 2, hh = t & 3;
  int gr = rbase + r;
  if (gr < n){
    float ps = 0.f, pd = 0.f;
    #pragma unroll
    for (int j = 0; j < 16; ++j){
      int c = hh * 32 + j * 2;
      int u = (c >> 3) ^ (r & 7);
      unsigned v = *(const unsigned*)&sX[r * 128 + (u << 3) + (c & 7)];
      float vx = b2f_lo(v), vy = b2f_hi(v);
      ps += vx * asrc[c] + vy * asrc[c + 1];
      pd += vx * adst[c] + vy * adst[c + 1];
    }
    a_s[(size_t)gr * 4 + hh] = ps * LOG2E;
    a_d[(size_t)gr * 4 + hh] = pd * LOG2E;
  }
}

// ---------------- attention: inline alpha (exp2, no-max), unroll-8 gather + accumulate ----------------
__global__ __launch_bounds__(256) void k_attn(const unsigned short* __restrict__ Hm16,
                                              const float* __restrict__ a_s,
                                              const float* __restrict__ a_d,
                                              const int* __restrict__ off,
                                              const int* __restrict__ esrc,
                                              const float* __restrict__ bias,
                                              float* __restrict__ Yf,
                                              unsigned short* __restrict__ Y16,
                                              int dorelu, int n){
  int t = threadIdx.x, lane = t & 63, w = t >> 6;
  int node = blockIdx.x * 4 + w;
  if (node >= n) return;
  node = __builtin_amdgcn_readfirstlane(node);
  int head = lane >> 4;
  float4 ad4 = ((const float4*)a_d)[node];
  float adh = sel4(ad4, head);
  int lo = off[node], hi = off[node + 1];
  lo = __builtin_amdgcn_readfirstlane(lo);
  hi = __builtin_amdgcn_readfirstlane(hi);
  int fo = lane * 2;
  float sum = 0.f, ax = 0.f, ay = 0.f;
  for (int e = lo; e < hi; e += 8){
    int si[8]; float ai[8]; unsigned vi[8];
    #pragma unroll
    for (int k = 0; k < 8; ++k) si[k] = esrc[min(e + k, hi - 1)];
    #pragma unroll
    for (int k = 0; k < 8; ++k) ai[k] = a_s[(si[k] << 2) + head];
    #pragma unroll
    for (int k = 0; k < 8; ++k) vi[k] = *(const unsigned*)(Hm16 + (size_t)si[k] * NF + fo);
    #pragma unroll
    for (int k = 0; k < 8; ++k){
      float wgt = (e + k < hi) ? exp2f(lrelu(ai[k] + adh)) : 0.f;
      sum += wgt;
      ax += wgt * b2f_lo(vi[k]);
      ay += wgt * b2f_hi(vi[k]);
    }
  }
  float inv = 1.f / (sum + 1e-16f);
  float2 b = *(const float2*)(bias + fo);
  float rx = ax * inv + b.x;
  float ry = ay * inv + b.y;
  if (dorelu){
    rx = fmaxf(rx, 0.f); ry = fmaxf(ry, 0.f);
    ushort2 pk; pk.x = f2b(rx); pk.y = f2b(ry);
    *(ushort2*)(Y16 + (size_t)node * NF + fo) = pk;
  }
  float2 r; r.x = rx; r.y = ry;
  *(float2*)(Yf + (size_t)node * NF + fo) = r;
}

// ---------------- pooling with fused final bn-residual: z = relu(bn(G)+H), per-graph sum ----------------
__global__ __launch_bounds__(256) void k_pool(const float* __restrict__ G,
                                              const float* __restrict__ H,
                                              const float* __restrict__ stats, float inv_n,
                                              const int* __restrict__ batch,
                                              float* __restrict__ g, int n){
  int gid = blockIdx.x;
  int t = threadIdx.x, lane = t & 63, w = t >> 6;
  int lo = 0, hi = n;
  while (lo < hi){ int mid = (lo + hi) >> 1; if (batch[mid] < gid) lo = mid + 1; else hi = mid; }
  int a = lo, b = n;
  while (a < b){ int mid = (a + b) >> 1; if (batch[mid] < gid + 1) a = mid + 1; else b = mid; }
  int c = lane * 2;
  float m0 = stats[c] * inv_n,     q0 = stats[128 + c] * inv_n;
  float m1 = stats[c + 1] * inv_n, q1 = stats[128 + c + 1] * inv_n;
  float rs0 = rsqrtf(q0 - m0 * m0 + EPS);
  float rs1 = rsqrtf(q1 - m1 * m1 + EPS);
  float sx = 0.f, sy = 0.f;
  for (int r = lo + w; r < a; r += 4){
    float2 gv = *(const float2*)(G + (size_t)r * NF + c);
    float2 hv = *(const float2*)(H + (size_t)r * NF + c);
    sx += fmaxf((gv.x - m0) * rs0 + BNB + hv.x, 0.f);
    sy += fmaxf((gv.y - m1) * rs1 + BNB + hv.y, 0.f);
  }
  __shared__ float ss[4][128];
  ss[w][lane * 2] = sx; ss[w][lane * 2 + 1] = sy;
  __syncthreads();
  if (t < 128) g[(size_t)gid * NF + t] = ss[0][t] + ss[1][t] + ss[2][t] + ss[3][t];
}

// ---------------- head stage 2: BN1-apply -> fc (LDS weights) -> relu -> BN2 partial stats ----------------
__global__ __launch_bounds__(256) void k_h2(const float* __restrict__ g,
                                            const float* __restrict__ st1,
                                            const float* __restrict__ fc_w,
                                            const float* __restrict__ fc_b,
                                            float* __restrict__ hfc,
                                            float* __restrict__ st2){
  __shared__ float sA[32 * 128];
  __shared__ float sW[128 * 128];
  __shared__ float redS[8][128], redQ[8][128];
  int t = threadIdx.x;
  int rbase = blockIdx.x * 32;
  #pragma unroll
  for (int i = 0; i < 16; ++i)
    ((float4*)sW)[t + 256 * i] = ((const float4*)fc_w)[t + 256 * i];
  const float inv128 = 1.f / 128.f;
  #pragma unroll
  for (int i = 0; i < 4; ++i){
    int idx = t + 256 * i;
    int r = idx >> 5, c4 = idx & 31;
    float4 v = ((const float4*)(g + (size_t)(rbase + r) * 128))[c4];
    int c0 = c4 * 4;
    float* vv = (float*)&v;
    #pragma unroll
    for (int j = 0; j < 4; ++j){
      float m = st1[c0 + j] * inv128;
      float var = st1[128 + c0 + j] * inv128 - m * m;
      vv[j] = (vv[j] - m) * rsqrtf(var + EPS) + BNB;
    }
    ((float4*)sA)[idx] = v;
  }
  __syncthreads();
  int c0 = (t & 31) * 4, r0 = (t >> 5) * 4;
  float o[4][4];
  float4 bb = *(const float4*)(fc_b + c0);
  #pragma unroll
  for (int i = 0; i < 4; ++i){ o[i][0] = bb.x; o[i][1] = bb.y; o[i][2] = bb.z; o[i][3] = bb.w; }
  for (int k = 0; k < 128; ++k){
    float4 wv = *(const float4*)&sW[k * 128 + c0];
    #pragma unroll
    for (int i = 0; i < 4; ++i){
      float xs = sA[(r0 + i) * 128 + k];
      o[i][0] += xs * wv.x; o[i][1] += xs * wv.y;
      o[i][2] += xs * wv.z; o[i][3] += xs * wv.w;
    }
  }
  float ps[4] = {0, 0, 0, 0}, pq[4] = {0, 0, 0, 0};
  #pragma unroll
  for (int i = 0; i < 4; ++i){
    #pragma unroll
    for (int j = 0; j < 4; ++j){
      float v = fmaxf(o[i][j], 0.f);
      o[i][j] = v;
      ps[j] += v; pq[j] += v * v;
    }
    float4 wv; wv.x = o[i][0]; wv.y = o[i][1]; wv.z = o[i][2]; wv.w = o[i][3];
    *(float4*)(hfc + (size_t)(rbase + r0 + i) * 128 + c0) = wv;
  }
  int g8 = t >> 5;
  #pragma unroll
  for (int j = 0; j < 4; ++j){ redS[g8][c0 + j] = ps[j]; redQ[g8][c0 + j] = pq[j]; }
  __syncthreads();
  if (t < 128){
    float s = 0.f, q = 0.f;
    #pragma unroll
    for (int gg = 0; gg < 8; ++gg){ s += redS[gg][t]; q += redQ[gg][t]; }
    atomicAdd(&st2[t], s);
    atomicAdd(&st2[128 + t], q);
  }
}

// ---------------- head stage 3: BN2-apply -> classifier -> log_softmax ----------------
__global__ __launch_bounds__(1024) void k_h3(const float* __restrict__ hfc,
                                             const float* __restrict__ st2,
                                             const float* __restrict__ cls_w,
                                             const float* __restrict__ cls_b,
                                             float* __restrict__ out){
  __shared__ float A[128 * 128];
  __shared__ float logits[256];
  int t = threadIdx.x;
  #pragma unroll
  for (int i = 0; i < 4; ++i)
    ((float4*)A)[t + 1024 * i] = ((const float4*)hfc)[t + 1024 * i];
  __syncthreads();
  const float inv128 = 1.f / 128.f;
  #pragma unroll
  for (int i = 0; i < 16; ++i){
    int idx = t + 1024 * i;
    int c = idx & 127;
    float m = st2[c] * inv128;
    float var = st2[128 + c] * inv128 - m * m;
    A[idx] = (A[idx] - m) * rsqrtf(var + EPS) + BNB;
  }
  __syncthreads();
  int o = t >> 2, sub = t & 3;
  int r = o >> 1, j = o & 1;
  float acc = 0.f;
  int k0 = sub * 32;
  for (int k = k0; k < k0 + 32; ++k)
    acc += A[r * 128 + k] * cls_w[k * 2 + j];
  acc += __shfl_xor(acc, 1, 64);
  acc += __shfl_xor(acc, 2, 64);
  if (sub == 0) logits[o] = acc + cls_b[j];
  __syncthreads();
  if (t < 256){
    int rr = t >> 1;
    float l0 = logits[rr * 2], l1 = logits[rr * 2 + 1];
    float mx = fmaxf(l0, l1);
    float lse = mx + logf(__expf(l0 - mx) + __expf(l1 - mx));
    out[t] = logits[t] - lse;
  }
}

extern "C" void kernel_launch(void* const* d_in, const int* in_sizes, int n_in,
                              void* d_out, int out_size, void* d_ws, size_t ws_size,
                              hipStream_t stream){
  const float* x        = (const float*)d_in[0];
  const int*   ei       = (const int*)d_in[1];
  const int*   batch    = (const int*)d_in[2];
  const float* gat_lin  = (const float*)d_in[3];
  const float* att_src  = (const float*)d_in[4];
  const float* att_dst  = (const float*)d_in[5];
  const float* gat_bias = (const float*)d_in[6];
  const float* fc_w     = (const float*)d_in[7];
  const float* fc_b     = (const float*)d_in[8];
  const float* cls_w    = (const float*)d_in[9];
  const float* cls_b    = (const float*)d_in[10];
  float* out = (float*)d_out;
  (void)n_in; (void)out_size; (void)ws_size;

  int N = in_sizes[0] / NF;
  int E = in_sizes[1] / 2;
  int total = E + N;
  int nbkt = cdiv(N, 256);
  float inv_n = 1.f / (float)N;

  char* p = (char*)d_ws;
  auto alloc = [&](size_t bytes) -> char* {
    char* r = p;
    p += (bytes + 255) & ~(size_t)255;
    return r;
  };
  int*   off     = (int*)alloc((size_t)(N + 1) * 4);
  int*   bcnt    = (int*)alloc((size_t)nbkt * 4);
  int*   boff    = (int*)alloc((size_t)(nbkt + 1) * 4);
  int*   bcursor = (int*)alloc((size_t)nbkt * 4);
  unsigned* ebuf = (unsigned*)alloc((size_t)total * 4);
  int*   esrc    = (int*)alloc((size_t)total * 4);
  float* stats   = (float*)alloc(8 * 256 * 4);
  float* hbuf    = (float*)alloc((size_t)N * NF * 4);
  unsigned short* hbuf16 = (unsigned short*)alloc((size_t)N * NF * 2);
  unsigned short* tmp16  = (unsigned short*)alloc((size_t)N * NF * 2);
  unsigned short* wbuf16 = (unsigned short*)alloc((size_t)4 * NF * NF * 2);
  float* gout    = (float*)alloc((size_t)N * NF * 4);
  float* a_s     = (float*)alloc((size_t)N * 4 * 4);
  float* a_d     = (float*)alloc((size_t)N * 4 * 4);
  float* gpool   = (float*)alloc(128 * NF * 4);
  float* hfc     = (float*)alloc(128 * NF * 4);

  // CSR build
  k_init<<<256, 256, 0, stream>>>(stats, bcnt, nbkt, 1536, gat_lin, wbuf16);
  k_bhist<<<256, 256, 0, stream>>>(ei, E, N, bcnt, nbkt);
  k_bscan<<<1, 256, 0, stream>>>(bcnt, boff, bcursor, nbkt);
  k_bscatter2<<<cdiv(total, CHUNK), 256, 0, stream>>>(ei, E, N, bcursor, ebuf, nbkt);
  k_bucket<<<nbkt, 256, 0, stream>>>(ebuf, boff, off, esrc, N);

  k_colstats<<<256, 256, 0, stream>>>(x, N, stats);   // stats0 (on x)

  for (int L = 0; L < 4; ++L){
    if (L == 0){
      // stage bn(x) inline (mode 1)
      k_gemm<<<cdiv(N, 128), 512, 0, stream>>>(hbuf16, x, hbuf, stats, inv_n, 1,
                                               wbuf16 + (size_t)L * NF * NF, tmp16,
                                               att_src + (size_t)L * NF, att_dst + (size_t)L * NF,
                                               a_s, a_d, N);
      k_attn<<<cdiv(N, 4), 256, 0, stream>>>(tmp16, a_s, a_d, off, esrc,
                                             gat_bias + (size_t)L * NF,
                                             hbuf, hbuf16, 1, N);
    } else {
      int mode = (L == 1) ? 0 : 2;   // L1 stages h1 (bf16 from attn L0); L2/L3 fuse bn-residual
      k_gemm<<<cdiv(N, 128), 512, 0, stream>>>(hbuf16, gout, hbuf, stats + (L - 1) * 256, inv_n, mode,
                                               wbuf16 + (size_t)L * NF * NF, tmp16,
                                               att_src + (size_t)L * NF, att_dst + (size_t)L * NF,
                                               a_s, a_d, N);
      k_attn<<<cdiv(N, 4), 256, 0, stream>>>(tmp16, a_s, a_d, off, esrc,
                                             gat_bias + (size_t)L * NF,
                                             gout, hbuf16, 0, N);
      k_colstats<<<256, 256, 0, stream>>>(gout, N, stats + L * 256);
    }
  }

  // pool with fused final bn-residual (stats3)
  k_pool<<<128, 256, 0, stream>>>(gout, hbuf, stats + 3 * 256, inv_n, batch, gpool, N);
  k_colstats<<<32, 256, 0, stream>>>(gpool, 128, stats + 1024);
  k_h2<<<4, 256, 0, stream>>>(gpool, stats + 1024, fc_w, fc_b, hfc, stats + 1280);
  k_h3<<<1, 1024, 0, stream>>>(hfc, stats + 1280, cls_w, cls_b, out);
}

// Round 14
// 415.279 us; speedup vs baseline: 1.2418x; 1.0442x over previous
//
#include <hip/hip_runtime.h>
#include <math.h>

#define NF 128
#define EPS 1e-5f
#define BNB 1e-4f
#define CHUNK 8192
#define LOG2E 1.44269504088896f

static inline int cdiv(int a, int b){ return (a + b - 1) / b; }

typedef __attribute__((ext_vector_type(8))) short bf16x8;
typedef __attribute__((ext_vector_type(4))) float f32x4;

__device__ __forceinline__ float lrelu(float x){ return x > 0.f ? x : 0.2f * x; }
__device__ __forceinline__ float sel4(float4 v, int h){
  float r = v.x;
  r = (h == 1) ? v.y : r;
  r = (h == 2) ? v.z : r;
  r = (h == 3) ? v.w : r;
  return r;
}
__device__ __forceinline__ float fast_exp2(float x){
  float r;
  asm("v_exp_f32 %0, %1" : "=v"(r) : "v"(x));
  return r;
}

// f32 -> bf16 round-to-nearest-even (finite inputs)
__device__ __forceinline__ unsigned short f2b(float f){
  unsigned u = __float_as_uint(f);
  u += 0x7fffu + ((u >> 16) & 1u);
  return (unsigned short)(u >> 16);
}
__device__ __forceinline__ unsigned pack2(float a, float b){
  return (unsigned)f2b(a) | ((unsigned)f2b(b) << 16);
}
__device__ __forceinline__ float b2f_lo(unsigned v){ return __uint_as_float(v << 16); }
__device__ __forceinline__ float b2f_hi(unsigned v){ return __uint_as_float(v & 0xffff0000u); }

// ---------------- init: zero stats/bcnt + weight convert/transpose (fused) ----------------
__global__ __launch_bounds__(256) void k_init(float* stats, int* bcnt, int nbkt, int statcount,
                                              const float* __restrict__ W,
                                              unsigned short* __restrict__ Wt){
  int i = blockIdx.x * blockDim.x + threadIdx.x;
  if (i < statcount) stats[i] = 0.f;
  if (i < nbkt) bcnt[i] = 0;
  int l = i >> 14, rem = i & 16383;
  int k = rem >> 7, nn = rem & 127;
  Wt[(l << 14) + nn * 128 + k] = f2b(W[i]);
}

// coarse histogram over buckets (dst>>8), LDS-aggregated
__global__ __launch_bounds__(256) void k_bhist(const int* __restrict__ ei, int E, int n,
                                               int* __restrict__ bcnt, int nbkt){
  __shared__ int h[256];
  h[threadIdx.x] = 0;
  __syncthreads();
  int total = E + n;
  for (int i = blockIdx.x * 256 + threadIdx.x; i < total; i += gridDim.x * 256){
    int d = (i < E) ? ei[E + i] : (i - E);
    atomicAdd(&h[d >> 8], 1);
  }
  __syncthreads();
  if (threadIdx.x < nbkt && h[threadIdx.x]) atomicAdd(&bcnt[threadIdx.x], h[threadIdx.x]);
}

// 1-block exclusive scan over nbkt (<=256) bucket counts -> boff, bcursor
__global__ __launch_bounds__(256) void k_bscan(const int* __restrict__ bcnt, int* __restrict__ boff,
                                               int* __restrict__ bcursor, int nb){
  int t = threadIdx.x;
  int v = (t < nb) ? bcnt[t] : 0;
  int lane = t & 63, w = t >> 6;
  int x = v;
  #pragma unroll
  for (int d = 1; d < 64; d <<= 1){
    int y = __shfl_up(x, d, 64);
    if (lane >= d) x += y;
  }
  __shared__ int wt[4], wex[4];
  if (lane == 63) wt[w] = x;
  __syncthreads();
  if (t == 0){ int r = 0; for (int i = 0; i < 4; ++i){ wex[i] = r; r += wt[i]; } }
  __syncthreads();
  int ex = wex[w] + x - v;
  if (t < nb){ boff[t] = ex; bcursor[t] = ex; }
  if (t == nb - 1) boff[nb] = ex + v;
}

// chunked scatter: per block, LDS hist -> one reservation atomic per bucket -> ranked write.
__global__ __launch_bounds__(256) void k_bscatter2(const int* __restrict__ ei, int E, int n,
                                                   int* __restrict__ bcursor,
                                                   unsigned* __restrict__ ebuf, int nbkt){
  __shared__ int h[256], base[256];
  int t = threadIdx.x;
  int total = E + n;
  int lo = blockIdx.x * CHUNK;
  int hi = min(lo + CHUNK, total);
  h[t] = 0;
  __syncthreads();
  for (int i = lo + t; i < hi; i += 256){
    int d = (i < E) ? ei[E + i] : (i - E);
    atomicAdd(&h[d >> 8], 1);
  }
  __syncthreads();
  int cnt = h[t];
  if (t < nbkt && cnt > 0) base[t] = atomicAdd(&bcursor[t], cnt);
  __syncthreads();
  h[t] = 0;
  __syncthreads();
  for (int i = lo + t; i < hi; i += 256){
    int s, d;
    if (i < E){ s = ei[i]; d = ei[E + i]; }
    else { s = i - E; d = s; }
    int b = d >> 8;
    int r = atomicAdd(&h[b], 1);
    ebuf[base[b] + r] = ((unsigned)s << 8) | (unsigned)(d & 255);
  }
}

// fused per-bucket CSR finisher: deg hist -> in-block scan -> off write -> ranked scatter.
__global__ __launch_bounds__(256) void k_bucket(const unsigned* __restrict__ ebuf,
                                                const int* __restrict__ boff,
                                                int* __restrict__ off,
                                                int* __restrict__ esrc, int n){
  __shared__ int h[256], sbase[256];
  __shared__ int wt[4], wex[4];
  int t = threadIdx.x, b = blockIdx.x;
  int lo = boff[b], hi = boff[b + 1];
  h[t] = 0;
  __syncthreads();
  for (int i = lo + t; i < hi; i += 256) atomicAdd(&h[ebuf[i] & 255u], 1);
  __syncthreads();
  int v = h[t];
  int lane = t & 63, w = t >> 6;
  int x = v;
  #pragma unroll
  for (int d = 1; d < 64; d <<= 1){
    int y = __shfl_up(x, d, 64);
    if (lane >= d) x += y;
  }
  if (lane == 63) wt[w] = x;
  __syncthreads();
  if (t == 0){ int r = 0; for (int i = 0; i < 4; ++i){ wex[i] = r; r += wt[i]; } }
  __syncthreads();
  int base = lo + wex[w] + (x - v);
  int node = b * 256 + t;
  if (node < n) off[node] = base;
  if (node == n - 1) off[n] = base + v;
  sbase[t] = base;
  __syncthreads();
  h[t] = 0;
  __syncthreads();
  for (int i = lo + t; i < hi; i += 256){
    unsigned pk = ebuf[i];
    int ld = (int)(pk & 255u);
    int s  = (int)(pk >> 8);
    int r = atomicAdd(&h[ld], 1);
    esrc[sbase[ld] + r] = s;
  }
}

// ---------------- BN column stats (sum, sumsq into out[0..127], out[128..255]) ----------------
__global__ __launch_bounds__(256) void k_colstats(const float* __restrict__ X, int n, float* __restrict__ out){
  __shared__ float ss[4][128], sq[4][128];
  int t = threadIdx.x, lane = t & 63, w = t >> 6;
  float sx = 0.f, sy = 0.f, qx = 0.f, qy = 0.f;
  for (int r = blockIdx.x * 4 + w; r < n; r += gridDim.x * 4){
    float2 v = *(const float2*)(X + (size_t)r * NF + lane * 2);
    sx += v.x; sy += v.y; qx += v.x * v.x; qy += v.y * v.y;
  }
  ss[w][lane * 2] = sx; ss[w][lane * 2 + 1] = sy;
  sq[w][lane * 2] = qx; sq[w][lane * 2 + 1] = qy;
  __syncthreads();
  if (t < 128){
    float tot = ss[0][t] + ss[1][t] + ss[2][t] + ss[3][t];
    atomicAdd(&out[t], tot);
  } else {
    int c = t - 128;
    float tot = sq[0][c] + sq[1][c] + sq[2][c] + sq[3][c];
    atomicAdd(&out[128 + c], tot);
  }
}

// ---------------- MFMA GEMM (128-row blocks, 8 waves) with fused BN staging + att-vec epilogue ----
__global__ __launch_bounds__(512) void k_gemm(const unsigned short* __restrict__ X16,
                                              const float* __restrict__ Xa,
                                              float* __restrict__ Xb,
                                              const float* __restrict__ stats, float inv_n,
                                              int mode,
                                              const unsigned short* __restrict__ Wt,
                                              unsigned short* __restrict__ Y,
                                              const float* __restrict__ asrc,
                                              const float* __restrict__ adst,
                                              float* __restrict__ a_s,
                                              float* __restrict__ a_d, int n){
  __shared__ unsigned short sX[128 * 128];   // 32 KB, XOR-swizzled 16B units
  __shared__ unsigned short sW[128 * 128];   // 32 KB, [n][k], XOR-swizzled
  int t = threadIdx.x;
  int rbase = blockIdx.x * 128;
  #pragma unroll
  for (int i = 0; i < 4; ++i){               // stage Wt: 2048 uint4 / 512
    int idx = t + 512 * i;
    int rn = idx >> 4, c16 = idx & 15;
    uint4 v = ((const uint4*)Wt)[idx];
    *(uint4*)&sW[rn * 128 + ((c16 ^ (rn & 7)) << 3)] = v;
  }
  if (mode == 0){
    #pragma unroll
    for (int i = 0; i < 4; ++i){
      int idx = t + 512 * i;
      int r = idx >> 4, c16 = idx & 15;
      int gr = rbase + r;
      uint4 v = (gr < n) ? ((const uint4*)(X16 + (size_t)gr * NF))[c16] : make_uint4(0, 0, 0, 0);
      *(uint4*)&sX[r * 128 + ((c16 ^ (r & 7)) << 3)] = v;
    }
  } else {
    #pragma unroll
    for (int i = 0; i < 4; ++i){
      int idx = t + 512 * i;
      int r = idx >> 4, c16 = idx & 15;
      int gr = rbase + r;
      int c = c16 * 8;
      float z[8];
      if (gr < n){
        float4 va = *(const float4*)(Xa + (size_t)gr * NF + c);
        float4 vb = *(const float4*)(Xa + (size_t)gr * NF + c + 4);
        float4 m1 = *(const float4*)(stats + c);
        float4 m2 = *(const float4*)(stats + c + 4);
        float4 q1 = *(const float4*)(stats + 128 + c);
        float4 q2 = *(const float4*)(stats + 128 + c + 4);
        const float* pa = (const float*)&va; const float* pb = (const float*)&vb;
        const float* pm1 = (const float*)&m1; const float* pm2 = (const float*)&m2;
        const float* pq1 = (const float*)&q1; const float* pq2 = (const float*)&q2;
        #pragma unroll
        for (int j = 0; j < 4; ++j){
          float m = pm1[j] * inv_n;
          float var = pq1[j] * inv_n - m * m;
          z[j] = (pa[j] - m) * rsqrtf(var + EPS) + BNB;
          float m_ = pm2[j] * inv_n;
          float var_ = pq2[j] * inv_n - m_ * m_;
          z[4 + j] = (pb[j] - m_) * rsqrtf(var_ + EPS) + BNB;
        }
        if (mode == 2){
          float4 ha = *(const float4*)(Xb + (size_t)gr * NF + c);
          float4 hb = *(const float4*)(Xb + (size_t)gr * NF + c + 4);
          const float* ph1 = (const float*)&ha; const float* ph2 = (const float*)&hb;
          #pragma unroll
          for (int j = 0; j < 4; ++j){
            z[j]     = fmaxf(z[j]     + ph1[j], 0.f);
            z[4 + j] = fmaxf(z[4 + j] + ph2[j], 0.f);
          }
          float4 o1, o2;
          o1.x = z[0]; o1.y = z[1]; o1.z = z[2]; o1.w = z[3];
          o2.x = z[4]; o2.y = z[5]; o2.z = z[6]; o2.w = z[7];
          *(float4*)(Xb + (size_t)gr * NF + c) = o1;
          *(float4*)(Xb + (size_t)gr * NF + c + 4) = o2;
        }
      } else {
        #pragma unroll
        for (int j = 0; j < 8; ++j) z[j] = 0.f;
      }
      uint4 u;
      u.x = pack2(z[0], z[1]); u.y = pack2(z[2], z[3]);
      u.z = pack2(z[4], z[5]); u.w = pack2(z[6], z[7]);
      *(uint4*)&sX[r * 128 + ((c16 ^ (r & 7)) << 3)] = u;
    }
  }
  __syncthreads();
  int lane = t & 63, w = t >> 6;
  int lrow = w * 16 + (lane & 15);
  int khi = lane >> 4;
  bf16x8 a[4];
  #pragma unroll
  for (int ks = 0; ks < 4; ++ks){
    int c16 = ks * 4 + khi;
    a[ks] = *(const bf16x8*)&sX[lrow * 128 + ((c16 ^ (lrow & 7)) << 3)];
  }
  f32x4 acc[8];
  #pragma unroll
  for (int nt = 0; nt < 8; ++nt){
    f32x4 z = {0.f, 0.f, 0.f, 0.f};
    acc[nt] = z;
    int nrow = nt * 16 + (lane & 15);
    #pragma unroll
    for (int ks = 0; ks < 4; ++ks){
      int c16 = ks * 4 + khi;
      bf16x8 b = *(const bf16x8*)&sW[nrow * 128 + ((c16 ^ (nrow & 7)) << 3)];
      acc[nt] = __builtin_amdgcn_mfma_f32_16x16x32_bf16(a[ks], b, acc[nt], 0, 0, 0);
    }
  }
  #pragma unroll
  for (int nt = 0; nt < 8; ++nt){
    #pragma unroll
    for (int i = 0; i < 4; ++i){
      int r = w * 16 + (khi << 2) + i;
      int c = nt * 16 + (lane & 15);
      int csw = c ^ ((r & 7) << 3);
      sX[r * 128 + csw] = f2b(acc[nt][i]);
    }
  }
  __syncthreads();
  #pragma unroll
  for (int i = 0; i < 4; ++i){
    int idx = t + 512 * i;
    int r = idx >> 4, c16 = idx & 15;
    int gr = rbase + r;
    if (gr < n)
      ((uint4*)(Y + (size_t)gr * NF))[c16] = *(const uint4*)&sX[r * 128 + ((c16 ^ (r & 7)) << 3)];
  }
  // fused att-vec (pre-scaled by log2e for v_exp_f32 in attn)
  int r = t >> 2, hh = t & 3;
  int gr = rbase + r;
  if (gr < n){
    float ps = 0.f, pd = 0.f;
    #pragma unroll
    for (int j = 0; j < 16; ++j){
      int c = hh * 32 + j * 2;
      int u = (c >> 3) ^ (r & 7);
      unsigned v = *(const unsigned*)&sX[r * 128 + (u << 3) + (c & 7)];
      float vx = b2f_lo(v), vy = b2f_hi(v);
      ps += vx * asrc[c] + vy * asrc[c + 1];
      pd += vx * adst[c] + vy * adst[c + 1];
    }
    a_s[(size_t)gr * 4 + hh] = ps * LOG2E;
    a_d[(size_t)gr * 4 + hh] = pd * LOG2E;
  }
}

// ---------------- attention: inline alpha (raw v_exp_f32, no-max), main/tail split ----------------
__global__ __launch_bounds__(256) void k_attn(const unsigned short* __restrict__ Hm16,
                                              const float* __restrict__ a_s,
                                              const float* __restrict__ a_d,
                                              const int* __restrict__ off,
                                              const int* __restrict__ esrc,
                                              const float* __restrict__ bias,
                                              float* __restrict__ Yf,
                                              unsigned short* __restrict__ Y16,
                                              int dorelu, int n){
  int t = threadIdx.x, lane = t & 63, w = t >> 6;
  int node = blockIdx.x * 4 + w;
  if (node >= n) return;
  node = __builtin_amdgcn_readfirstlane(node);
  int head = lane >> 4;
  float4 ad4 = ((const float4*)a_d)[node];
  float adh = sel4(ad4, head);
  int lo = off[node], hi = off[node + 1];
  lo = __builtin_amdgcn_readfirstlane(lo);
  hi = __builtin_amdgcn_readfirstlane(hi);
  int fo = lane * 2;
  float sum = 0.f, ax = 0.f, ay = 0.f;
  int e = lo;
  for (; e + 8 <= hi; e += 8){
    int si[8]; float ai[8]; unsigned vi[8];
    #pragma unroll
    for (int k = 0; k < 8; ++k) si[k] = esrc[e + k];
    #pragma unroll
    for (int k = 0; k < 8; ++k) ai[k] = a_s[(si[k] << 2) + head];
    #pragma unroll
    for (int k = 0; k < 8; ++k) vi[k] = *(const unsigned*)(Hm16 + (size_t)si[k] * NF + fo);
    #pragma unroll
    for (int k = 0; k < 8; ++k){
      float wgt = fast_exp2(lrelu(ai[k] + adh));
      sum += wgt;
      ax += wgt * b2f_lo(vi[k]);
      ay += wgt * b2f_hi(vi[k]);
    }
  }
  if (e < hi){
    int si[8]; float ai[8]; unsigned vi[8];
    #pragma unroll
    for (int k = 0; k < 8; ++k) si[k] = esrc[min(e + k, hi - 1)];
    #pragma unroll
    for (int k = 0; k < 8; ++k) ai[k] = a_s[(si[k] << 2) + head];
    #pragma unroll
    for (int k = 0; k < 8; ++k) vi[k] = *(const unsigned*)(Hm16 + (size_t)si[k] * NF + fo);
    #pragma unroll
    for (int k = 0; k < 8; ++k){
      float wgt = (e + k < hi) ? fast_exp2(lrelu(ai[k] + adh)) : 0.f;
      sum += wgt;
      ax += wgt * b2f_lo(vi[k]);
      ay += wgt * b2f_hi(vi[k]);
    }
  }
  float inv = 1.f / (sum + 1e-16f);
  float2 b = *(const float2*)(bias + fo);
  float rx = ax * inv + b.x;
  float ry = ay * inv + b.y;
  if (dorelu){
    rx = fmaxf(rx, 0.f); ry = fmaxf(ry, 0.f);
    ushort2 pk; pk.x = f2b(rx); pk.y = f2b(ry);
    *(ushort2*)(Y16 + (size_t)node * NF + fo) = pk;
  }
  float2 r; r.x = rx; r.y = ry;
  *(float2*)(Yf + (size_t)node * NF + fo) = r;
}

// ---------------- pooling with fused final bn-residual: z = relu(bn(G)+H), per-graph sum ----------------
__global__ __launch_bounds__(256) void k_pool(const float* __restrict__ G,
                                              const float* __restrict__ H,
                                              const float* __restrict__ stats, float inv_n,
                                              const int* __restrict__ batch,
                                              float* __restrict__ g, int n){
  int gid = blockIdx.x;
  int t = threadIdx.x, lane = t & 63, w = t >> 6;
  int lo = 0, hi = n;
  while (lo < hi){ int mid = (lo + hi) >> 1; if (batch[mid] < gid) lo = mid + 1; else hi = mid; }
  int a = lo, b = n;
  while (a < b){ int mid = (a + b) >> 1; if (batch[mid] < gid + 1) a = mid + 1; else b = mid; }
  int c = lane * 2;
  float m0 = stats[c] * inv_n,     q0 = stats[128 + c] * inv_n;
  float m1 = stats[c + 1] * inv_n, q1 = stats[128 + c + 1] * inv_n;
  float rs0 = rsqrtf(q0 - m0 * m0 + EPS);
  float rs1 = rsqrtf(q1 - m1 * m1 + EPS);
  float sx = 0.f, sy = 0.f;
  for (int r = lo + w; r < a; r += 4){
    float2 gv = *(const float2*)(G + (size_t)r * NF + c);
    float2 hv = *(const float2*)(H + (size_t)r * NF + c);
    sx += fmaxf((gv.x - m0) * rs0 + BNB + hv.x, 0.f);
    sy += fmaxf((gv.y - m1) * rs1 + BNB + hv.y, 0.f);
  }
  __shared__ float ss[4][128];
  ss[w][lane * 2] = sx; ss[w][lane * 2 + 1] = sy;
  __syncthreads();
  if (t < 128) g[(size_t)gid * NF + t] = ss[0][t] + ss[1][t] + ss[2][t] + ss[3][t];
}

// ---------------- head stage 2: BN1-apply -> fc (LDS weights) -> relu -> BN2 partial stats ----------------
__global__ __launch_bounds__(256) void k_h2(const float* __restrict__ g,
                                            const float* __restrict__ st1,
                                            const float* __restrict__ fc_w,
                                            const float* __restrict__ fc_b,
                                            float* __restrict__ hfc,
                                            float* __restrict__ st2){
  __shared__ float sA[32 * 128];
  __shared__ float sW[128 * 128];
  __shared__ float redS[8][128], redQ[8][128];
  int t = threadIdx.x;
  int rbase = blockIdx.x * 32;
  #pragma unroll
  for (int i = 0; i < 16; ++i)
    ((float4*)sW)[t + 256 * i] = ((const float4*)fc_w)[t + 256 * i];
  const float inv128 = 1.f / 128.f;
  #pragma unroll
  for (int i = 0; i < 4; ++i){
    int idx = t + 256 * i;
    int r = idx >> 5, c4 = idx & 31;
    float4 v = ((const float4*)(g + (size_t)(rbase + r) * 128))[c4];
    int c0 = c4 * 4;
    float* vv = (float*)&v;
    #pragma unroll
    for (int j = 0; j < 4; ++j){
      float m = st1[c0 + j] * inv128;
      float var = st1[128 + c0 + j] * inv128 - m * m;
      vv[j] = (vv[j] - m) * rsqrtf(var + EPS) + BNB;
    }
    ((float4*)sA)[idx] = v;
  }
  __syncthreads();
  int c0 = (t & 31) * 4, r0 = (t >> 5) * 4;
  float o[4][4];
  float4 bb = *(const float4*)(fc_b + c0);
  #pragma unroll
  for (int i = 0; i < 4; ++i){ o[i][0] = bb.x; o[i][1] = bb.y; o[i][2] = bb.z; o[i][3] = bb.w; }
  for (int k = 0; k < 128; ++k){
    float4 wv = *(const float4*)&sW[k * 128 + c0];
    #pragma unroll
    for (int i = 0; i < 4; ++i){
      float xs = sA[(r0 + i) * 128 + k];
      o[i][0] += xs * wv.x; o[i][1] += xs * wv.y;
      o[i][2] += xs * wv.z; o[i][3] += xs * wv.w;
    }
  }
  float ps[4] = {0, 0, 0, 0}, pq[4] = {0, 0, 0, 0};
  #pragma unroll
  for (int i = 0; i < 4; ++i){
    #pragma unroll
    for (int j = 0; j < 4; ++j){
      float v = fmaxf(o[i][j], 0.f);
      o[i][j] = v;
      ps[j] += v; pq[j] += v * v;
    }
    float4 wv; wv.x = o[i][0]; wv.y = o[i][1]; wv.z = o[i][2]; wv.w = o[i][3];
    *(float4*)(hfc + (size_t)(rbase + r0 + i) * 128 + c0) = wv;
  }
  int g8 = t >> 5;
  #pragma unroll
  for (int j = 0; j < 4; ++j){ redS[g8][c0 + j] = ps[j]; redQ[g8][c0 + j] = pq[j]; }
  __syncthreads();
  if (t < 128){
    float s = 0.f, q = 0.f;
    #pragma unroll
    for (int gg = 0; gg < 8; ++gg){ s += redS[gg][t]; q += redQ[gg][t]; }
    atomicAdd(&st2[t], s);
    atomicAdd(&st2[128 + t], q);
  }
}

// ---------------- head stage 3: BN2-apply -> classifier -> log_softmax ----------------
__global__ __launch_bounds__(1024) void k_h3(const float* __restrict__ hfc,
                                             const float* __restrict__ st2,
                                             const float* __restrict__ cls_w,
                                             const float* __restrict__ cls_b,
                                             float* __restrict__ out){
  __shared__ float A[128 * 128];
  __shared__ float logits[256];
  int t = threadIdx.x;
  #pragma unroll
  for (int i = 0; i < 4; ++i)
    ((float4*)A)[t + 1024 * i] = ((const float4*)hfc)[t + 1024 * i];
  __syncthreads();
  const float inv128 = 1.f / 128.f;
  #pragma unroll
  for (int i = 0; i < 16; ++i){
    int idx = t + 1024 * i;
    int c = idx & 127;
    float m = st2[c] * inv128;
    float var = st2[128 + c] * inv128 - m * m;
    A[idx] = (A[idx] - m) * rsqrtf(var + EPS) + BNB;
  }
  __syncthreads();
  int o = t >> 2, sub = t & 3;
  int r = o >> 1, j = o & 1;
  float acc = 0.f;
  int k0 = sub * 32;
  for (int k = k0; k < k0 + 32; ++k)
    acc += A[r * 128 + k] * cls_w[k * 2 + j];
  acc += __shfl_xor(acc, 1, 64);
  acc += __shfl_xor(acc, 2, 64);
  if (sub == 0) logits[o] = acc + cls_b[j];
  __syncthreads();
  if (t < 256){
    int rr = t >> 1;
    float l0 = logits[rr * 2], l1 = logits[rr * 2 + 1];
    float mx = fmaxf(l0, l1);
    float lse = mx + logf(__expf(l0 - mx) + __expf(l1 - mx));
    out[t] = logits[t] - lse;
  }
}

extern "C" void kernel_launch(void* const* d_in, const int* in_sizes, int n_in,
                              void* d_out, int out_size, void* d_ws, size_t ws_size,
                              hipStream_t stream){
  const float* x        = (const float*)d_in[0];
  const int*   ei       = (const int*)d_in[1];
  const int*   batch    = (const int*)d_in[2];
  const float* gat_lin  = (const float*)d_in[3];
  const float* att_src  = (const float*)d_in[4];
  const float* att_dst  = (const float*)d_in[5];
  const float* gat_bias = (const float*)d_in[6];
  const float* fc_w     = (const float*)d_in[7];
  const float* fc_b     = (const float*)d_in[8];
  const float* cls_w    = (const float*)d_in[9];
  const float* cls_b    = (const float*)d_in[10];
  float* out = (float*)d_out;
  (void)n_in; (void)out_size; (void)ws_size;

  int N = in_sizes[0] / NF;
  int E = in_sizes[1] / 2;
  int total = E + N;
  int nbkt = cdiv(N, 256);
  float inv_n = 1.f / (float)N;

  char* p = (char*)d_ws;
  auto alloc = [&](size_t bytes) -> char* {
    char* r = p;
    p += (bytes + 255) & ~(size_t)255;
    return r;
  };
  int*   off     = (int*)alloc((size_t)(N + 1) * 4);
  int*   bcnt    = (int*)alloc((size_t)nbkt * 4);
  int*   boff    = (int*)alloc((size_t)(nbkt + 1) * 4);
  int*   bcursor = (int*)alloc((size_t)nbkt * 4);
  unsigned* ebuf = (unsigned*)alloc((size_t)total * 4);
  int*   esrc    = (int*)alloc((size_t)total * 4);
  float* stats   = (float*)alloc(8 * 256 * 4);
  float* hbuf    = (float*)alloc((size_t)N * NF * 4);
  unsigned short* hbuf16 = (unsigned short*)alloc((size_t)N * NF * 2);
  unsigned short* tmp16  = (unsigned short*)alloc((size_t)N * NF * 2);
  unsigned short* wbuf16 = (unsigned short*)alloc((size_t)4 * NF * NF * 2);
  float* gout    = (float*)alloc((size_t)N * NF * 4);
  float* a_s     = (float*)alloc((size_t)N * 4 * 4);
  float* a_d     = (float*)alloc((size_t)N * 4 * 4);
  float* gpool   = (float*)alloc(128 * NF * 4);
  float* hfc     = (float*)alloc(128 * NF * 4);

  // CSR build
  k_init<<<256, 256, 0, stream>>>(stats, bcnt, nbkt, 1536, gat_lin, wbuf16);
  k_bhist<<<256, 256, 0, stream>>>(ei, E, N, bcnt, nbkt);
  k_bscan<<<1, 256, 0, stream>>>(bcnt, boff, bcursor, nbkt);
  k_bscatter2<<<cdiv(total, CHUNK), 256, 0, stream>>>(ei, E, N, bcursor, ebuf, nbkt);
  k_bucket<<<nbkt, 256, 0, stream>>>(ebuf, boff, off, esrc, N);

  k_colstats<<<256, 256, 0, stream>>>(x, N, stats);   // stats0 (on x)

  for (int L = 0; L < 4; ++L){
    if (L == 0){
      k_gemm<<<cdiv(N, 128), 512, 0, stream>>>(hbuf16, x, hbuf, stats, inv_n, 1,
                                               wbuf16 + (size_t)L * NF * NF, tmp16,
                                               att_src + (size_t)L * NF, att_dst + (size_t)L * NF,
                                               a_s, a_d, N);
      k_attn<<<cdiv(N, 4), 256, 0, stream>>>(tmp16, a_s, a_d, off, esrc,
                                             gat_bias + (size_t)L * NF,
                                             hbuf, hbuf16, 1, N);
    } else {
      int mode = (L == 1) ? 0 : 2;
      k_gemm<<<cdiv(N, 128), 512, 0, stream>>>(hbuf16, gout, hbuf, stats + (L - 1) * 256, inv_n, mode,
                                               wbuf16 + (size_t)L * NF * NF, tmp16,
                                               att_src + (size_t)L * NF, att_dst + (size_t)L * NF,
                                               a_s, a_d, N);
      k_attn<<<cdiv(N, 4), 256, 0, stream>>>(tmp16, a_s, a_d, off, esrc,
                                             gat_bias + (size_t)L * NF,
                                             gout, hbuf16, 0, N);
      k_colstats<<<256, 256, 0, stream>>>(gout, N, stats + L * 256);
    }
  }

  k_pool<<<128, 256, 0, stream>>>(gout, hbuf, stats + 3 * 256, inv_n, batch, gpool, N);
  k_colstats<<<32, 256, 0, stream>>>(gpool, 128, stats + 1024);
  k_h2<<<4, 256, 0, stream>>>(gpool, stats + 1024, fc_w, fc_b, hfc, stats + 1280);
  k_h3<<<1, 1024, 0, stream>>>(hfc, stats + 1280, cls_w, cls_b, out);
}

// Round 15
// 384.046 us; speedup vs baseline: 1.3428x; 1.0813x over previous
//
#include <hip/hip_runtime.h>
#include <math.h>

#define NF 128
#define EPS 1e-5f
#define BNB 1e-4f
#define CHUNK 8192
#define LOG2E 1.44269504088896f

static inline int cdiv(int a, int b){ return (a + b - 1) / b; }

typedef __attribute__((ext_vector_type(8))) short bf16x8;
typedef __attribute__((ext_vector_type(4))) float f32x4;

__device__ __forceinline__ float lrelu(float x){ return x > 0.f ? x : 0.2f * x; }
__device__ __forceinline__ float sel4(float4 v, int h){
  float r = v.x;
  r = (h == 1) ? v.y : r;
  r = (h == 2) ? v.z : r;
  r = (h == 3) ? v.w : r;
  return r;
}
__device__ __forceinline__ float fast_exp2(float x){
  float r;
  asm("v_exp_f32 %0, %1" : "=v"(r) : "v"(x));
  return r;
}

// f32 -> bf16 round-to-nearest-even (finite inputs)
__device__ __forceinline__ unsigned short f2b(float f){
  unsigned u = __float_as_uint(f);
  u += 0x7fffu + ((u >> 16) & 1u);
  return (unsigned short)(u >> 16);
}
__device__ __forceinline__ unsigned pack2(float a, float b){
  return (unsigned)f2b(a) | ((unsigned)f2b(b) << 16);
}
__device__ __forceinline__ float b2f_lo(unsigned v){ return __uint_as_float(v << 16); }
__device__ __forceinline__ float b2f_hi(unsigned v){ return __uint_as_float(v & 0xffff0000u); }

// ---------------- init: zero stats/bcnt/gpool + weight convert/transpose (fused) ----------------
__global__ __launch_bounds__(256) void k_init(float* stats, int* bcnt, int nbkt, int statcount,
                                              float* gpool,
                                              const float* __restrict__ W,
                                              unsigned short* __restrict__ Wt){
  int i = blockIdx.x * blockDim.x + threadIdx.x;
  if (i < statcount) stats[i] = 0.f;
  if (i < nbkt) bcnt[i] = 0;
  if (i < 16384) gpool[i] = 0.f;
  int l = i >> 14, rem = i & 16383;
  int k = rem >> 7, nn = rem & 127;
  Wt[(l << 14) + nn * 128 + k] = f2b(W[i]);
}

// coarse histogram over buckets (dst>>8), LDS-aggregated
__global__ __launch_bounds__(256) void k_bhist(const int* __restrict__ ei, int E, int n,
                                               int* __restrict__ bcnt, int nbkt){
  __shared__ int h[256];
  h[threadIdx.x] = 0;
  __syncthreads();
  int total = E + n;
  for (int i = blockIdx.x * 256 + threadIdx.x; i < total; i += gridDim.x * 256){
    int d = (i < E) ? ei[E + i] : (i - E);
    atomicAdd(&h[d >> 8], 1);
  }
  __syncthreads();
  if (threadIdx.x < nbkt && h[threadIdx.x]) atomicAdd(&bcnt[threadIdx.x], h[threadIdx.x]);
}

// 1-block exclusive scan over nbkt (<=256) bucket counts -> boff, bcursor
__global__ __launch_bounds__(256) void k_bscan(const int* __restrict__ bcnt, int* __restrict__ boff,
                                               int* __restrict__ bcursor, int nb){
  int t = threadIdx.x;
  int v = (t < nb) ? bcnt[t] : 0;
  int lane = t & 63, w = t >> 6;
  int x = v;
  #pragma unroll
  for (int d = 1; d < 64; d <<= 1){
    int y = __shfl_up(x, d, 64);
    if (lane >= d) x += y;
  }
  __shared__ int wt[4], wex[4];
  if (lane == 63) wt[w] = x;
  __syncthreads();
  if (t == 0){ int r = 0; for (int i = 0; i < 4; ++i){ wex[i] = r; r += wt[i]; } }
  __syncthreads();
  int ex = wex[w] + x - v;
  if (t < nb){ boff[t] = ex; bcursor[t] = ex; }
  if (t == nb - 1) boff[nb] = ex + v;
}

// chunked scatter: per block, LDS hist -> one reservation atomic per bucket -> ranked write.
__global__ __launch_bounds__(256) void k_bscatter2(const int* __restrict__ ei, int E, int n,
                                                   int* __restrict__ bcursor,
                                                   unsigned* __restrict__ ebuf, int nbkt){
  __shared__ int h[256], base[256];
  int t = threadIdx.x;
  int total = E + n;
  int lo = blockIdx.x * CHUNK;
  int hi = min(lo + CHUNK, total);
  h[t] = 0;
  __syncthreads();
  for (int i = lo + t; i < hi; i += 256){
    int d = (i < E) ? ei[E + i] : (i - E);
    atomicAdd(&h[d >> 8], 1);
  }
  __syncthreads();
  int cnt = h[t];
  if (t < nbkt && cnt > 0) base[t] = atomicAdd(&bcursor[t], cnt);
  __syncthreads();
  h[t] = 0;
  __syncthreads();
  for (int i = lo + t; i < hi; i += 256){
    int s, d;
    if (i < E){ s = ei[i]; d = ei[E + i]; }
    else { s = i - E; d = s; }
    int b = d >> 8;
    int r = atomicAdd(&h[b], 1);
    ebuf[base[b] + r] = ((unsigned)s << 8) | (unsigned)(d & 255);
  }
}

// fused per-bucket CSR finisher: deg hist -> in-block scan -> off write -> ranked scatter.
__global__ __launch_bounds__(256) void k_bucket(const unsigned* __restrict__ ebuf,
                                                const int* __restrict__ boff,
                                                int* __restrict__ off,
                                                int* __restrict__ esrc, int n){
  __shared__ int h[256], sbase[256];
  __shared__ int wt[4], wex[4];
  int t = threadIdx.x, b = blockIdx.x;
  int lo = boff[b], hi = boff[b + 1];
  h[t] = 0;
  __syncthreads();
  for (int i = lo + t; i < hi; i += 256) atomicAdd(&h[ebuf[i] & 255u], 1);
  __syncthreads();
  int v = h[t];
  int lane = t & 63, w = t >> 6;
  int x = v;
  #pragma unroll
  for (int d = 1; d < 64; d <<= 1){
    int y = __shfl_up(x, d, 64);
    if (lane >= d) x += y;
  }
  if (lane == 63) wt[w] = x;
  __syncthreads();
  if (t == 0){ int r = 0; for (int i = 0; i < 4; ++i){ wex[i] = r; r += wt[i]; } }
  __syncthreads();
  int base = lo + wex[w] + (x - v);
  int node = b * 256 + t;
  if (node < n) off[node] = base;
  if (node == n - 1) off[n] = base + v;
  sbase[t] = base;
  __syncthreads();
  h[t] = 0;
  __syncthreads();
  for (int i = lo + t; i < hi; i += 256){
    unsigned pk = ebuf[i];
    int ld = (int)(pk & 255u);
    int s  = (int)(pk >> 8);
    int r = atomicAdd(&h[ld], 1);
    esrc[sbase[ld] + r] = s;
  }
}

// ---------------- BN column stats (sum, sumsq into out[0..127], out[128..255]) ----------------
__global__ __launch_bounds__(256) void k_colstats(const float* __restrict__ X, int n, float* __restrict__ out){
  __shared__ float ss[4][128], sq[4][128];
  int t = threadIdx.x, lane = t & 63, w = t >> 6;
  float sx = 0.f, sy = 0.f, qx = 0.f, qy = 0.f;
  for (int r = blockIdx.x * 4 + w; r < n; r += gridDim.x * 4){
    float2 v = *(const float2*)(X + (size_t)r * NF + lane * 2);
    sx += v.x; sy += v.y; qx += v.x * v.x; qy += v.y * v.y;
  }
  ss[w][lane * 2] = sx; ss[w][lane * 2 + 1] = sy;
  sq[w][lane * 2] = qx; sq[w][lane * 2 + 1] = qy;
  __syncthreads();
  if (t < 128){
    float tot = ss[0][t] + ss[1][t] + ss[2][t] + ss[3][t];
    atomicAdd(&out[t], tot);
  } else {
    int c = t - 128;
    float tot = sq[0][c] + sq[1][c] + sq[2][c] + sq[3][c];
    atomicAdd(&out[128 + c], tot);
  }
}

// ---------------- MFMA GEMM (128-row blocks, 8 waves) with fused BN staging + att-vec epilogue ----
__global__ __launch_bounds__(512) void k_gemm(const unsigned short* __restrict__ X16,
                                              const float* __restrict__ Xa,
                                              float* __restrict__ Xb,
                                              const float* __restrict__ stats, float inv_n,
                                              int mode,
                                              const unsigned short* __restrict__ Wt,
                                              unsigned short* __restrict__ Y,
                                              const float* __restrict__ asrc,
                                              const float* __restrict__ adst,
                                              float* __restrict__ a_s,
                                              float* __restrict__ a_d, int n){
  __shared__ unsigned short sX[128 * 128];   // 32 KB, XOR-swizzled 16B units
  __shared__ unsigned short sW[128 * 128];   // 32 KB, [n][k], XOR-swizzled
  int t = threadIdx.x;
  int rbase = blockIdx.x * 128;
  #pragma unroll
  for (int i = 0; i < 4; ++i){               // stage Wt: 2048 uint4 / 512
    int idx = t + 512 * i;
    int rn = idx >> 4, c16 = idx & 15;
    uint4 v = ((const uint4*)Wt)[idx];
    *(uint4*)&sW[rn * 128 + ((c16 ^ (rn & 7)) << 3)] = v;
  }
  if (mode == 0){
    #pragma unroll
    for (int i = 0; i < 4; ++i){
      int idx = t + 512 * i;
      int r = idx >> 4, c16 = idx & 15;
      int gr = rbase + r;
      uint4 v = (gr < n) ? ((const uint4*)(X16 + (size_t)gr * NF))[c16] : make_uint4(0, 0, 0, 0);
      *(uint4*)&sX[r * 128 + ((c16 ^ (r & 7)) << 3)] = v;
    }
  } else {
    #pragma unroll
    for (int i = 0; i < 4; ++i){
      int idx = t + 512 * i;
      int r = idx >> 4, c16 = idx & 15;
      int gr = rbase + r;
      int c = c16 * 8;
      float z[8];
      if (gr < n){
        float4 va = *(const float4*)(Xa + (size_t)gr * NF + c);
        float4 vb = *(const float4*)(Xa + (size_t)gr * NF + c + 4);
        float4 m1 = *(const float4*)(stats + c);
        float4 m2 = *(const float4*)(stats + c + 4);
        float4 q1 = *(const float4*)(stats + 128 + c);
        float4 q2 = *(const float4*)(stats + 128 + c + 4);
        const float* pa = (const float*)&va; const float* pb = (const float*)&vb;
        const float* pm1 = (const float*)&m1; const float* pm2 = (const float*)&m2;
        const float* pq1 = (const float*)&q1; const float* pq2 = (const float*)&q2;
        #pragma unroll
        for (int j = 0; j < 4; ++j){
          float m = pm1[j] * inv_n;
          float var = pq1[j] * inv_n - m * m;
          z[j] = (pa[j] - m) * rsqrtf(var + EPS) + BNB;
          float m_ = pm2[j] * inv_n;
          float var_ = pq2[j] * inv_n - m_ * m_;
          z[4 + j] = (pb[j] - m_) * rsqrtf(var_ + EPS) + BNB;
        }
        if (mode == 2){
          float4 ha = *(const float4*)(Xb + (size_t)gr * NF + c);
          float4 hb = *(const float4*)(Xb + (size_t)gr * NF + c + 4);
          const float* ph1 = (const float*)&ha; const float* ph2 = (const float*)&hb;
          #pragma unroll
          for (int j = 0; j < 4; ++j){
            z[j]     = fmaxf(z[j]     + ph1[j], 0.f);
            z[4 + j] = fmaxf(z[4 + j] + ph2[j], 0.f);
          }
          float4 o1, o2;
          o1.x = z[0]; o1.y = z[1]; o1.z = z[2]; o1.w = z[3];
          o2.x = z[4]; o2.y = z[5]; o2.z = z[6]; o2.w = z[7];
          *(float4*)(Xb + (size_t)gr * NF + c) = o1;
          *(float4*)(Xb + (size_t)gr * NF + c + 4) = o2;
        }
      } else {
        #pragma unroll
        for (int j = 0; j < 8; ++j) z[j] = 0.f;
      }
      uint4 u;
      u.x = pack2(z[0], z[1]); u.y = pack2(z[2], z[3]);
      u.z = pack2(z[4], z[5]); u.w = pack2(z[6], z[7]);
      *(uint4*)&sX[r * 128 + ((c16 ^ (r & 7)) << 3)] = u;
    }
  }
  __syncthreads();
  int lane = t & 63, w = t >> 6;
  int lrow = w * 16 + (lane & 15);
  int khi = lane >> 4;
  bf16x8 a[4];
  #pragma unroll
  for (int ks = 0; ks < 4; ++ks){
    int c16 = ks * 4 + khi;
    a[ks] = *(const bf16x8*)&sX[lrow * 128 + ((c16 ^ (lrow & 7)) << 3)];
  }
  f32x4 acc[8];
  #pragma unroll
  for (int nt = 0; nt < 8; ++nt){
    f32x4 z = {0.f, 0.f, 0.f, 0.f};
    acc[nt] = z;
    int nrow = nt * 16 + (lane & 15);
    #pragma unroll
    for (int ks = 0; ks < 4; ++ks){
      int c16 = ks * 4 + khi;
      bf16x8 b = *(const bf16x8*)&sW[nrow * 128 + ((c16 ^ (nrow & 7)) << 3)];
      acc[nt] = __builtin_amdgcn_mfma_f32_16x16x32_bf16(a[ks], b, acc[nt], 0, 0, 0);
    }
  }
  #pragma unroll
  for (int nt = 0; nt < 8; ++nt){
    #pragma unroll
    for (int i = 0; i < 4; ++i){
      int r = w * 16 + (khi << 2) + i;
      int c = nt * 16 + (lane & 15);
      int csw = c ^ ((r & 7) << 3);
      sX[r * 128 + csw] = f2b(acc[nt][i]);
    }
  }
  __syncthreads();
  #pragma unroll
  for (int i = 0; i < 4; ++i){
    int idx = t + 512 * i;
    int r = idx >> 4, c16 = idx & 15;
    int gr = rbase + r;
    if (gr < n)
      ((uint4*)(Y + (size_t)gr * NF))[c16] = *(const uint4*)&sX[r * 128 + ((c16 ^ (r & 7)) << 3)];
  }
  // fused att-vec (pre-scaled by log2e for v_exp_f32 in attn)
  int r = t >> 2, hh = t & 3;
  int gr = rbase + r;
  if (gr < n){
    float ps = 0.f, pd = 0.f;
    #pragma unroll
    for (int j = 0; j < 16; ++j){
      int c = hh * 32 + j * 2;
      int u = (c >> 3) ^ (r & 7);
      unsigned v = *(const unsigned*)&sX[r * 128 + (u << 3) + (c & 7)];
      float vx = b2f_lo(v), vy = b2f_hi(v);
      ps += vx * asrc[c] + vy * asrc[c + 1];
      pd += vx * adst[c] + vy * adst[c + 1];
    }
    a_s[(size_t)gr * 4 + hh] = ps * LOG2E;
    a_d[(size_t)gr * 4 + hh] = pd * LOG2E;
  }
}

// ---------------- attention: inline alpha (raw v_exp_f32, no-max), main/tail split ----------------
__global__ __launch_bounds__(256) void k_attn(const unsigned short* __restrict__ Hm16,
                                              const float* __restrict__ a_s,
                                              const float* __restrict__ a_d,
                                              const int* __restrict__ off,
                                              const int* __restrict__ esrc,
                                              const float* __restrict__ bias,
                                              float* __restrict__ Yf,
                                              unsigned short* __restrict__ Y16,
                                              int dorelu, int n){
  int t = threadIdx.x, lane = t & 63, w = t >> 6;
  int node = blockIdx.x * 4 + w;
  if (node >= n) return;
  node = __builtin_amdgcn_readfirstlane(node);
  int head = lane >> 4;
  float4 ad4 = ((const float4*)a_d)[node];
  float adh = sel4(ad4, head);
  int lo = off[node], hi = off[node + 1];
  lo = __builtin_amdgcn_readfirstlane(lo);
  hi = __builtin_amdgcn_readfirstlane(hi);
  int fo = lane * 2;
  float sum = 0.f, ax = 0.f, ay = 0.f;
  int e = lo;
  for (; e + 8 <= hi; e += 8){
    int si[8]; float ai[8]; unsigned vi[8];
    #pragma unroll
    for (int k = 0; k < 8; ++k) si[k] = esrc[e + k];
    #pragma unroll
    for (int k = 0; k < 8; ++k) ai[k] = a_s[(si[k] << 2) + head];
    #pragma unroll
    for (int k = 0; k < 8; ++k) vi[k] = *(const unsigned*)(Hm16 + (size_t)si[k] * NF + fo);
    #pragma unroll
    for (int k = 0; k < 8; ++k){
      float wgt = fast_exp2(lrelu(ai[k] + adh));
      sum += wgt;
      ax += wgt * b2f_lo(vi[k]);
      ay += wgt * b2f_hi(vi[k]);
    }
  }
  if (e < hi){
    int si[8]; float ai[8]; unsigned vi[8];
    #pragma unroll
    for (int k = 0; k < 8; ++k) si[k] = esrc[min(e + k, hi - 1)];
    #pragma unroll
    for (int k = 0; k < 8; ++k) ai[k] = a_s[(si[k] << 2) + head];
    #pragma unroll
    for (int k = 0; k < 8; ++k) vi[k] = *(const unsigned*)(Hm16 + (size_t)si[k] * NF + fo);
    #pragma unroll
    for (int k = 0; k < 8; ++k){
      float wgt = (e + k < hi) ? fast_exp2(lrelu(ai[k] + adh)) : 0.f;
      sum += wgt;
      ax += wgt * b2f_lo(vi[k]);
      ay += wgt * b2f_hi(vi[k]);
    }
  }
  float inv = 1.f / (sum + 1e-16f);
  float2 b = *(const float2*)(bias + fo);
  float rx = ax * inv + b.x;
  float ry = ay * inv + b.y;
  if (dorelu){
    rx = fmaxf(rx, 0.f); ry = fmaxf(ry, 0.f);
    ushort2 pk; pk.x = f2b(rx); pk.y = f2b(ry);
    *(ushort2*)(Y16 + (size_t)node * NF + fo) = pk;
  }
  float2 r; r.x = rx; r.y = ry;
  *(float2*)(Yf + (size_t)node * NF + fo) = r;
}

// ---------------- pooling (row-parallel) with fused final bn-residual ----------------
// 64 rows per block; batch sorted -> block spans few graphs; ballot finds per-graph row ranges;
// partial sums flushed via atomicAdd (gpool zeroed in k_init).
__global__ __launch_bounds__(256) void k_pool(const float* __restrict__ G,
                                              const float* __restrict__ H,
                                              const float* __restrict__ stats, float inv_n,
                                              const int* __restrict__ batch,
                                              float* __restrict__ g, int n){
  int t = threadIdx.x, lane = t & 63, w = t >> 6;
  int rstart = blockIdx.x * 64;
  int cnt = min(64, n - rstart);
  int bv = batch[rstart + min(lane, cnt - 1)];
  int g0 = __shfl(bv, 0, 64);
  int g1 = __shfl(bv, cnt - 1, 64);
  int c = lane * 2;
  float m0 = stats[c] * inv_n,     q0 = stats[128 + c] * inv_n;
  float m1 = stats[c + 1] * inv_n, q1 = stats[128 + c + 1] * inv_n;
  float rs0 = rsqrtf(q0 - m0 * m0 + EPS);
  float rs1 = rsqrtf(q1 - m1 * m1 + EPS);
  __shared__ float ss[4][128];
  for (int gg = g0; gg <= g1; ++gg){
    unsigned long long mlt = __ballot(lane < cnt && bv < gg);
    unsigned long long mle = __ballot(lane < cnt && bv <= gg);
    int lo = __popcll(mlt);
    int hi = __popcll(mle);
    float sx = 0.f, sy = 0.f;
    for (int r = lo + w; r < hi; r += 4){
      int row = rstart + r;
      float2 gv = *(const float2*)(G + (size_t)row * NF + c);
      float2 hv = *(const float2*)(H + (size_t)row * NF + c);
      sx += fmaxf((gv.x - m0) * rs0 + BNB + hv.x, 0.f);
      sy += fmaxf((gv.y - m1) * rs1 + BNB + hv.y, 0.f);
    }
    ss[w][lane * 2] = sx; ss[w][lane * 2 + 1] = sy;
    __syncthreads();
    if (t < 128){
      float tot = ss[0][t] + ss[1][t] + ss[2][t] + ss[3][t];
      if (tot != 0.f) atomicAdd(&g[(size_t)gg * NF + t], tot);
    }
    __syncthreads();
  }
}

// ---------------- head stage 2: BN1-apply -> fc (LDS weights) -> relu -> BN2 partial stats ----------------
__global__ __launch_bounds__(256) void k_h2(const float* __restrict__ g,
                                            const float* __restrict__ st1,
                                            const float* __restrict__ fc_w,
                                            const float* __restrict__ fc_b,
                                            float* __restrict__ hfc,
                                            float* __restrict__ st2){
  __shared__ float sA[32 * 128];
  __shared__ float sW[128 * 128];
  __shared__ float redS[8][128], redQ[8][128];
  int t = threadIdx.x;
  int rbase = blockIdx.x * 32;
  #pragma unroll
  for (int i = 0; i < 16; ++i)
    ((float4*)sW)[t + 256 * i] = ((const float4*)fc_w)[t + 256 * i];
  const float inv128 = 1.f / 128.f;
  #pragma unroll
  for (int i = 0; i < 4; ++i){
    int idx = t + 256 * i;
    int r = idx >> 5, c4 = idx & 31;
    float4 v = ((const float4*)(g + (size_t)(rbase + r) * 128))[c4];
    int c0 = c4 * 4;
    float* vv = (float*)&v;
    #pragma unroll
    for (int j = 0; j < 4; ++j){
      float m = st1[c0 + j] * inv128;
      float var = st1[128 + c0 + j] * inv128 - m * m;
      vv[j] = (vv[j] - m) * rsqrtf(var + EPS) + BNB;
    }
    ((float4*)sA)[idx] = v;
  }
  __syncthreads();
  int c0 = (t & 31) * 4, r0 = (t >> 5) * 4;
  float o[4][4];
  float4 bb = *(const float4*)(fc_b + c0);
  #pragma unroll
  for (int i = 0; i < 4; ++i){ o[i][0] = bb.x; o[i][1] = bb.y; o[i][2] = bb.z; o[i][3] = bb.w; }
  for (int k = 0; k < 128; ++k){
    float4 wv = *(const float4*)&sW[k * 128 + c0];
    #pragma unroll
    for (int i = 0; i < 4; ++i){
      float xs = sA[(r0 + i) * 128 + k];
      o[i][0] += xs * wv.x; o[i][1] += xs * wv.y;
      o[i][2] += xs * wv.z; o[i][3] += xs * wv.w;
    }
  }
  float ps[4] = {0, 0, 0, 0}, pq[4] = {0, 0, 0, 0};
  #pragma unroll
  for (int i = 0; i < 4; ++i){
    #pragma unroll
    for (int j = 0; j < 4; ++j){
      float v = fmaxf(o[i][j], 0.f);
      o[i][j] = v;
      ps[j] += v; pq[j] += v * v;
    }
    float4 wv; wv.x = o[i][0]; wv.y = o[i][1]; wv.z = o[i][2]; wv.w = o[i][3];
    *(float4*)(hfc + (size_t)(rbase + r0 + i) * 128 + c0) = wv;
  }
  int g8 = t >> 5;
  #pragma unroll
  for (int j = 0; j < 4; ++j){ redS[g8][c0 + j] = ps[j]; redQ[g8][c0 + j] = pq[j]; }
  __syncthreads();
  if (t < 128){
    float s = 0.f, q = 0.f;
    #pragma unroll
    for (int gg = 0; gg < 8; ++gg){ s += redS[gg][t]; q += redQ[gg][t]; }
    atomicAdd(&st2[t], s);
    atomicAdd(&st2[128 + t], q);
  }
}

// ---------------- head stage 3: BN2-apply -> classifier -> log_softmax ----------------
__global__ __launch_bounds__(1024) void k_h3(const float* __restrict__ hfc,
                                             const float* __restrict__ st2,
                                             const float* __restrict__ cls_w,
                                             const float* __restrict__ cls_b,
                                             float* __restrict__ out){
  __shared__ float A[128 * 128];
  __shared__ float logits[256];
  int t = threadIdx.x;
  #pragma unroll
  for (int i = 0; i < 4; ++i)
    ((float4*)A)[t + 1024 * i] = ((const float4*)hfc)[t + 1024 * i];
  __syncthreads();
  const float inv128 = 1.f / 128.f;
  #pragma unroll
  for (int i = 0; i < 16; ++i){
    int idx = t + 1024 * i;
    int c = idx & 127;
    float m = st2[c] * inv128;
    float var = st2[128 + c] * inv128 - m * m;
    A[idx] = (A[idx] - m) * rsqrtf(var + EPS) + BNB;
  }
  __syncthreads();
  int o = t >> 2, sub = t & 3;
  int r = o >> 1, j = o & 1;
  float acc = 0.f;
  int k0 = sub * 32;
  for (int k = k0; k < k0 + 32; ++k)
    acc += A[r * 128 + k] * cls_w[k * 2 + j];
  acc += __shfl_xor(acc, 1, 64);
  acc += __shfl_xor(acc, 2, 64);
  if (sub == 0) logits[o] = acc + cls_b[j];
  __syncthreads();
  if (t < 256){
    int rr = t >> 1;
    float l0 = logits[rr * 2], l1 = logits[rr * 2 + 1];
    float mx = fmaxf(l0, l1);
    float lse = mx + logf(__expf(l0 - mx) + __expf(l1 - mx));
    out[t] = logits[t] - lse;
  }
}

extern "C" void kernel_launch(void* const* d_in, const int* in_sizes, int n_in,
                              void* d_out, int out_size, void* d_ws, size_t ws_size,
                              hipStream_t stream){
  const float* x        = (const float*)d_in[0];
  const int*   ei       = (const int*)d_in[1];
  const int*   batch    = (const int*)d_in[2];
  const float* gat_lin  = (const float*)d_in[3];
  const float* att_src  = (const float*)d_in[4];
  const float* att_dst  = (const float*)d_in[5];
  const float* gat_bias = (const float*)d_in[6];
  const float* fc_w     = (const float*)d_in[7];
  const float* fc_b     = (const float*)d_in[8];
  const float* cls_w    = (const float*)d_in[9];
  const float* cls_b    = (const float*)d_in[10];
  float* out = (float*)d_out;
  (void)n_in; (void)out_size; (void)ws_size;

  int N = in_sizes[0] / NF;
  int E = in_sizes[1] / 2;
  int total = E + N;
  int nbkt = cdiv(N, 256);
  float inv_n = 1.f / (float)N;

  char* p = (char*)d_ws;
  auto alloc = [&](size_t bytes) -> char* {
    char* r = p;
    p += (bytes + 255) & ~(size_t)255;
    return r;
  };
  int*   off     = (int*)alloc((size_t)(N + 1) * 4);
  int*   bcnt    = (int*)alloc((size_t)nbkt * 4);
  int*   boff    = (int*)alloc((size_t)(nbkt + 1) * 4);
  int*   bcursor = (int*)alloc((size_t)nbkt * 4);
  unsigned* ebuf = (unsigned*)alloc((size_t)total * 4);
  int*   esrc    = (int*)alloc((size_t)total * 4);
  float* stats   = (float*)alloc(8 * 256 * 4);
  float* hbuf    = (float*)alloc((size_t)N * NF * 4);
  unsigned short* hbuf16 = (unsigned short*)alloc((size_t)N * NF * 2);
  unsigned short* tmp16  = (unsigned short*)alloc((size_t)N * NF * 2);
  unsigned short* wbuf16 = (unsigned short*)alloc((size_t)4 * NF * NF * 2);
  float* gout    = (float*)alloc((size_t)N * NF * 4);
  float* a_s     = (float*)alloc((size_t)N * 4 * 4);
  float* a_d     = (float*)alloc((size_t)N * 4 * 4);
  float* gpool   = (float*)alloc(128 * NF * 4);
  float* hfc     = (float*)alloc(128 * NF * 4);

  // CSR build
  k_init<<<256, 256, 0, stream>>>(stats, bcnt, nbkt, 1536, gpool, gat_lin, wbuf16);
  k_bhist<<<256, 256, 0, stream>>>(ei, E, N, bcnt, nbkt);
  k_bscan<<<1, 256, 0, stream>>>(bcnt, boff, bcursor, nbkt);
  k_bscatter2<<<cdiv(total, CHUNK), 256, 0, stream>>>(ei, E, N, bcursor, ebuf, nbkt);
  k_bucket<<<nbkt, 256, 0, stream>>>(ebuf, boff, off, esrc, N);

  k_colstats<<<256, 256, 0, stream>>>(x, N, stats);   // stats0 (on x)

  for (int L = 0; L < 4; ++L){
    if (L == 0){
      k_gemm<<<cdiv(N, 128), 512, 0, stream>>>(hbuf16, x, hbuf, stats, inv_n, 1,
                                               wbuf16 + (size_t)L * NF * NF, tmp16,
                                               att_src + (size_t)L * NF, att_dst + (size_t)L * NF,
                                               a_s, a_d, N);
      k_attn<<<cdiv(N, 4), 256, 0, stream>>>(tmp16, a_s, a_d, off, esrc,
                                             gat_bias + (size_t)L * NF,
                                             hbuf, hbuf16, 1, N);
    } else {
      int mode = (L == 1) ? 0 : 2;
      k_gemm<<<cdiv(N, 128), 512, 0, stream>>>(hbuf16, gout, hbuf, stats + (L - 1) * 256, inv_n, mode,
                                               wbuf16 + (size_t)L * NF * NF, tmp16,
                                               att_src + (size_t)L * NF, att_dst + (size_t)L * NF,
                                               a_s, a_d, N);
      k_attn<<<cdiv(N, 4), 256, 0, stream>>>(tmp16, a_s, a_d, off, esrc,
                                             gat_bias + (size_t)L * NF,
                                             gout, hbuf16, 0, N);
      k_colstats<<<256, 256, 0, stream>>>(gout, N, stats + L * 256);
    }
  }

  k_pool<<<cdiv(N, 64), 256, 0, stream>>>(gout, hbuf, stats + 3 * 256, inv_n, batch, gpool, N);
  k_colstats<<<32, 256, 0, stream>>>(gpool, 128, stats + 1024);
  k_h2<<<4, 256, 0, stream>>>(gpool, stats + 1024, fc_w, fc_b, hfc, stats + 1280);
  k_h3<<<1, 1024, 0, stream>>>(hfc, stats + 1280, cls_w, cls_b, out);
}